// Round 9
// baseline (275.995 us; speedup 1.0000x reference)
//
#include <hip/hip_runtime.h>
#include <math.h>

#define IMGS 16
#define EMB 2400
#define HW 196
#define CAPS 64
#define ATTK 180
#define NPOOL 15
#define NCOLS (IMGS * HW)  // 3136
#define KPAD 224           // 196 padded to multiple of 32

typedef __attribute__((ext_vector_type(8))) short short8;
typedef __attribute__((ext_vector_type(4))) float f32x4;
typedef const __attribute__((address_space(1))) unsigned int* gas1_t;
typedef __attribute__((address_space(3))) unsigned int* las3_t;
typedef unsigned long long ull;

__device__ inline unsigned short f2bf(float f) {
    unsigned int u = __builtin_bit_cast(unsigned int, f);
    u += 0x7fffu + ((u >> 16) & 1u);  // round-to-nearest-even
    return (unsigned short)(u >> 16);
}
__device__ inline float bf2f(unsigned int lo16) {
    return __builtin_bit_cast(float, lo16 << 16);
}
__device__ inline unsigned f2sort(float f) {
    unsigned u = __builtin_bit_cast(unsigned, f);
    int msk = ((int)u) >> 31;
    return u ^ (unsigned)(msk | 0x80000000);
}

// ---- DPP 64-lane reductions (rocPRIM pattern) ----
__device__ inline float wave_max64_dpp(float v) {
    int x = __builtin_bit_cast(int, v);
#define STEPMX(c)                                                              \
    {                                                                          \
        int y = __builtin_amdgcn_update_dpp(x, x, c, 0xf, 0xf, false);         \
        float a = fmaxf(__builtin_bit_cast(float, x), __builtin_bit_cast(float, y)); \
        x = __builtin_bit_cast(int, a);                                        \
    }
    STEPMX(0x111) STEPMX(0x112) STEPMX(0x114) STEPMX(0x118) STEPMX(0x142) STEPMX(0x143)
#undef STEPMX
    return __builtin_bit_cast(float, __builtin_amdgcn_readlane(x, 63));
}
__device__ inline float wave_min64_dpp(float v) {
    int x = __builtin_bit_cast(int, v);
#define STEPMN(c)                                                              \
    {                                                                          \
        int y = __builtin_amdgcn_update_dpp(x, x, c, 0xf, 0xf, false);         \
        float a = fminf(__builtin_bit_cast(float, x), __builtin_bit_cast(float, y)); \
        x = __builtin_bit_cast(int, a);                                        \
    }
    STEPMN(0x111) STEPMN(0x112) STEPMN(0x114) STEPMN(0x118) STEPMN(0x142) STEPMN(0x143)
#undef STEPMN
    return __builtin_bit_cast(float, __builtin_amdgcn_readlane(x, 63));
}

// ---------------- Weldon pooling v4: DPP reduce + unique-id floats ----------------
__global__ __launch_bounds__(256) void weldon_kernel(const float* __restrict__ g,
                                                     float* __restrict__ hpool) {
    int wid = (blockIdx.x * 256 + threadIdx.x) >> 6;
    int lane = threadIdx.x & 63;
    const float* row = g + (size_t)wid * HW;
    float s[4], t[4];
#pragma unroll
    for (int q = 0; q < 4; q++) {
        int e = lane + 64 * q;
        if (e < HW) {
            unsigned u = __builtin_bit_cast(unsigned, row[e]);
            u = (u & 0xFFFFFF00u) | (unsigned)(q * 64 + lane);
            float f = __builtin_bit_cast(float, u);
            s[q] = f;
            t[q] = f;
        } else {
            s[q] = -INFINITY;
            t[q] = INFINITY;
        }
    }
    float stop = 0.f, sbot = 0.f;
#pragma unroll
    for (int it = 0; it < NPOOL; ++it) {
        float m = wave_max64_dpp(fmaxf(fmaxf(s[0], s[1]), fmaxf(s[2], s[3])));
        stop += m;
        unsigned mb = __builtin_bit_cast(unsigned, m);
#pragma unroll
        for (int q = 0; q < 4; q++)
            s[q] = (__builtin_bit_cast(unsigned, s[q]) == mb) ? -INFINITY : s[q];

        float n = wave_min64_dpp(fminf(fminf(t[0], t[1]), fminf(t[2], t[3])));
        sbot += n;
        unsigned nb = __builtin_bit_cast(unsigned, n);
#pragma unroll
        for (int q = 0; q < 4; q++)
            t[q] = (__builtin_bit_cast(unsigned, t[q]) == nb) ? INFINITY : t[q];
    }
    if (lane == 0) hpool[wid] = (stop + sbot) / 15.0f;
}

// ---------------- x = hpool @ fc_w.T + fc_b ----------------
__global__ void x_kernel(const float* __restrict__ hpool, const float* __restrict__ fc_w,
                         const float* __restrict__ fc_b, float* __restrict__ x_out) {
    int o = blockIdx.x;
    int lane = threadIdx.x;  // 64
    float acc[IMGS];
#pragma unroll
    for (int i = 0; i < IMGS; i++) acc[i] = 0.f;
    const float* wrow = fc_w + (size_t)o * EMB;
    for (int e = lane; e < EMB; e += 64) {
        float wv = wrow[e];
#pragma unroll
        for (int i = 0; i < IMGS; i++) acc[i] += hpool[i * EMB + e] * wv;
    }
#pragma unroll
    for (int i = 0; i < IMGS; i++) {
#pragma unroll
        for (int s = 32; s > 0; s >>= 1) acc[i] += __shfl_xor(acc[i], s, 64);
    }
    if (lane == 0) {
        float bo = fc_b[o];
#pragma unroll
        for (int i = 0; i < IMGS; i++) x_out[i * EMB + o] = acc[i] + bo;
    }
}

// ---------------- topk v4: radix select with parallel bucket scan ----------------
__global__ __launch_bounds__(256) void topk_kernel(const float* __restrict__ caps,
                                                   int* __restrict__ idxs,
                                                   float* __restrict__ vals) {
    __shared__ float rowf[EMB];
    __shared__ unsigned hist[4][256];
    __shared__ unsigned scanbuf[256];
    __shared__ unsigned cnts[256];
    __shared__ ull sprefix;
    __shared__ int srank;
    int c = blockIdx.x;
    int tid = threadIdx.x;
    const float4* src = (const float4*)(caps + (size_t)c * EMB);
    for (int j = tid; j < EMB / 4; j += 256) {
        float4 v = src[j];
        *(float4*)&rowf[j * 4] = v;
    }
    if (tid == 0) { sprefix = 0ull; srank = ATTK; }

#pragma unroll 1
    for (int pass = 0; pass < 6; ++pass) {
        __syncthreads();
        ull pref = sprefix;
        int rk = srank;
        int shift = 40 - pass * 8;
        ull pmaskhi = (pass == 0) ? 0ull : ~((1ull << (shift + 8)) - 1ull);
        hist[0][tid] = 0; hist[1][tid] = 0; hist[2][tid] = 0; hist[3][tid] = 0;
        __syncthreads();
        unsigned* myhist = hist[tid >> 6];
#pragma unroll 1
        for (int s = 0; s < 10; s++) {
            int e = tid + s * 256;
            if (e < EMB) {
                ull key = ((ull)f2sort(rowf[e]) << 16) | ((unsigned)(2399 - e) << 4);
                if ((key & pmaskhi) == pref)
                    atomicAdd(&myhist[(unsigned)(key >> shift) & 255u], 1u);
            }
        }
        __syncthreads();
        unsigned h = hist[0][tid] + hist[1][tid] + hist[2][tid] + hist[3][tid];
        scanbuf[255 - tid] = h;
        __syncthreads();
#pragma unroll
        for (int d = 1; d < 256; d <<= 1) {
            unsigned add = (tid >= d) ? scanbuf[tid - d] : 0u;
            __syncthreads();
            scanbuf[tid] += add;
            __syncthreads();
        }
        unsigned incl = scanbuf[255 - tid];
        unsigned excl = incl - h;
        if (h > 0u && excl < (unsigned)rk && incl >= (unsigned)rk) {
            srank = rk - (int)excl;
            sprefix = pref | ((ull)tid << shift);
        }
    }
    __syncthreads();
    ull T = sprefix;
    unsigned selmask = 0, cnt = 0;
#pragma unroll 1
    for (int s = 0; s < 10; s++) {
        int e = tid + s * 256;
        if (e < EMB) {
            ull key = ((ull)f2sort(rowf[e]) << 16) | ((unsigned)(2399 - e) << 4);
            if (key >= T) { selmask |= 1u << s; cnt++; }
        }
    }
    cnts[tid] = cnt;
    __syncthreads();
#pragma unroll
    for (int d = 1; d < 256; d <<= 1) {
        unsigned add = (tid >= d) ? cnts[tid - d] : 0u;
        __syncthreads();
        cnts[tid] += add;
        __syncthreads();
    }
    unsigned slot = cnts[tid] - cnt;
#pragma unroll 1
    for (int s = 0; s < 10; s++) {
        if (selmask & (1u << s)) {
            int e = tid + s * 256;
            idxs[c * ATTK + slot] = e;
            vals[c * ATTK + slot] = fabsf(rowf[e]);
            slot++;
        }
    }
}

// ---------------- fc_w fp32 -> bf16 row-major copy ----------------
__global__ void convert_w_kernel(const float* __restrict__ w, unsigned short* __restrict__ wbf) {
    int i = (blockIdx.x * 256 + threadIdx.x) * 4;
    if (i >= EMB * EMB) return;
    float4 a = *(const float4*)&w[i];
    ushort4 r;
    r.x = f2bf(a.x); r.y = f2bf(a.y); r.z = f2bf(a.z); r.w = f2bf(a.w);
    *(ushort4*)&wbf[i] = r;
}

// ---------------- gbf[i][e][KPAD] = bf16(g[i][e][hw]), zero-padded ----------------
__global__ __launch_bounds__(256) void convert_g_kernel(const float* __restrict__ g,
                                                        unsigned short* __restrict__ gbf) {
    int row = blockIdx.x * 4 + (threadIdx.x >> 6);
    int l = threadIdx.x & 63;
    const float* src = g + (size_t)row * HW;
    unsigned short* dst = gbf + (size_t)row * KPAD;
    if (l < KPAD / 4) {
        ushort4 o = {0, 0, 0, 0};
        if (l < HW / 4) {
            float4 v = ((const float4*)src)[l];
            o.x = f2bf(v.x); o.y = f2bf(v.y); o.z = f2bf(v.z); o.w = f2bf(v.w);
        }
        ((ushort4*)dst)[l] = o;
    }
}

// ---------------- gT[n][e] = bf16(g[i(n)][e][hw(n)]) ----------------
__global__ void transpose_g_kernel(const float* __restrict__ g, unsigned short* __restrict__ gT) {
    __shared__ float t[96][50];
    int i = blockIdx.z;
    int e0 = blockIdx.y * 96;
    int h0 = blockIdx.x * 49;
    int tid = threadIdx.x;
    for (int f = tid; f < 96 * 49; f += 256) {
        int e = f / 49, hh = f % 49;
        t[e][hh] = g[(size_t)i * EMB * HW + (size_t)(e0 + e) * HW + h0 + hh];
    }
    __syncthreads();
    for (int f = tid; f < 49 * 96; f += 256) {
        int hh = f / 96, e = f % 96;
        gT[(size_t)(i * HW + h0 + hh) * EMB + e0 + e] = f2bf(t[e][hh]);
    }
}

// ======== NT bf16 MFMA GEMM, global_load_lds staging, double-buffered 1-barrier loop ========
// T2 swizzle (rule #21, both-sides-or-neither): LDS dest stays LINEAR (gll requirement);
// the 16B k-chunk each lane SOURCES is permuted (chunk = (l&3)^((l>>3)&3)), and the
// fragment READ applies the same permutation (slot = (l>>4)^((l>>1)&3)). Read bank-group
// becomes (ln&1)*4 + (q^((ln>>1)&3)): 16 lanes cover all 8 groups x2 => 2-way (free),
// vs 8-way before (r8: 6.17M conflicts, MfmaUtil 19%).
template <int MF, int NF, int OUT_MODE>
__global__ __launch_bounds__(256) void gemm_gll(const unsigned short* __restrict__ A,
                                                const unsigned short* __restrict__ B,
                                                void* __restrict__ outp,
                                                int M, int N, int K, int kper,
                                                long az, long bz) {
    constexpr int BM = MF * 32, BN = NF * 32;
    constexpr int ROWS = BM + BN;
    constexpr int NCALL = ROWS / 16;
    __shared__ unsigned short lds[2][ROWS][32];
    int m0 = blockIdx.y * BM, n0 = blockIdx.x * BN;
    int z = blockIdx.z;
    const unsigned short* Ab = A + (size_t)z * az;
    const unsigned short* Bb = B + (size_t)z * bz;
    int kb = (az == 0 && bz == 0) ? z * kper : 0;
    int nt = kper / 32;
    int tid = threadIdx.x, w = tid >> 6, lane = tid & 63;
    int wm = (w >> 1) * (MF * 16), wn = (w & 1) * (NF * 16);
    int ln = lane & 15;
    // swizzled read slot: chunk q=(lane>>4) stored at slot q^((row>>1)&3); row bases %16==0
    int ks = (((lane >> 4) ^ ((lane >> 1) & 3))) * 8;
    int srow = lane >> 2;
    // swizzled store source chunk: slot (lane&3) at row j*16+(lane>>2) holds chunk (l&3)^((l>>3)&3)
    int skc = (((lane & 3) ^ ((lane >> 3) & 3))) * 8;

    auto STAGE = [&](int buf, int t) {
        int k0 = kb + t * 32;
        for (int j = w; j < NCALL; j += 4) {
            int r = j * 16 + srow;
            const unsigned short* src = (r < BM)
                ? (Ab + (size_t)(m0 + r) * K + k0 + skc)
                : (Bb + (size_t)(n0 + r - BM) * K + k0 + skc);
            __builtin_amdgcn_global_load_lds((gas1_t)(const void*)src,
                                             (las3_t)(void*)&lds[buf][j * 16][0], 16, 0, 0);
        }
    };

    STAGE(0, 0);
    __syncthreads();
    f32x4 acc[MF][NF] = {};
    int cur = 0;
    for (int t = 0; t < nt; ++t) {
        if (t + 1 < nt) STAGE(cur ^ 1, t + 1);
        short8 af[MF], bfv[NF];
#pragma unroll
        for (int mf = 0; mf < MF; mf++)
            af[mf] = *(const short8*)&lds[cur][wm + mf * 16 + ln][ks];
#pragma unroll
        for (int nf = 0; nf < NF; nf++)
            bfv[nf] = *(const short8*)&lds[cur][BM + wn + nf * 16 + ln][ks];
#pragma unroll
        for (int mf = 0; mf < MF; mf++)
#pragma unroll
            for (int nf = 0; nf < NF; nf++)
                acc[mf][nf] = __builtin_amdgcn_mfma_f32_16x16x32_bf16(af[mf], bfv[nf],
                                                                      acc[mf][nf], 0, 0, 0);
        __syncthreads();
        cur ^= 1;
    }
#pragma unroll
    for (int mf = 0; mf < MF; mf++) {
#pragma unroll
        for (int nf = 0; nf < NF; nf++) {
#pragma unroll
            for (int rr = 0; rr < 4; rr++) {
                int row = m0 + wm + mf * 16 + (lane >> 4) * 4 + rr;
                int col = n0 + wn + nf * 16 + ln;
                float v = acc[mf][nf][rr];
                if (OUT_MODE == 0) {
                    ((unsigned short*)outp)[(size_t)row * N + col] = f2bf(fabsf(v));
                } else if (OUT_MODE == 2) {
                    ((float*)outp)[(size_t)z * M * N + (size_t)row * N + col] = v;
                } else {
                    ((unsigned short*)outp)[(size_t)z * M * N + (size_t)row * N + col] = f2bf(v);
                }
            }
        }
    }
}

// ======== fallback reg-staged NT GEMM (used only if ws too small for wbf) ========
__device__ inline uint4 load8(const unsigned short* p) { return *(const uint4*)p; }
__device__ inline uint4 load8(const float* p) {
    float4 a = *(const float4*)p;
    float4 b = *(const float4*)(p + 4);
    uint4 r;
    r.x = (unsigned)f2bf(a.x) | ((unsigned)f2bf(a.y) << 16);
    r.y = (unsigned)f2bf(a.z) | ((unsigned)f2bf(a.w) << 16);
    r.z = (unsigned)f2bf(b.x) | ((unsigned)f2bf(b.y) << 16);
    r.w = (unsigned)f2bf(b.z) | ((unsigned)f2bf(b.w) << 16);
    return r;
}

template <int MF, int NF, int OUT_MODE, typename TA, typename TB>
__global__ __launch_bounds__(256) void mfma_gemm_nt(const TA* __restrict__ A,
                                                    const TB* __restrict__ B,
                                                    const float* __restrict__ bias,
                                                    void* __restrict__ outp,
                                                    int M, int N, int K, int kper) {
    constexpr int BM = MF * 32, BN = NF * 32;
    constexpr int nA = BM * 4, nTot = (BM + BN) * 4;
    constexpr int NCH = (nTot + 255) / 256;
    __shared__ unsigned short As[BM][40];
    __shared__ unsigned short Bs[BN][40];
    int m0 = blockIdx.y * BM, n0 = blockIdx.x * BN;
    int sk = blockIdx.z;
    int kb = sk * kper, ke = kb + kper;
    int tid = threadIdx.x;
    int w = tid >> 6, lane = tid & 63;
    int wm = (w >> 1) * (MF * 16), wn = (w & 1) * (NF * 16);
    int ln = lane & 15, ks = (lane >> 4) * 8;
    uint4 r[NCH];
#pragma unroll
    for (int j = 0; j < NCH; j++) {
        int c = tid + 256 * j;
        if (c < nTot) {
            if (c < nA) {
                int row = c >> 2, kc = c & 3;
                r[j] = load8(A + (size_t)(m0 + row) * K + kb + kc * 8);
            } else {
                int cc = c - nA, row = cc >> 2, kc = cc & 3;
                r[j] = load8(B + (size_t)(n0 + row) * K + kb + kc * 8);
            }
        }
    }
    f32x4 acc[MF][NF] = {};
    for (int k0 = kb; k0 < ke; k0 += 32) {
#pragma unroll
        for (int j = 0; j < NCH; j++) {
            int c = tid + 256 * j;
            if (c < nTot) {
                if (c < nA) {
                    int row = c >> 2, kc = c & 3;
                    *(uint4*)&As[row][kc * 8] = r[j];
                } else {
                    int cc = c - nA, row = cc >> 2, kc = cc & 3;
                    *(uint4*)&Bs[row][kc * 8] = r[j];
                }
            }
        }
        __syncthreads();
        if (k0 + 32 < ke) {
#pragma unroll
            for (int j = 0; j < NCH; j++) {
                int c = tid + 256 * j;
                if (c < nTot) {
                    if (c < nA) {
                        int row = c >> 2, kc = c & 3;
                        r[j] = load8(A + (size_t)(m0 + row) * K + (k0 + 32) + kc * 8);
                    } else {
                        int cc = c - nA, row = cc >> 2, kc = cc & 3;
                        r[j] = load8(B + (size_t)(n0 + row) * K + (k0 + 32) + kc * 8);
                    }
                }
            }
        }
        short8 af[MF], bfv[NF];
#pragma unroll
        for (int mf = 0; mf < MF; mf++)
            af[mf] = *(const short8*)&As[wm + mf * 16 + ln][ks];
#pragma unroll
        for (int nf = 0; nf < NF; nf++)
            bfv[nf] = *(const short8*)&Bs[wn + nf * 16 + ln][ks];
#pragma unroll
        for (int mf = 0; mf < MF; mf++)
#pragma unroll
            for (int nf = 0; nf < NF; nf++)
                acc[mf][nf] = __builtin_amdgcn_mfma_f32_16x16x32_bf16(af[mf], bfv[nf],
                                                                      acc[mf][nf], 0, 0, 0);
        __syncthreads();
    }
#pragma unroll
    for (int mf = 0; mf < MF; mf++) {
#pragma unroll
        for (int nf = 0; nf < NF; nf++) {
#pragma unroll
            for (int rr = 0; rr < 4; rr++) {
                int row = m0 + wm + mf * 16 + (lane >> 4) * 4 + rr;
                int col = n0 + wn + nf * 16 + ln;
                float v = acc[mf][nf][rr];
                if (OUT_MODE == 0) {
                    ((unsigned short*)outp)[(size_t)row * N + col] = f2bf(fabsf(v));
                } else if (OUT_MODE == 2) {
                    ((float*)outp)[(size_t)sk * M * N + (size_t)row * N + col] = v;
                }
            }
        }
    }
}

// ---------------- reduce 3 split-K partials + bias -> xa_out ----------------
__global__ void reduce3_kernel(const float* __restrict__ p, const float* __restrict__ bias,
                               float* __restrict__ out) {
    int i = (blockIdx.x * 256 + threadIdx.x) * 4;
    if (i >= IMGS * CAPS * EMB) return;
    float4 a = *(const float4*)&p[i];
    float4 b = *(const float4*)&p[i + IMGS * CAPS * EMB];
    float4 c = *(const float4*)&p[i + 2 * IMGS * CAPS * EMB];
    float4 bb = *(const float4*)&bias[i % EMB];
    float4 r = {a.x + b.x + c.x + bb.x, a.y + b.y + c.y + bb.y,
                a.z + b.z + c.z + bb.z, a.w + b.w + c.w + bb.w};
    *(float4*)&out[i] = r;
}

// ---------------- heat: H[c,n] = sum_j vals[c,j] * Abf[idx[c,j], n] ----------------
__global__ void heat_kernel(const int* __restrict__ idxs, const float* __restrict__ vals,
                            const unsigned short* __restrict__ A, float* __restrict__ H) {
    __shared__ int sidx[ATTK];
    __shared__ float sval[ATTK];
    int c = blockIdx.y;
    int tid = threadIdx.x;
    if (tid < ATTK) {
        sidx[tid] = idxs[c * ATTK + tid];
        sval[tid] = vals[c * ATTK + tid];
    }
    __syncthreads();
    int n = (blockIdx.x * 256 + tid) * 4;
    if (n >= NCOLS) return;
    float a0 = 0.f, a1 = 0.f, a2 = 0.f, a3 = 0.f;
    for (int j = 0; j < ATTK; j++) {
        uint2 p = *(const uint2*)&A[(size_t)sidx[j] * NCOLS + n];
        float sv = sval[j];
        a0 += sv * bf2f(p.x & 0xffffu);
        a1 += sv * bf2f(p.x >> 16);
        a2 += sv * bf2f(p.y & 0xffffu);
        a3 += sv * bf2f(p.y >> 16);
    }
    float4 r = {a0, a1, a2, a3};
    *(float4*)&H[(size_t)c * NCOLS + n] = r;
}

// ---------------- norm: Hbf[i][c][KPAD] = bf16(H / rowsum), zero-padded ----------------
__global__ void norm_kernel(const float* __restrict__ H, unsigned short* __restrict__ Hbf) {
    int c = blockIdx.x / IMGS, i = blockIdx.x % IMGS;
    const float* p = H + (size_t)c * NCOLS + i * HW;
    int lane = threadIdx.x;  // 64
    float s = 0.f;
    for (int hw = lane; hw < HW; hw += 64) s += p[hw];
#pragma unroll
    for (int d = 32; d > 0; d >>= 1) s += __shfl_xor(s, d, 64);
    float inv = 1.0f / s;
    unsigned short* dst = Hbf + ((size_t)i * CAPS + c) * KPAD;
    for (int hw = lane; hw < KPAD; hw += 64)
        dst[hw] = (hw < HW) ? f2bf(p[hw] * inv) : (unsigned short)0;
}

extern "C" void kernel_launch(void* const* d_in, const int* in_sizes, int n_in,
                              void* d_out, int out_size, void* d_ws, size_t ws_size,
                              hipStream_t stream) {
    const float* g = (const float*)d_in[0];
    const float* caps = (const float*)d_in[1];
    const float* fc_w = (const float*)d_in[2];
    const float* fc_b = (const float*)d_in[3];

    float* out = (float*)d_out;
    float* x_out = out;                    // 38400
    float* xa_out = out + 38400;           // 2457600
    float* g_out = out + 38400 + 2457600;  // 7526400 floats = 30.1 MB scratch until final copy
    unsigned short* Abf = (unsigned short*)g_out;
    unsigned short* gT = Abf + (size_t)EMB * NCOLS;
    unsigned short* gbf = (unsigned short*)g_out;
    unsigned short* Hbf = gbf + (size_t)IMGS * EMB * KPAD;
    float* Ppart = g_out;

    float* ws = (float*)d_ws;
    float* hpool = ws;                                      // 38400 f
    int* idxs = (int*)(ws + 38400);                         // 11520
    float* vals = ws + 49920;                               // 11520
    float* H = ws + 61440;                                  // 200704 f
    unsigned short* Pbf = (unsigned short*)(ws + 262144);   // ends byte 5963776
    unsigned short* wbf = (unsigned short*)(ws + 1490944);  // ends byte 17483776
    bool use_wbf = ws_size >= (size_t)17483776;

    weldon_kernel<<<(IMGS * EMB) / 4, 256, 0, stream>>>(g, hpool);
    x_kernel<<<EMB, 64, 0, stream>>>(hpool, fc_w, fc_b, x_out);
    topk_kernel<<<CAPS, 256, 0, stream>>>(caps, idxs, vals);
    transpose_g_kernel<<<dim3(4, 25, IMGS), 256, 0, stream>>>(g, gT);

    if (use_wbf) {
        convert_w_kernel<<<(EMB * EMB / 4 + 255) / 256, 256, 0, stream>>>(fc_w, wbf);
        gemm_gll<5, 2, 0><<<dim3(NCOLS / 64, EMB / 160, 1), 256, 0, stream>>>(
            wbf, gT, Abf, EMB, NCOLS, EMB, EMB, 0, 0);
    } else {
        mfma_gemm_nt<5, 2, 0, float, unsigned short>
            <<<dim3(NCOLS / 64, EMB / 160), 256, 0, stream>>>(fc_w, gT, nullptr, Abf,
                                                              EMB, NCOLS, EMB, EMB);
    }
    heat_kernel<<<dim3((NCOLS / 4 + 255) / 256, CAPS), 256, 0, stream>>>(idxs, vals, Abf, H);
    norm_kernel<<<CAPS * IMGS, 64, 0, stream>>>(H, Hbf);
    convert_g_kernel<<<(IMGS * EMB) / 4, 256, 0, stream>>>(g, gbf);
    gemm_gll<2, 5, 3><<<dim3(EMB / 160, 1, IMGS), 256, 0, stream>>>(
        Hbf, gbf, Pbf, CAPS, EMB, KPAD, KPAD, (long)CAPS * KPAD, (long)EMB * KPAD);
    if (use_wbf) {
        gemm_gll<2, 5, 2><<<dim3(EMB / 160, (IMGS * CAPS) / 64, 3), 256, 0, stream>>>(
            Pbf, wbf, Ppart, IMGS * CAPS, EMB, EMB, 800, 0, 0);
    } else {
        mfma_gemm_nt<2, 3, 2, unsigned short, float>
            <<<dim3(EMB / 96, (IMGS * CAPS) / 64, 3), 256, 0, stream>>>(Pbf, fc_w, nullptr, Ppart,
                                                                        IMGS * CAPS, EMB, EMB, 800);
    }
    reduce3_kernel<<<(IMGS * CAPS * EMB / 4) / 256, 256, 0, stream>>>(Ppart, fc_b, xa_out);
    hipMemcpyAsync(g_out, g, sizeof(float) * (size_t)IMGS * EMB * HW,
                   hipMemcpyDeviceToDevice, stream);
}

// Round 10
// 275.492 us; speedup vs baseline: 1.0018x; 1.0018x over previous
//
#include <hip/hip_runtime.h>
#include <math.h>

#define IMGS 16
#define EMB 2400
#define HW 196
#define CAPS 64
#define ATTK 180
#define NPOOL 15
#define NCOLS (IMGS * HW)  // 3136
#define KPAD 224           // 196 padded to multiple of 32

typedef __attribute__((ext_vector_type(8))) short short8;
typedef __attribute__((ext_vector_type(4))) float f32x4;
typedef const __attribute__((address_space(1))) unsigned int* gas1_t;
typedef __attribute__((address_space(3))) unsigned int* las3_t;
typedef unsigned long long ull;

__device__ inline unsigned short f2bf(float f) {
    unsigned int u = __builtin_bit_cast(unsigned int, f);
    u += 0x7fffu + ((u >> 16) & 1u);  // round-to-nearest-even
    return (unsigned short)(u >> 16);
}
__device__ inline float bf2f(unsigned int lo16) {
    return __builtin_bit_cast(float, lo16 << 16);
}
__device__ inline unsigned f2sort(float f) {
    unsigned u = __builtin_bit_cast(unsigned, f);
    int msk = ((int)u) >> 31;
    return u ^ (unsigned)(msk | 0x80000000);
}

// ---- DPP 64-lane reductions (rocPRIM pattern) ----
__device__ inline float wave_max64_dpp(float v) {
    int x = __builtin_bit_cast(int, v);
#define STEPMX(c)                                                              \
    {                                                                          \
        int y = __builtin_amdgcn_update_dpp(x, x, c, 0xf, 0xf, false);         \
        float a = fmaxf(__builtin_bit_cast(float, x), __builtin_bit_cast(float, y)); \
        x = __builtin_bit_cast(int, a);                                        \
    }
    STEPMX(0x111) STEPMX(0x112) STEPMX(0x114) STEPMX(0x118) STEPMX(0x142) STEPMX(0x143)
#undef STEPMX
    return __builtin_bit_cast(float, __builtin_amdgcn_readlane(x, 63));
}
__device__ inline float wave_min64_dpp(float v) {
    int x = __builtin_bit_cast(int, v);
#define STEPMN(c)                                                              \
    {                                                                          \
        int y = __builtin_amdgcn_update_dpp(x, x, c, 0xf, 0xf, false);         \
        float a = fminf(__builtin_bit_cast(float, x), __builtin_bit_cast(float, y)); \
        x = __builtin_bit_cast(int, a);                                        \
    }
    STEPMN(0x111) STEPMN(0x112) STEPMN(0x114) STEPMN(0x118) STEPMN(0x142) STEPMN(0x143)
#undef STEPMN
    return __builtin_bit_cast(float, __builtin_amdgcn_readlane(x, 63));
}

// ---------------- Weldon pooling v4: DPP reduce + unique-id floats ----------------
__global__ __launch_bounds__(256) void weldon_kernel(const float* __restrict__ g,
                                                     float* __restrict__ hpool) {
    int wid = (blockIdx.x * 256 + threadIdx.x) >> 6;
    int lane = threadIdx.x & 63;
    const float* row = g + (size_t)wid * HW;
    float s[4], t[4];
#pragma unroll
    for (int q = 0; q < 4; q++) {
        int e = lane + 64 * q;
        if (e < HW) {
            unsigned u = __builtin_bit_cast(unsigned, row[e]);
            u = (u & 0xFFFFFF00u) | (unsigned)(q * 64 + lane);
            float f = __builtin_bit_cast(float, u);
            s[q] = f;
            t[q] = f;
        } else {
            s[q] = -INFINITY;
            t[q] = INFINITY;
        }
    }
    float stop = 0.f, sbot = 0.f;
#pragma unroll
    for (int it = 0; it < NPOOL; ++it) {
        float m = wave_max64_dpp(fmaxf(fmaxf(s[0], s[1]), fmaxf(s[2], s[3])));
        stop += m;
        unsigned mb = __builtin_bit_cast(unsigned, m);
#pragma unroll
        for (int q = 0; q < 4; q++)
            s[q] = (__builtin_bit_cast(unsigned, s[q]) == mb) ? -INFINITY : s[q];

        float n = wave_min64_dpp(fminf(fminf(t[0], t[1]), fminf(t[2], t[3])));
        sbot += n;
        unsigned nb = __builtin_bit_cast(unsigned, n);
#pragma unroll
        for (int q = 0; q < 4; q++)
            t[q] = (__builtin_bit_cast(unsigned, t[q]) == nb) ? INFINITY : t[q];
    }
    if (lane == 0) hpool[wid] = (stop + sbot) / 15.0f;
}

// ---------------- x = hpool @ fc_w.T + fc_b ----------------
__global__ void x_kernel(const float* __restrict__ hpool, const float* __restrict__ fc_w,
                         const float* __restrict__ fc_b, float* __restrict__ x_out) {
    int o = blockIdx.x;
    int lane = threadIdx.x;  // 64
    float acc[IMGS];
#pragma unroll
    for (int i = 0; i < IMGS; i++) acc[i] = 0.f;
    const float* wrow = fc_w + (size_t)o * EMB;
    for (int e = lane; e < EMB; e += 64) {
        float wv = wrow[e];
#pragma unroll
        for (int i = 0; i < IMGS; i++) acc[i] += hpool[i * EMB + e] * wv;
    }
#pragma unroll
    for (int i = 0; i < IMGS; i++) {
#pragma unroll
        for (int s = 32; s > 0; s >>= 1) acc[i] += __shfl_xor(acc[i], s, 64);
    }
    if (lane == 0) {
        float bo = fc_b[o];
#pragma unroll
        for (int i = 0; i < IMGS; i++) x_out[i * EMB + o] = acc[i] + bo;
    }
}

// ---------------- topk v4: radix select with parallel bucket scan ----------------
__global__ __launch_bounds__(256) void topk_kernel(const float* __restrict__ caps,
                                                   int* __restrict__ idxs,
                                                   float* __restrict__ vals) {
    __shared__ float rowf[EMB];
    __shared__ unsigned hist[4][256];
    __shared__ unsigned scanbuf[256];
    __shared__ unsigned cnts[256];
    __shared__ ull sprefix;
    __shared__ int srank;
    int c = blockIdx.x;
    int tid = threadIdx.x;
    const float4* src = (const float4*)(caps + (size_t)c * EMB);
    for (int j = tid; j < EMB / 4; j += 256) {
        float4 v = src[j];
        *(float4*)&rowf[j * 4] = v;
    }
    if (tid == 0) { sprefix = 0ull; srank = ATTK; }

#pragma unroll 1
    for (int pass = 0; pass < 6; ++pass) {
        __syncthreads();
        ull pref = sprefix;
        int rk = srank;
        int shift = 40 - pass * 8;
        ull pmaskhi = (pass == 0) ? 0ull : ~((1ull << (shift + 8)) - 1ull);
        hist[0][tid] = 0; hist[1][tid] = 0; hist[2][tid] = 0; hist[3][tid] = 0;
        __syncthreads();
        unsigned* myhist = hist[tid >> 6];
#pragma unroll 1
        for (int s = 0; s < 10; s++) {
            int e = tid + s * 256;
            if (e < EMB) {
                ull key = ((ull)f2sort(rowf[e]) << 16) | ((unsigned)(2399 - e) << 4);
                if ((key & pmaskhi) == pref)
                    atomicAdd(&myhist[(unsigned)(key >> shift) & 255u], 1u);
            }
        }
        __syncthreads();
        unsigned h = hist[0][tid] + hist[1][tid] + hist[2][tid] + hist[3][tid];
        scanbuf[255 - tid] = h;
        __syncthreads();
#pragma unroll
        for (int d = 1; d < 256; d <<= 1) {
            unsigned add = (tid >= d) ? scanbuf[tid - d] : 0u;
            __syncthreads();
            scanbuf[tid] += add;
            __syncthreads();
        }
        unsigned incl = scanbuf[255 - tid];
        unsigned excl = incl - h;
        if (h > 0u && excl < (unsigned)rk && incl >= (unsigned)rk) {
            srank = rk - (int)excl;
            sprefix = pref | ((ull)tid << shift);
        }
    }
    __syncthreads();
    ull T = sprefix;
    unsigned selmask = 0, cnt = 0;
#pragma unroll 1
    for (int s = 0; s < 10; s++) {
        int e = tid + s * 256;
        if (e < EMB) {
            ull key = ((ull)f2sort(rowf[e]) << 16) | ((unsigned)(2399 - e) << 4);
            if (key >= T) { selmask |= 1u << s; cnt++; }
        }
    }
    cnts[tid] = cnt;
    __syncthreads();
#pragma unroll
    for (int d = 1; d < 256; d <<= 1) {
        unsigned add = (tid >= d) ? cnts[tid - d] : 0u;
        __syncthreads();
        cnts[tid] += add;
        __syncthreads();
    }
    unsigned slot = cnts[tid] - cnt;
#pragma unroll 1
    for (int s = 0; s < 10; s++) {
        if (selmask & (1u << s)) {
            int e = tid + s * 256;
            idxs[c * ATTK + slot] = e;
            vals[c * ATTK + slot] = fabsf(rowf[e]);
            slot++;
        }
    }
}

// ---------------- fc_w fp32 -> bf16 row-major copy ----------------
__global__ void convert_w_kernel(const float* __restrict__ w, unsigned short* __restrict__ wbf) {
    int i = (blockIdx.x * 256 + threadIdx.x) * 4;
    if (i >= EMB * EMB) return;
    float4 a = *(const float4*)&w[i];
    ushort4 r;
    r.x = f2bf(a.x); r.y = f2bf(a.y); r.z = f2bf(a.z); r.w = f2bf(a.w);
    *(ushort4*)&wbf[i] = r;
}

// ---------------- gbf[i][e][KPAD] = bf16(g[i][e][hw]), zero-padded ----------------
__global__ __launch_bounds__(256) void convert_g_kernel(const float* __restrict__ g,
                                                        unsigned short* __restrict__ gbf) {
    int row = blockIdx.x * 4 + (threadIdx.x >> 6);
    int l = threadIdx.x & 63;
    const float* src = g + (size_t)row * HW;
    unsigned short* dst = gbf + (size_t)row * KPAD;
    if (l < KPAD / 4) {
        ushort4 o = {0, 0, 0, 0};
        if (l < HW / 4) {
            float4 v = ((const float4*)src)[l];
            o.x = f2bf(v.x); o.y = f2bf(v.y); o.z = f2bf(v.z); o.w = f2bf(v.w);
        }
        ((ushort4*)dst)[l] = o;
    }
}

// ---------------- gT[n][e] = bf16(g[i(n)][e][hw(n)]) ----------------
__global__ void transpose_g_kernel(const float* __restrict__ g, unsigned short* __restrict__ gT) {
    __shared__ float t[96][50];
    int i = blockIdx.z;
    int e0 = blockIdx.y * 96;
    int h0 = blockIdx.x * 49;
    int tid = threadIdx.x;
    for (int f = tid; f < 96 * 49; f += 256) {
        int e = f / 49, hh = f % 49;
        t[e][hh] = g[(size_t)i * EMB * HW + (size_t)(e0 + e) * HW + h0 + hh];
    }
    __syncthreads();
    for (int f = tid; f < 49 * 96; f += 256) {
        int hh = f / 96, e = f % 96;
        gT[(size_t)(i * HW + h0 + hh) * EMB + e0 + e] = f2bf(t[e][hh]);
    }
}

// ======== NT bf16 MFMA GEMM, gll staging, 3-buffer COUNTED-vmcnt pipeline (T4) ========
// r9 lesson (regime gate): 2-phase __syncthreads drains vmcnt(0) per K-step -> load
// latency on critical path; T2 swizzle alone was null. Fix: 3 LDS buffers, raw
// s_barrier, and counted `s_waitcnt vmcnt(4)` so tile t+1's loads stay in flight
// across the barrier (T4). Uniform per-wave load count (4) via ROWS 224->RPAD 256
// (2 dummy calls/wave re-read tile row 0 into scratch LDS rows). Swizzle (T2, r9)
// kept: zero-conflict ds_reads now ON the critical path.
template <int MF, int NF, int OUT_MODE>
__global__ __launch_bounds__(256) void gemm_gll(const unsigned short* __restrict__ A,
                                                const unsigned short* __restrict__ B,
                                                void* __restrict__ outp,
                                                int M, int N, int K, int kper,
                                                long az, long bz) {
    constexpr int BM = MF * 32, BN = NF * 32;
    constexpr int ROWS = BM + BN;               // 224 for (5,2)/(2,5)
    constexpr int RPAD = (ROWS + 63) & ~63;     // 256: NCALL%4==0 -> 4 loads/wave/tile
    constexpr int NCALL = RPAD / 16;            // 16
    __shared__ unsigned short lds[3][RPAD][32];
    int m0 = blockIdx.y * BM, n0 = blockIdx.x * BN;
    int z = blockIdx.z;
    const unsigned short* Ab = A + (size_t)z * az;
    const unsigned short* Bb = B + (size_t)z * bz;
    int kb = (az == 0 && bz == 0) ? z * kper : 0;
    int nt = kper / 32;
    int tid = threadIdx.x, w = tid >> 6, lane = tid & 63;
    int wm = (w >> 1) * (MF * 16), wn = (w & 1) * (NF * 16);
    int ln = lane & 15;
    // T2 read slot (r9): chunk q=(lane>>4) stored at slot q^((row>>1)&3)
    int ks = (((lane >> 4) ^ ((lane >> 1) & 3))) * 8;
    int srow = lane >> 2;
    // T2 store source chunk: (l&3)^((l>>3)&3)
    int skc = (((lane & 3) ^ ((lane >> 3) & 3))) * 8;

    auto STAGE = [&](int buf, int t) {
        int k0 = kb + t * 32;
#pragma unroll
        for (int j = 0; j < NCALL / 4; j++) {
            int jj = w + j * 4;
            int r = jj * 16 + srow;
            const unsigned short* src;
            if (r < BM) src = Ab + (size_t)(m0 + r) * K + k0 + skc;
            else if (r < ROWS) src = Bb + (size_t)(n0 + r - BM) * K + k0 + skc;
            else src = Ab + (size_t)m0 * K + k0 + skc;  // dummy (uniform vmcnt), L2-hit
            __builtin_amdgcn_global_load_lds((gas1_t)(const void*)src,
                                             (las3_t)(void*)&lds[buf][jj * 16][0], 16, 0, 0);
        }
    };

    STAGE(0, 0);
    if (nt > 1) STAGE(1, 1);
    f32x4 acc[MF][NF] = {};
    for (int t = 0; t < nt; ++t) {
        // wait: tile t's 4 loads done; tile t+1's 4 may remain in flight. lgkm: my
        // ds_reads of t-1 retired (so post-barrier buffer overwrite is safe).
        if (t + 1 < nt) {
            asm volatile("s_waitcnt vmcnt(4) lgkmcnt(0)" ::: "memory");
        } else {
            asm volatile("s_waitcnt vmcnt(0) lgkmcnt(0)" ::: "memory");
        }
        __builtin_amdgcn_s_barrier();
        __builtin_amdgcn_sched_barrier(0);  // rule #18: no ds_read hoisting above wait
        if (t + 2 < nt) STAGE((t + 2) % 3, t + 2);
        const unsigned short(*buf)[32] = lds[t % 3];
        short8 af[MF], bfv[NF];
#pragma unroll
        for (int mf = 0; mf < MF; mf++)
            af[mf] = *(const short8*)&buf[wm + mf * 16 + ln][ks];
#pragma unroll
        for (int nf = 0; nf < NF; nf++)
            bfv[nf] = *(const short8*)&buf[BM + wn + nf * 16 + ln][ks];
#pragma unroll
        for (int mf = 0; mf < MF; mf++)
#pragma unroll
            for (int nf = 0; nf < NF; nf++)
                acc[mf][nf] = __builtin_amdgcn_mfma_f32_16x16x32_bf16(af[mf], bfv[nf],
                                                                      acc[mf][nf], 0, 0, 0);
    }
#pragma unroll
    for (int mf = 0; mf < MF; mf++) {
#pragma unroll
        for (int nf = 0; nf < NF; nf++) {
#pragma unroll
            for (int rr = 0; rr < 4; rr++) {
                int row = m0 + wm + mf * 16 + (lane >> 4) * 4 + rr;
                int col = n0 + wn + nf * 16 + ln;
                float v = acc[mf][nf][rr];
                if (OUT_MODE == 0) {
                    ((unsigned short*)outp)[(size_t)row * N + col] = f2bf(fabsf(v));
                } else if (OUT_MODE == 2) {
                    ((float*)outp)[(size_t)z * M * N + (size_t)row * N + col] = v;
                } else {
                    ((unsigned short*)outp)[(size_t)z * M * N + (size_t)row * N + col] = f2bf(v);
                }
            }
        }
    }
}

// ======== fallback reg-staged NT GEMM (used only if ws too small for wbf) ========
__device__ inline uint4 load8(const unsigned short* p) { return *(const uint4*)p; }
__device__ inline uint4 load8(const float* p) {
    float4 a = *(const float4*)p;
    float4 b = *(const float4*)(p + 4);
    uint4 r;
    r.x = (unsigned)f2bf(a.x) | ((unsigned)f2bf(a.y) << 16);
    r.y = (unsigned)f2bf(a.z) | ((unsigned)f2bf(a.w) << 16);
    r.z = (unsigned)f2bf(b.x) | ((unsigned)f2bf(b.y) << 16);
    r.w = (unsigned)f2bf(b.z) | ((unsigned)f2bf(b.w) << 16);
    return r;
}

template <int MF, int NF, int OUT_MODE, typename TA, typename TB>
__global__ __launch_bounds__(256) void mfma_gemm_nt(const TA* __restrict__ A,
                                                    const TB* __restrict__ B,
                                                    const float* __restrict__ bias,
                                                    void* __restrict__ outp,
                                                    int M, int N, int K, int kper) {
    constexpr int BM = MF * 32, BN = NF * 32;
    constexpr int nA = BM * 4, nTot = (BM + BN) * 4;
    constexpr int NCH = (nTot + 255) / 256;
    __shared__ unsigned short As[BM][40];
    __shared__ unsigned short Bs[BN][40];
    int m0 = blockIdx.y * BM, n0 = blockIdx.x * BN;
    int sk = blockIdx.z;
    int kb = sk * kper, ke = kb + kper;
    int tid = threadIdx.x;
    int w = tid >> 6, lane = tid & 63;
    int wm = (w >> 1) * (MF * 16), wn = (w & 1) * (NF * 16);
    int ln = lane & 15, ks = (lane >> 4) * 8;
    uint4 r[NCH];
#pragma unroll
    for (int j = 0; j < NCH; j++) {
        int c = tid + 256 * j;
        if (c < nTot) {
            if (c < nA) {
                int row = c >> 2, kc = c & 3;
                r[j] = load8(A + (size_t)(m0 + row) * K + kb + kc * 8);
            } else {
                int cc = c - nA, row = cc >> 2, kc = cc & 3;
                r[j] = load8(B + (size_t)(n0 + row) * K + kb + kc * 8);
            }
        }
    }
    f32x4 acc[MF][NF] = {};
    for (int k0 = kb; k0 < ke; k0 += 32) {
#pragma unroll
        for (int j = 0; j < NCH; j++) {
            int c = tid + 256 * j;
            if (c < nTot) {
                if (c < nA) {
                    int row = c >> 2, kc = c & 3;
                    *(uint4*)&As[row][kc * 8] = r[j];
                } else {
                    int cc = c - nA, row = cc >> 2, kc = cc & 3;
                    *(uint4*)&Bs[row][kc * 8] = r[j];
                }
            }
        }
        __syncthreads();
        if (k0 + 32 < ke) {
#pragma unroll
            for (int j = 0; j < NCH; j++) {
                int c = tid + 256 * j;
                if (c < nTot) {
                    if (c < nA) {
                        int row = c >> 2, kc = c & 3;
                        r[j] = load8(A + (size_t)(m0 + row) * K + (k0 + 32) + kc * 8);
                    } else {
                        int cc = c - nA, row = cc >> 2, kc = cc & 3;
                        r[j] = load8(B + (size_t)(n0 + row) * K + (k0 + 32) + kc * 8);
                    }
                }
            }
        }
        short8 af[MF], bfv[NF];
#pragma unroll
        for (int mf = 0; mf < MF; mf++)
            af[mf] = *(const short8*)&As[wm + mf * 16 + ln][ks];
#pragma unroll
        for (int nf = 0; nf < NF; nf++)
            bfv[nf] = *(const short8*)&Bs[wn + nf * 16 + ln][ks];
#pragma unroll
        for (int mf = 0; mf < MF; mf++)
#pragma unroll
            for (int nf = 0; nf < NF; nf++)
                acc[mf][nf] = __builtin_amdgcn_mfma_f32_16x16x32_bf16(af[mf], bfv[nf],
                                                                      acc[mf][nf], 0, 0, 0);
        __syncthreads();
    }
#pragma unroll
    for (int mf = 0; mf < MF; mf++) {
#pragma unroll
        for (int nf = 0; nf < NF; nf++) {
#pragma unroll
            for (int rr = 0; rr < 4; rr++) {
                int row = m0 + wm + mf * 16 + (lane >> 4) * 4 + rr;
                int col = n0 + wn + nf * 16 + ln;
                float v = acc[mf][nf][rr];
                if (OUT_MODE == 0) {
                    ((unsigned short*)outp)[(size_t)row * N + col] = f2bf(fabsf(v));
                } else if (OUT_MODE == 2) {
                    ((float*)outp)[(size_t)sk * M * N + (size_t)row * N + col] = v;
                }
            }
        }
    }
}

// ---------------- reduce 3 split-K partials + bias -> xa_out ----------------
__global__ void reduce3_kernel(const float* __restrict__ p, const float* __restrict__ bias,
                               float* __restrict__ out) {
    int i = (blockIdx.x * 256 + threadIdx.x) * 4;
    if (i >= IMGS * CAPS * EMB) return;
    float4 a = *(const float4*)&p[i];
    float4 b = *(const float4*)&p[i + IMGS * CAPS * EMB];
    float4 c = *(const float4*)&p[i + 2 * IMGS * CAPS * EMB];
    float4 bb = *(const float4*)&bias[i % EMB];
    float4 r = {a.x + b.x + c.x + bb.x, a.y + b.y + c.y + bb.y,
                a.z + b.z + c.z + bb.z, a.w + b.w + c.w + bb.w};
    *(float4*)&out[i] = r;
}

// ---------------- heat: H[c,n] = sum_j vals[c,j] * Abf[idx[c,j], n] ----------------
__global__ void heat_kernel(const int* __restrict__ idxs, const float* __restrict__ vals,
                            const unsigned short* __restrict__ A, float* __restrict__ H) {
    __shared__ int sidx[ATTK];
    __shared__ float sval[ATTK];
    int c = blockIdx.y;
    int tid = threadIdx.x;
    if (tid < ATTK) {
        sidx[tid] = idxs[c * ATTK + tid];
        sval[tid] = vals[c * ATTK + tid];
    }
    __syncthreads();
    int n = (blockIdx.x * 256 + tid) * 4;
    if (n >= NCOLS) return;
    float a0 = 0.f, a1 = 0.f, a2 = 0.f, a3 = 0.f;
    for (int j = 0; j < ATTK; j++) {
        uint2 p = *(const uint2*)&A[(size_t)sidx[j] * NCOLS + n];
        float sv = sval[j];
        a0 += sv * bf2f(p.x & 0xffffu);
        a1 += sv * bf2f(p.x >> 16);
        a2 += sv * bf2f(p.y & 0xffffu);
        a3 += sv * bf2f(p.y >> 16);
    }
    float4 r = {a0, a1, a2, a3};
    *(float4*)&H[(size_t)c * NCOLS + n] = r;
}

// ---------------- norm: Hbf[i][c][KPAD] = bf16(H / rowsum), zero-padded ----------------
__global__ void norm_kernel(const float* __restrict__ H, unsigned short* __restrict__ Hbf) {
    int c = blockIdx.x / IMGS, i = blockIdx.x % IMGS;
    const float* p = H + (size_t)c * NCOLS + i * HW;
    int lane = threadIdx.x;  // 64
    float s = 0.f;
    for (int hw = lane; hw < HW; hw += 64) s += p[hw];
#pragma unroll
    for (int d = 32; d > 0; d >>= 1) s += __shfl_xor(s, d, 64);
    float inv = 1.0f / s;
    unsigned short* dst = Hbf + ((size_t)i * CAPS + c) * KPAD;
    for (int hw = lane; hw < KPAD; hw += 64)
        dst[hw] = (hw < HW) ? f2bf(p[hw] * inv) : (unsigned short)0;
}

extern "C" void kernel_launch(void* const* d_in, const int* in_sizes, int n_in,
                              void* d_out, int out_size, void* d_ws, size_t ws_size,
                              hipStream_t stream) {
    const float* g = (const float*)d_in[0];
    const float* caps = (const float*)d_in[1];
    const float* fc_w = (const float*)d_in[2];
    const float* fc_b = (const float*)d_in[3];

    float* out = (float*)d_out;
    float* x_out = out;                    // 38400
    float* xa_out = out + 38400;           // 2457600
    float* g_out = out + 38400 + 2457600;  // 7526400 floats = 30.1 MB scratch until final copy
    unsigned short* Abf = (unsigned short*)g_out;
    unsigned short* gT = Abf + (size_t)EMB * NCOLS;
    unsigned short* gbf = (unsigned short*)g_out;
    unsigned short* Hbf = gbf + (size_t)IMGS * EMB * KPAD;
    float* Ppart = g_out;

    float* ws = (float*)d_ws;
    float* hpool = ws;                                      // 38400 f
    int* idxs = (int*)(ws + 38400);                         // 11520
    float* vals = ws + 49920;                               // 11520
    float* H = ws + 61440;                                  // 200704 f
    unsigned short* Pbf = (unsigned short*)(ws + 262144);   // ends byte 5963776
    unsigned short* wbf = (unsigned short*)(ws + 1490944);  // ends byte 17483776
    bool use_wbf = ws_size >= (size_t)17483776;

    weldon_kernel<<<(IMGS * EMB) / 4, 256, 0, stream>>>(g, hpool);
    x_kernel<<<EMB, 64, 0, stream>>>(hpool, fc_w, fc_b, x_out);
    topk_kernel<<<CAPS, 256, 0, stream>>>(caps, idxs, vals);
    transpose_g_kernel<<<dim3(4, 25, IMGS), 256, 0, stream>>>(g, gT);

    if (use_wbf) {
        convert_w_kernel<<<(EMB * EMB / 4 + 255) / 256, 256, 0, stream>>>(fc_w, wbf);
        gemm_gll<5, 2, 0><<<dim3(NCOLS / 64, EMB / 160, 1), 256, 0, stream>>>(
            wbf, gT, Abf, EMB, NCOLS, EMB, EMB, 0, 0);
    } else {
        mfma_gemm_nt<5, 2, 0, float, unsigned short>
            <<<dim3(NCOLS / 64, EMB / 160), 256, 0, stream>>>(fc_w, gT, nullptr, Abf,
                                                              EMB, NCOLS, EMB, EMB);
    }
    heat_kernel<<<dim3((NCOLS / 4 + 255) / 256, CAPS), 256, 0, stream>>>(idxs, vals, Abf, H);
    norm_kernel<<<CAPS * IMGS, 64, 0, stream>>>(H, Hbf);
    convert_g_kernel<<<(IMGS * EMB) / 4, 256, 0, stream>>>(g, gbf);
    gemm_gll<2, 5, 3><<<dim3(EMB / 160, 1, IMGS), 256, 0, stream>>>(
        Hbf, gbf, Pbf, CAPS, EMB, KPAD, KPAD, (long)CAPS * KPAD, (long)EMB * KPAD);
    if (use_wbf) {
        gemm_gll<2, 5, 2><<<dim3(EMB / 160, (IMGS * CAPS) / 64, 3), 256, 0, stream>>>(
            Pbf, wbf, Ppart, IMGS * CAPS, EMB, EMB, 800, 0, 0);
    } else {
        mfma_gemm_nt<2, 3, 2, unsigned short, float>
            <<<dim3(EMB / 96, (IMGS * CAPS) / 64, 3), 256, 0, stream>>>(Pbf, fc_w, nullptr, Ppart,
                                                                        IMGS * CAPS, EMB, EMB, 800);
    }
    reduce3_kernel<<<(IMGS * CAPS * EMB / 4) / 256, 256, 0, stream>>>(Ppart, fc_b, xa_out);
    hipMemcpyAsync(g_out, g, sizeof(float) * (size_t)IMGS * EMB * HW,
                   hipMemcpyDeviceToDevice, stream);
}

// Round 11
// 270.500 us; speedup vs baseline: 1.0203x; 1.0185x over previous
//
#include <hip/hip_runtime.h>
#include <math.h>

#define IMGS 16
#define EMB 2400
#define HW 196
#define CAPS 64
#define ATTK 180
#define NPOOL 15
#define NCOLS (IMGS * HW)  // 3136
#define KPAD 224           // 196 padded to multiple of 32

typedef __attribute__((ext_vector_type(8))) short short8;
typedef __attribute__((ext_vector_type(4))) float f32x4;
typedef const __attribute__((address_space(1))) unsigned int* gas1_t;
typedef __attribute__((address_space(3))) unsigned int* las3_t;
typedef unsigned long long ull;

__device__ inline unsigned short f2bf(float f) {
    unsigned int u = __builtin_bit_cast(unsigned int, f);
    u += 0x7fffu + ((u >> 16) & 1u);  // round-to-nearest-even
    return (unsigned short)(u >> 16);
}
__device__ inline float bf2f(unsigned int lo16) {
    return __builtin_bit_cast(float, lo16 << 16);
}
__device__ inline unsigned f2sort(float f) {
    unsigned u = __builtin_bit_cast(unsigned, f);
    int msk = ((int)u) >> 31;
    return u ^ (unsigned)(msk | 0x80000000);
}

// ---- DPP 64-lane reductions (rocPRIM pattern) ----
__device__ inline float wave_max64_dpp(float v) {
    int x = __builtin_bit_cast(int, v);
#define STEPMX(c)                                                              \
    {                                                                          \
        int y = __builtin_amdgcn_update_dpp(x, x, c, 0xf, 0xf, false);         \
        float a = fmaxf(__builtin_bit_cast(float, x), __builtin_bit_cast(float, y)); \
        x = __builtin_bit_cast(int, a);                                        \
    }
    STEPMX(0x111) STEPMX(0x112) STEPMX(0x114) STEPMX(0x118) STEPMX(0x142) STEPMX(0x143)
#undef STEPMX
    return __builtin_bit_cast(float, __builtin_amdgcn_readlane(x, 63));
}
__device__ inline float wave_min64_dpp(float v) {
    int x = __builtin_bit_cast(int, v);
#define STEPMN(c)                                                              \
    {                                                                          \
        int y = __builtin_amdgcn_update_dpp(x, x, c, 0xf, 0xf, false);         \
        float a = fminf(__builtin_bit_cast(float, x), __builtin_bit_cast(float, y)); \
        x = __builtin_bit_cast(int, a);                                        \
    }
    STEPMN(0x111) STEPMN(0x112) STEPMN(0x114) STEPMN(0x118) STEPMN(0x142) STEPMN(0x143)
#undef STEPMN
    return __builtin_bit_cast(float, __builtin_amdgcn_readlane(x, 63));
}

// ---------------- Weldon pooling v4: DPP reduce + unique-id floats ----------------
__global__ __launch_bounds__(256) void weldon_kernel(const float* __restrict__ g,
                                                     float* __restrict__ hpool) {
    int wid = (blockIdx.x * 256 + threadIdx.x) >> 6;
    int lane = threadIdx.x & 63;
    const float* row = g + (size_t)wid * HW;
    float s[4], t[4];
#pragma unroll
    for (int q = 0; q < 4; q++) {
        int e = lane + 64 * q;
        if (e < HW) {
            unsigned u = __builtin_bit_cast(unsigned, row[e]);
            u = (u & 0xFFFFFF00u) | (unsigned)(q * 64 + lane);
            float f = __builtin_bit_cast(float, u);
            s[q] = f;
            t[q] = f;
        } else {
            s[q] = -INFINITY;
            t[q] = INFINITY;
        }
    }
    float stop = 0.f, sbot = 0.f;
#pragma unroll
    for (int it = 0; it < NPOOL; ++it) {
        float m = wave_max64_dpp(fmaxf(fmaxf(s[0], s[1]), fmaxf(s[2], s[3])));
        stop += m;
        unsigned mb = __builtin_bit_cast(unsigned, m);
#pragma unroll
        for (int q = 0; q < 4; q++)
            s[q] = (__builtin_bit_cast(unsigned, s[q]) == mb) ? -INFINITY : s[q];

        float n = wave_min64_dpp(fminf(fminf(t[0], t[1]), fminf(t[2], t[3])));
        sbot += n;
        unsigned nb = __builtin_bit_cast(unsigned, n);
#pragma unroll
        for (int q = 0; q < 4; q++)
            t[q] = (__builtin_bit_cast(unsigned, t[q]) == nb) ? INFINITY : t[q];
    }
    if (lane == 0) hpool[wid] = (stop + sbot) / 15.0f;
}

// ---------------- x = hpool @ fc_w.T + fc_b ----------------
__global__ void x_kernel(const float* __restrict__ hpool, const float* __restrict__ fc_w,
                         const float* __restrict__ fc_b, float* __restrict__ x_out) {
    int o = blockIdx.x;
    int lane = threadIdx.x;  // 64
    float acc[IMGS];
#pragma unroll
    for (int i = 0; i < IMGS; i++) acc[i] = 0.f;
    const float* wrow = fc_w + (size_t)o * EMB;
    for (int e = lane; e < EMB; e += 64) {
        float wv = wrow[e];
#pragma unroll
        for (int i = 0; i < IMGS; i++) acc[i] += hpool[i * EMB + e] * wv;
    }
#pragma unroll
    for (int i = 0; i < IMGS; i++) {
#pragma unroll
        for (int s = 32; s > 0; s >>= 1) acc[i] += __shfl_xor(acc[i], s, 64);
    }
    if (lane == 0) {
        float bo = fc_b[o];
#pragma unroll
        for (int i = 0; i < IMGS; i++) x_out[i * EMB + o] = acc[i] + bo;
    }
}

// ---------------- topk v4: radix select with parallel bucket scan ----------------
__global__ __launch_bounds__(256) void topk_kernel(const float* __restrict__ caps,
                                                   int* __restrict__ idxs,
                                                   float* __restrict__ vals) {
    __shared__ float rowf[EMB];
    __shared__ unsigned hist[4][256];
    __shared__ unsigned scanbuf[256];
    __shared__ unsigned cnts[256];
    __shared__ ull sprefix;
    __shared__ int srank;
    int c = blockIdx.x;
    int tid = threadIdx.x;
    const float4* src = (const float4*)(caps + (size_t)c * EMB);
    for (int j = tid; j < EMB / 4; j += 256) {
        float4 v = src[j];
        *(float4*)&rowf[j * 4] = v;
    }
    if (tid == 0) { sprefix = 0ull; srank = ATTK; }

#pragma unroll 1
    for (int pass = 0; pass < 6; ++pass) {
        __syncthreads();
        ull pref = sprefix;
        int rk = srank;
        int shift = 40 - pass * 8;
        ull pmaskhi = (pass == 0) ? 0ull : ~((1ull << (shift + 8)) - 1ull);
        hist[0][tid] = 0; hist[1][tid] = 0; hist[2][tid] = 0; hist[3][tid] = 0;
        __syncthreads();
        unsigned* myhist = hist[tid >> 6];
#pragma unroll 1
        for (int s = 0; s < 10; s++) {
            int e = tid + s * 256;
            if (e < EMB) {
                ull key = ((ull)f2sort(rowf[e]) << 16) | ((unsigned)(2399 - e) << 4);
                if ((key & pmaskhi) == pref)
                    atomicAdd(&myhist[(unsigned)(key >> shift) & 255u], 1u);
            }
        }
        __syncthreads();
        unsigned h = hist[0][tid] + hist[1][tid] + hist[2][tid] + hist[3][tid];
        scanbuf[255 - tid] = h;
        __syncthreads();
#pragma unroll
        for (int d = 1; d < 256; d <<= 1) {
            unsigned add = (tid >= d) ? scanbuf[tid - d] : 0u;
            __syncthreads();
            scanbuf[tid] += add;
            __syncthreads();
        }
        unsigned incl = scanbuf[255 - tid];
        unsigned excl = incl - h;
        if (h > 0u && excl < (unsigned)rk && incl >= (unsigned)rk) {
            srank = rk - (int)excl;
            sprefix = pref | ((ull)tid << shift);
        }
    }
    __syncthreads();
    ull T = sprefix;
    unsigned selmask = 0, cnt = 0;
#pragma unroll 1
    for (int s = 0; s < 10; s++) {
        int e = tid + s * 256;
        if (e < EMB) {
            ull key = ((ull)f2sort(rowf[e]) << 16) | ((unsigned)(2399 - e) << 4);
            if (key >= T) { selmask |= 1u << s; cnt++; }
        }
    }
    cnts[tid] = cnt;
    __syncthreads();
#pragma unroll
    for (int d = 1; d < 256; d <<= 1) {
        unsigned add = (tid >= d) ? cnts[tid - d] : 0u;
        __syncthreads();
        cnts[tid] += add;
        __syncthreads();
    }
    unsigned slot = cnts[tid] - cnt;
#pragma unroll 1
    for (int s = 0; s < 10; s++) {
        if (selmask & (1u << s)) {
            int e = tid + s * 256;
            idxs[c * ATTK + slot] = e;
            vals[c * ATTK + slot] = fabsf(rowf[e]);
            slot++;
        }
    }
}

// ---------------- fc_w fp32 -> bf16 row-major copy ----------------
__global__ void convert_w_kernel(const float* __restrict__ w, unsigned short* __restrict__ wbf) {
    int i = (blockIdx.x * 256 + threadIdx.x) * 4;
    if (i >= EMB * EMB) return;
    float4 a = *(const float4*)&w[i];
    ushort4 r;
    r.x = f2bf(a.x); r.y = f2bf(a.y); r.z = f2bf(a.z); r.w = f2bf(a.w);
    *(ushort4*)&wbf[i] = r;
}

// ---------------- gbf[i][e][KPAD] = bf16(g[i][e][hw]), zero-padded ----------------
__global__ __launch_bounds__(256) void convert_g_kernel(const float* __restrict__ g,
                                                        unsigned short* __restrict__ gbf) {
    int row = blockIdx.x * 4 + (threadIdx.x >> 6);
    int l = threadIdx.x & 63;
    const float* src = g + (size_t)row * HW;
    unsigned short* dst = gbf + (size_t)row * KPAD;
    if (l < KPAD / 4) {
        ushort4 o = {0, 0, 0, 0};
        if (l < HW / 4) {
            float4 v = ((const float4*)src)[l];
            o.x = f2bf(v.x); o.y = f2bf(v.y); o.z = f2bf(v.z); o.w = f2bf(v.w);
        }
        ((ushort4*)dst)[l] = o;
    }
}

// ---------------- gT[n][e] = bf16(g[i(n)][e][hw(n)]) ----------------
__global__ void transpose_g_kernel(const float* __restrict__ g, unsigned short* __restrict__ gT) {
    __shared__ float t[96][50];
    int i = blockIdx.z;
    int e0 = blockIdx.y * 96;
    int h0 = blockIdx.x * 49;
    int tid = threadIdx.x;
    for (int f = tid; f < 96 * 49; f += 256) {
        int e = f / 49, hh = f % 49;
        t[e][hh] = g[(size_t)i * EMB * HW + (size_t)(e0 + e) * HW + h0 + hh];
    }
    __syncthreads();
    for (int f = tid; f < 49 * 96; f += 256) {
        int hh = f / 96, e = f % 96;
        gT[(size_t)(i * HW + h0 + hh) * EMB + e0 + e] = f2bf(t[e][hh]);
    }
}

// ======== NT bf16 MFMA GEMM, gll staging, 3-buffer counted-vmcnt pipeline ========
// r10 lesson: MfmaUtil pinned at 19% across 3 structural changes -> bytes-per-MFMA
// bound (LDS pipe AND L2/L3 panel re-fetch = 2KMN(1/BM+1/BN)). Fix: fatter tiles.
// gemm1 (3,7): traffic 790->537 MB, wave 21 MFMA : 10 ds_read (vs 10:7).
// gemm3 (4,5): 258->166 MB. LPW = loads/wave/tile is constexpr -> counted vmcnt.
// T2 source/read swizzle kept (r9, conflicts=0). T5 setprio around MFMA cluster.
template <int MF, int NF, int OUT_MODE>
__global__ __launch_bounds__(256) void gemm_gll(const unsigned short* __restrict__ A,
                                                const unsigned short* __restrict__ B,
                                                void* __restrict__ outp,
                                                int M, int N, int K, int kper,
                                                long az, long bz) {
    constexpr int BM = MF * 32, BN = NF * 32;
    constexpr int ROWS = BM + BN;
    constexpr int RPAD = (ROWS + 63) & ~63;  // NCALL%4==0 -> uniform loads/wave
    constexpr int NCALL = RPAD / 16;
    constexpr int LPW = NCALL / 4;           // loads per wave per tile
    __shared__ unsigned short lds[3][RPAD][32];
    int m0 = blockIdx.y * BM, n0 = blockIdx.x * BN;
    int z = blockIdx.z;
    const unsigned short* Ab = A + (size_t)z * az;
    const unsigned short* Bb = B + (size_t)z * bz;
    int kb = (az == 0 && bz == 0) ? z * kper : 0;
    int nt = kper / 32;
    int tid = threadIdx.x, w = tid >> 6, lane = tid & 63;
    int wm = (w >> 1) * (MF * 16), wn = (w & 1) * (NF * 16);
    int ln = lane & 15;
    int ks = (((lane >> 4) ^ ((lane >> 1) & 3))) * 8;   // T2 read slot
    int srow = lane >> 2;
    int skc = (((lane & 3) ^ ((lane >> 3) & 3))) * 8;   // T2 source chunk

    auto STAGE = [&](int buf, int t) {
        int k0 = kb + t * 32;
#pragma unroll
        for (int j = 0; j < LPW; j++) {
            int jj = w + j * 4;
            int r = jj * 16 + srow;
            const unsigned short* src;
            if (r < BM) src = Ab + (size_t)(m0 + r) * K + k0 + skc;
            else if (r < ROWS) src = Bb + (size_t)(n0 + r - BM) * K + k0 + skc;
            else src = Ab + (size_t)m0 * K + k0 + skc;  // dummy (uniform vmcnt), L2-hit
            __builtin_amdgcn_global_load_lds((gas1_t)(const void*)src,
                                             (las3_t)(void*)&lds[buf][jj * 16][0], 16, 0, 0);
        }
    };

    STAGE(0, 0);
    if (nt > 1) STAGE(1, 1);
    f32x4 acc[MF][NF] = {};
    for (int t = 0; t < nt; ++t) {
        // wait tile t's LPW loads; tile t+1's LPW may stay in flight (T4)
        if (t + 1 < nt) {
            if constexpr (LPW == 4) asm volatile("s_waitcnt vmcnt(4) lgkmcnt(0)" ::: "memory");
            else if constexpr (LPW == 5) asm volatile("s_waitcnt vmcnt(5) lgkmcnt(0)" ::: "memory");
            else if constexpr (LPW == 6) asm volatile("s_waitcnt vmcnt(6) lgkmcnt(0)" ::: "memory");
            else asm volatile("s_waitcnt vmcnt(0) lgkmcnt(0)" ::: "memory");
        } else {
            asm volatile("s_waitcnt vmcnt(0) lgkmcnt(0)" ::: "memory");
        }
        __builtin_amdgcn_s_barrier();
        __builtin_amdgcn_sched_barrier(0);  // rule #18
        if (t + 2 < nt) STAGE((t + 2) % 3, t + 2);
        const unsigned short(*buf)[32] = lds[t % 3];
        short8 af[MF], bfv[NF];
#pragma unroll
        for (int mf = 0; mf < MF; mf++)
            af[mf] = *(const short8*)&buf[wm + mf * 16 + ln][ks];
#pragma unroll
        for (int nf = 0; nf < NF; nf++)
            bfv[nf] = *(const short8*)&buf[BM + wn + nf * 16 + ln][ks];
        __builtin_amdgcn_s_setprio(1);  // T5
#pragma unroll
        for (int mf = 0; mf < MF; mf++)
#pragma unroll
            for (int nf = 0; nf < NF; nf++)
                acc[mf][nf] = __builtin_amdgcn_mfma_f32_16x16x32_bf16(af[mf], bfv[nf],
                                                                      acc[mf][nf], 0, 0, 0);
        __builtin_amdgcn_s_setprio(0);
    }
#pragma unroll
    for (int mf = 0; mf < MF; mf++) {
#pragma unroll
        for (int nf = 0; nf < NF; nf++) {
#pragma unroll
            for (int rr = 0; rr < 4; rr++) {
                int row = m0 + wm + mf * 16 + (lane >> 4) * 4 + rr;
                int col = n0 + wn + nf * 16 + ln;
                float v = acc[mf][nf][rr];
                if (OUT_MODE == 0) {
                    ((unsigned short*)outp)[(size_t)row * N + col] = f2bf(fabsf(v));
                } else if (OUT_MODE == 2) {
                    ((float*)outp)[(size_t)z * M * N + (size_t)row * N + col] = v;
                } else {
                    ((unsigned short*)outp)[(size_t)z * M * N + (size_t)row * N + col] = f2bf(v);
                }
            }
        }
    }
}

// ======== fallback reg-staged NT GEMM (used only if ws too small for wbf) ========
__device__ inline uint4 load8(const unsigned short* p) { return *(const uint4*)p; }
__device__ inline uint4 load8(const float* p) {
    float4 a = *(const float4*)p;
    float4 b = *(const float4*)(p + 4);
    uint4 r;
    r.x = (unsigned)f2bf(a.x) | ((unsigned)f2bf(a.y) << 16);
    r.y = (unsigned)f2bf(a.z) | ((unsigned)f2bf(a.w) << 16);
    r.z = (unsigned)f2bf(b.x) | ((unsigned)f2bf(b.y) << 16);
    r.w = (unsigned)f2bf(b.z) | ((unsigned)f2bf(b.w) << 16);
    return r;
}

template <int MF, int NF, int OUT_MODE, typename TA, typename TB>
__global__ __launch_bounds__(256) void mfma_gemm_nt(const TA* __restrict__ A,
                                                    const TB* __restrict__ B,
                                                    const float* __restrict__ bias,
                                                    void* __restrict__ outp,
                                                    int M, int N, int K, int kper) {
    constexpr int BM = MF * 32, BN = NF * 32;
    constexpr int nA = BM * 4, nTot = (BM + BN) * 4;
    constexpr int NCH = (nTot + 255) / 256;
    __shared__ unsigned short As[BM][40];
    __shared__ unsigned short Bs[BN][40];
    int m0 = blockIdx.y * BM, n0 = blockIdx.x * BN;
    int sk = blockIdx.z;
    int kb = sk * kper, ke = kb + kper;
    int tid = threadIdx.x;
    int w = tid >> 6, lane = tid & 63;
    int wm = (w >> 1) * (MF * 16), wn = (w & 1) * (NF * 16);
    int ln = lane & 15, ks = (lane >> 4) * 8;
    uint4 r[NCH];
#pragma unroll
    for (int j = 0; j < NCH; j++) {
        int c = tid + 256 * j;
        if (c < nTot) {
            if (c < nA) {
                int row = c >> 2, kc = c & 3;
                r[j] = load8(A + (size_t)(m0 + row) * K + kb + kc * 8);
            } else {
                int cc = c - nA, row = cc >> 2, kc = cc & 3;
                r[j] = load8(B + (size_t)(n0 + row) * K + kb + kc * 8);
            }
        }
    }
    f32x4 acc[MF][NF] = {};
    for (int k0 = kb; k0 < ke; k0 += 32) {
#pragma unroll
        for (int j = 0; j < NCH; j++) {
            int c = tid + 256 * j;
            if (c < nTot) {
                if (c < nA) {
                    int row = c >> 2, kc = c & 3;
                    *(uint4*)&As[row][kc * 8] = r[j];
                } else {
                    int cc = c - nA, row = cc >> 2, kc = cc & 3;
                    *(uint4*)&Bs[row][kc * 8] = r[j];
                }
            }
        }
        __syncthreads();
        if (k0 + 32 < ke) {
#pragma unroll
            for (int j = 0; j < NCH; j++) {
                int c = tid + 256 * j;
                if (c < nTot) {
                    if (c < nA) {
                        int row = c >> 2, kc = c & 3;
                        r[j] = load8(A + (size_t)(m0 + row) * K + (k0 + 32) + kc * 8);
                    } else {
                        int cc = c - nA, row = cc >> 2, kc = cc & 3;
                        r[j] = load8(B + (size_t)(n0 + row) * K + (k0 + 32) + kc * 8);
                    }
                }
            }
        }
        short8 af[MF], bfv[NF];
#pragma unroll
        for (int mf = 0; mf < MF; mf++)
            af[mf] = *(const short8*)&As[wm + mf * 16 + ln][ks];
#pragma unroll
        for (int nf = 0; nf < NF; nf++)
            bfv[nf] = *(const short8*)&Bs[wn + nf * 16 + ln][ks];
#pragma unroll
        for (int mf = 0; mf < MF; mf++)
#pragma unroll
            for (int nf = 0; nf < NF; nf++)
                acc[mf][nf] = __builtin_amdgcn_mfma_f32_16x16x32_bf16(af[mf], bfv[nf],
                                                                      acc[mf][nf], 0, 0, 0);
        __syncthreads();
    }
#pragma unroll
    for (int mf = 0; mf < MF; mf++) {
#pragma unroll
        for (int nf = 0; nf < NF; nf++) {
#pragma unroll
            for (int rr = 0; rr < 4; rr++) {
                int row = m0 + wm + mf * 16 + (lane >> 4) * 4 + rr;
                int col = n0 + wn + nf * 16 + ln;
                float v = acc[mf][nf][rr];
                if (OUT_MODE == 0) {
                    ((unsigned short*)outp)[(size_t)row * N + col] = f2bf(fabsf(v));
                } else if (OUT_MODE == 2) {
                    ((float*)outp)[(size_t)sk * M * N + (size_t)row * N + col] = v;
                }
            }
        }
    }
}

// ---------------- reduce 3 split-K partials + bias -> xa_out ----------------
__global__ void reduce3_kernel(const float* __restrict__ p, const float* __restrict__ bias,
                               float* __restrict__ out) {
    int i = (blockIdx.x * 256 + threadIdx.x) * 4;
    if (i >= IMGS * CAPS * EMB) return;
    float4 a = *(const float4*)&p[i];
    float4 b = *(const float4*)&p[i + IMGS * CAPS * EMB];
    float4 c = *(const float4*)&p[i + 2 * IMGS * CAPS * EMB];
    float4 bb = *(const float4*)&bias[i % EMB];
    float4 r = {a.x + b.x + c.x + bb.x, a.y + b.y + c.y + bb.y,
                a.z + b.z + c.z + bb.z, a.w + b.w + c.w + bb.w};
    *(float4*)&out[i] = r;
}

// ---------------- heat: H[c,n] = sum_j vals[c,j] * Abf[idx[c,j], n] ----------------
__global__ void heat_kernel(const int* __restrict__ idxs, const float* __restrict__ vals,
                            const unsigned short* __restrict__ A, float* __restrict__ H) {
    __shared__ int sidx[ATTK];
    __shared__ float sval[ATTK];
    int c = blockIdx.y;
    int tid = threadIdx.x;
    if (tid < ATTK) {
        sidx[tid] = idxs[c * ATTK + tid];
        sval[tid] = vals[c * ATTK + tid];
    }
    __syncthreads();
    int n = (blockIdx.x * 256 + tid) * 4;
    if (n >= NCOLS) return;
    float a0 = 0.f, a1 = 0.f, a2 = 0.f, a3 = 0.f;
    for (int j = 0; j < ATTK; j++) {
        uint2 p = *(const uint2*)&A[(size_t)sidx[j] * NCOLS + n];
        float sv = sval[j];
        a0 += sv * bf2f(p.x & 0xffffu);
        a1 += sv * bf2f(p.x >> 16);
        a2 += sv * bf2f(p.y & 0xffffu);
        a3 += sv * bf2f(p.y >> 16);
    }
    float4 r = {a0, a1, a2, a3};
    *(float4*)&H[(size_t)c * NCOLS + n] = r;
}

// ---------------- norm: Hbf[i][c][KPAD] = bf16(H / rowsum), zero-padded ----------------
__global__ void norm_kernel(const float* __restrict__ H, unsigned short* __restrict__ Hbf) {
    int c = blockIdx.x / IMGS, i = blockIdx.x % IMGS;
    const float* p = H + (size_t)c * NCOLS + i * HW;
    int lane = threadIdx.x;  // 64
    float s = 0.f;
    for (int hw = lane; hw < HW; hw += 64) s += p[hw];
#pragma unroll
    for (int d = 32; d > 0; d >>= 1) s += __shfl_xor(s, d, 64);
    float inv = 1.0f / s;
    unsigned short* dst = Hbf + ((size_t)i * CAPS + c) * KPAD;
    for (int hw = lane; hw < KPAD; hw += 64)
        dst[hw] = (hw < HW) ? f2bf(p[hw] * inv) : (unsigned short)0;
}

extern "C" void kernel_launch(void* const* d_in, const int* in_sizes, int n_in,
                              void* d_out, int out_size, void* d_ws, size_t ws_size,
                              hipStream_t stream) {
    const float* g = (const float*)d_in[0];
    const float* caps = (const float*)d_in[1];
    const float* fc_w = (const float*)d_in[2];
    const float* fc_b = (const float*)d_in[3];

    float* out = (float*)d_out;
    float* x_out = out;                    // 38400
    float* xa_out = out + 38400;           // 2457600
    float* g_out = out + 38400 + 2457600;  // 7526400 floats = 30.1 MB scratch until final copy
    unsigned short* Abf = (unsigned short*)g_out;
    unsigned short* gT = Abf + (size_t)EMB * NCOLS;
    unsigned short* gbf = (unsigned short*)g_out;
    unsigned short* Hbf = gbf + (size_t)IMGS * EMB * KPAD;
    float* Ppart = g_out;

    float* ws = (float*)d_ws;
    float* hpool = ws;                                      // 38400 f
    int* idxs = (int*)(ws + 38400);                         // 11520
    float* vals = ws + 49920;                               // 11520
    float* H = ws + 61440;                                  // 200704 f
    unsigned short* Pbf = (unsigned short*)(ws + 262144);   // ends byte 5963776
    unsigned short* wbf = (unsigned short*)(ws + 1490944);  // ends byte 17483776
    bool use_wbf = ws_size >= (size_t)17483776;

    weldon_kernel<<<(IMGS * EMB) / 4, 256, 0, stream>>>(g, hpool);
    x_kernel<<<EMB, 64, 0, stream>>>(hpool, fc_w, fc_b, x_out);
    topk_kernel<<<CAPS, 256, 0, stream>>>(caps, idxs, vals);
    transpose_g_kernel<<<dim3(4, 25, IMGS), 256, 0, stream>>>(g, gT);

    if (use_wbf) {
        convert_w_kernel<<<(EMB * EMB / 4 + 255) / 256, 256, 0, stream>>>(fc_w, wbf);
        // gemm1 (3,7): BM=96 (2400/96=25), BN=224 (3136/224=14) -> 350 blocks
        gemm_gll<3, 7, 0><<<dim3(NCOLS / 224, EMB / 96, 1), 256, 0, stream>>>(
            wbf, gT, Abf, EMB, NCOLS, EMB, EMB, 0, 0);
    } else {
        mfma_gemm_nt<5, 2, 0, float, unsigned short>
            <<<dim3(NCOLS / 64, EMB / 160), 256, 0, stream>>>(fc_w, gT, nullptr, Abf,
                                                              EMB, NCOLS, EMB, EMB);
    }
    heat_kernel<<<dim3((NCOLS / 4 + 255) / 256, CAPS), 256, 0, stream>>>(idxs, vals, Abf, H);
    norm_kernel<<<CAPS * IMGS, 64, 0, stream>>>(H, Hbf);
    convert_g_kernel<<<(IMGS * EMB) / 4, 256, 0, stream>>>(g, gbf);
    gemm_gll<2, 5, 3><<<dim3(EMB / 160, 1, IMGS), 256, 0, stream>>>(
        Hbf, gbf, Pbf, CAPS, EMB, KPAD, KPAD, (long)CAPS * KPAD, (long)EMB * KPAD);
    if (use_wbf) {
        // gemm3 (4,5): BM=128 (1024/128=8), BN=160 (2400/160=15), split-K x3 -> 360 blocks
        gemm_gll<4, 5, 2><<<dim3(EMB / 160, (IMGS * CAPS) / 128, 3), 256, 0, stream>>>(
            Pbf, wbf, Ppart, IMGS * CAPS, EMB, EMB, 800, 0, 0);
    } else {
        mfma_gemm_nt<2, 3, 2, unsigned short, float>
            <<<dim3(EMB / 96, (IMGS * CAPS) / 64, 3), 256, 0, stream>>>(Pbf, fc_w, nullptr, Ppart,
                                                                        IMGS * CAPS, EMB, EMB, 800);
    }
    reduce3_kernel<<<(IMGS * CAPS * EMB / 4) / 256, 256, 0, stream>>>(Ppart, fc_b, xa_out);
    hipMemcpyAsync(g_out, g, sizeof(float) * (size_t)IMGS * EMB * HW,
                   hipMemcpyDeviceToDevice, stream);
}

// Round 12
// 234.029 us; speedup vs baseline: 1.1793x; 1.1558x over previous
//
#include <hip/hip_runtime.h>
#include <math.h>

#define IMGS 16
#define EMB 2400
#define HW 196
#define CAPS 64
#define ATTK 180
#define NPOOL 15
#define NCOLS (IMGS * HW)  // 3136
#define KPAD 224           // 196 padded to multiple of 32

typedef __attribute__((ext_vector_type(8))) short short8;
typedef __attribute__((ext_vector_type(4))) float f32x4;
typedef const __attribute__((address_space(1))) unsigned int* gas1_t;
typedef __attribute__((address_space(3))) unsigned int* las3_t;
typedef unsigned long long ull;

__device__ inline unsigned short f2bf(float f) {
    unsigned int u = __builtin_bit_cast(unsigned int, f);
    u += 0x7fffu + ((u >> 16) & 1u);  // round-to-nearest-even
    return (unsigned short)(u >> 16);
}
__device__ inline float bf2f(unsigned int lo16) {
    return __builtin_bit_cast(float, lo16 << 16);
}
__device__ inline unsigned f2sort(float f) {
    unsigned u = __builtin_bit_cast(unsigned, f);
    int msk = ((int)u) >> 31;
    return u ^ (unsigned)(msk | 0x80000000);
}

// ---------------- Weldon pooling v5: half-wave split + negation ----------------
// r11: VALUBusy ~100% -> pure VALU-throughput bound; cut ops/iteration.
// Lanes 0-31 hold the row, lanes 32-63 hold the NEGATED row; ONE max-extraction
// chain serves top-15 (low half) and bottom-15 (= -top-15 of -x, high half).
// 5-step DPP reduce within 32-lane halves (row_shr1/2/4/8 + row_bcast15 never
// cross lane 32). Unique low-byte ids -> branch-free equality knockout.
// ~32 VALU/iter vs ~50 in v4.
__global__ __launch_bounds__(256) void weldon_kernel(const float* __restrict__ g,
                                                     float* __restrict__ hpool) {
    int wid = (blockIdx.x * 256 + threadIdx.x) >> 6;
    int tlane = threadIdx.x & 63;
    int hl = tlane & 31;
    bool neg = tlane >= 32;
    const float* row = g + (size_t)wid * HW;
    float s[7];
#pragma unroll
    for (int q = 0; q < 7; q++) {
        int e = hl + 32 * q;
        if (e < HW) {
            unsigned u = __builtin_bit_cast(unsigned, row[e]);
            if (neg) u ^= 0x80000000u;                       // negate
            u = (u & 0xFFFFFF00u) | (unsigned)(q * 32 + hl); // unique id (<224)
            s[q] = __builtin_bit_cast(float, u);
        } else {
            s[q] = -INFINITY;
        }
    }
    float acc = 0.f;
#pragma unroll
    for (int it = 0; it < NPOOL; ++it) {
        float m = fmaxf(fmaxf(fmaxf(s[0], s[1]), fmaxf(s[2], s[3])),
                        fmaxf(fmaxf(s[4], s[5]), s[6]));
        int x = __builtin_bit_cast(int, m);
#define ST(c)                                                                  \
    {                                                                          \
        int y = __builtin_amdgcn_update_dpp(x, x, c, 0xf, 0xf, false);         \
        float a = fmaxf(__builtin_bit_cast(float, x), __builtin_bit_cast(float, y)); \
        x = __builtin_bit_cast(int, a);                                        \
    }
        ST(0x111) ST(0x112) ST(0x114) ST(0x118) ST(0x142)
#undef ST
        int m31 = __builtin_amdgcn_readlane(x, 31);  // max of lanes 0-31
        int m63 = __builtin_amdgcn_readlane(x, 63);  // max of lanes 32-63
        float msel = __builtin_bit_cast(float, neg ? m63 : m31);
        acc += msel;
        unsigned mb = __builtin_bit_cast(unsigned, msel);
#pragma unroll
        for (int q = 0; q < 7; q++)
            s[q] = (__builtin_bit_cast(unsigned, s[q]) == mb) ? -INFINITY : s[q];
    }
    // lane0 acc = top-15 sum; lane32 acc = sum of max(-x) = -(bottom-15 sum)
    int ai = __builtin_bit_cast(int, acc);
    float a0 = __builtin_bit_cast(float, __builtin_amdgcn_readlane(ai, 0));
    float a32 = __builtin_bit_cast(float, __builtin_amdgcn_readlane(ai, 32));
    if (tlane == 0) hpool[wid] = (a0 - a32) / 15.0f;
}

// ---------------- x = hpool @ fc_w.T + fc_b ----------------
__global__ void x_kernel(const float* __restrict__ hpool, const float* __restrict__ fc_w,
                         const float* __restrict__ fc_b, float* __restrict__ x_out) {
    int o = blockIdx.x;
    int lane = threadIdx.x;  // 64
    float acc[IMGS];
#pragma unroll
    for (int i = 0; i < IMGS; i++) acc[i] = 0.f;
    const float* wrow = fc_w + (size_t)o * EMB;
    for (int e = lane; e < EMB; e += 64) {
        float wv = wrow[e];
#pragma unroll
        for (int i = 0; i < IMGS; i++) acc[i] += hpool[i * EMB + e] * wv;
    }
#pragma unroll
    for (int i = 0; i < IMGS; i++) {
#pragma unroll
        for (int s = 32; s > 0; s >>= 1) acc[i] += __shfl_xor(acc[i], s, 64);
    }
    if (lane == 0) {
        float bo = fc_b[o];
#pragma unroll
        for (int i = 0; i < IMGS; i++) x_out[i * EMB + o] = acc[i] + bo;
    }
}

// ---------------- topk v4: radix select with parallel bucket scan ----------------
__global__ __launch_bounds__(256) void topk_kernel(const float* __restrict__ caps,
                                                   int* __restrict__ idxs,
                                                   float* __restrict__ vals) {
    __shared__ float rowf[EMB];
    __shared__ unsigned hist[4][256];
    __shared__ unsigned scanbuf[256];
    __shared__ unsigned cnts[256];
    __shared__ ull sprefix;
    __shared__ int srank;
    int c = blockIdx.x;
    int tid = threadIdx.x;
    const float4* src = (const float4*)(caps + (size_t)c * EMB);
    for (int j = tid; j < EMB / 4; j += 256) {
        float4 v = src[j];
        *(float4*)&rowf[j * 4] = v;
    }
    if (tid == 0) { sprefix = 0ull; srank = ATTK; }

#pragma unroll 1
    for (int pass = 0; pass < 6; ++pass) {
        __syncthreads();
        ull pref = sprefix;
        int rk = srank;
        int shift = 40 - pass * 8;
        ull pmaskhi = (pass == 0) ? 0ull : ~((1ull << (shift + 8)) - 1ull);
        hist[0][tid] = 0; hist[1][tid] = 0; hist[2][tid] = 0; hist[3][tid] = 0;
        __syncthreads();
        unsigned* myhist = hist[tid >> 6];
#pragma unroll 1
        for (int s = 0; s < 10; s++) {
            int e = tid + s * 256;
            if (e < EMB) {
                ull key = ((ull)f2sort(rowf[e]) << 16) | ((unsigned)(2399 - e) << 4);
                if ((key & pmaskhi) == pref)
                    atomicAdd(&myhist[(unsigned)(key >> shift) & 255u], 1u);
            }
        }
        __syncthreads();
        unsigned h = hist[0][tid] + hist[1][tid] + hist[2][tid] + hist[3][tid];
        scanbuf[255 - tid] = h;
        __syncthreads();
#pragma unroll
        for (int d = 1; d < 256; d <<= 1) {
            unsigned add = (tid >= d) ? scanbuf[tid - d] : 0u;
            __syncthreads();
            scanbuf[tid] += add;
            __syncthreads();
        }
        unsigned incl = scanbuf[255 - tid];
        unsigned excl = incl - h;
        if (h > 0u && excl < (unsigned)rk && incl >= (unsigned)rk) {
            srank = rk - (int)excl;
            sprefix = pref | ((ull)tid << shift);
        }
    }
    __syncthreads();
    ull T = sprefix;
    unsigned selmask = 0, cnt = 0;
#pragma unroll 1
    for (int s = 0; s < 10; s++) {
        int e = tid + s * 256;
        if (e < EMB) {
            ull key = ((ull)f2sort(rowf[e]) << 16) | ((unsigned)(2399 - e) << 4);
            if (key >= T) { selmask |= 1u << s; cnt++; }
        }
    }
    cnts[tid] = cnt;
    __syncthreads();
#pragma unroll
    for (int d = 1; d < 256; d <<= 1) {
        unsigned add = (tid >= d) ? cnts[tid - d] : 0u;
        __syncthreads();
        cnts[tid] += add;
        __syncthreads();
    }
    unsigned slot = cnts[tid] - cnt;
#pragma unroll 1
    for (int s = 0; s < 10; s++) {
        if (selmask & (1u << s)) {
            int e = tid + s * 256;
            idxs[c * ATTK + slot] = e;
            vals[c * ATTK + slot] = fabsf(rowf[e]);
            slot++;
        }
    }
}

// ---------------- fc_w fp32 -> bf16 row-major copy ----------------
__global__ void convert_w_kernel(const float* __restrict__ w, unsigned short* __restrict__ wbf) {
    int i = (blockIdx.x * 256 + threadIdx.x) * 4;
    if (i >= EMB * EMB) return;
    float4 a = *(const float4*)&w[i];
    ushort4 r;
    r.x = f2bf(a.x); r.y = f2bf(a.y); r.z = f2bf(a.z); r.w = f2bf(a.w);
    *(ushort4*)&wbf[i] = r;
}

// ---------------- gbf[i][e][KPAD] = bf16(g[i][e][hw]), zero-padded ----------------
__global__ __launch_bounds__(256) void convert_g_kernel(const float* __restrict__ g,
                                                        unsigned short* __restrict__ gbf) {
    int row = blockIdx.x * 4 + (threadIdx.x >> 6);
    int l = threadIdx.x & 63;
    const float* src = g + (size_t)row * HW;
    unsigned short* dst = gbf + (size_t)row * KPAD;
    if (l < KPAD / 4) {
        ushort4 o = {0, 0, 0, 0};
        if (l < HW / 4) {
            float4 v = ((const float4*)src)[l];
            o.x = f2bf(v.x); o.y = f2bf(v.y); o.z = f2bf(v.z); o.w = f2bf(v.w);
        }
        ((ushort4*)dst)[l] = o;
    }
}

// ---------------- gT[n][e] = bf16(g[i(n)][e][hw(n)]) ----------------
__global__ void transpose_g_kernel(const float* __restrict__ g, unsigned short* __restrict__ gT) {
    __shared__ float t[96][50];
    int i = blockIdx.z;
    int e0 = blockIdx.y * 96;
    int h0 = blockIdx.x * 49;
    int tid = threadIdx.x;
    for (int f = tid; f < 96 * 49; f += 256) {
        int e = f / 49, hh = f % 49;
        t[e][hh] = g[(size_t)i * EMB * HW + (size_t)(e0 + e) * HW + h0 + hh];
    }
    __syncthreads();
    for (int f = tid; f < 49 * 96; f += 256) {
        int hh = f / 96, e = f % 96;
        gT[(size_t)(i * HW + h0 + hh) * EMB + e0 + e] = f2bf(t[e][hh]);
    }
}

// ======== NT bf16 MFMA GEMM, gll staging, 3-buffer counted-vmcnt pipeline ========
// r11 lesson: (3,7)=350 blocks -> 68% CU-busy (grid quantization) ate the ratio
// gain. r12: gemm1 (5,7): ratio 35/12=2.9, traffic 387 MB, ROWS=384 (no dummies),
// 210 blocks at 2 blocks/CU -> ~82% busy. T2 swizzle + T4 counted vmcnt + T5 kept.
template <int MF, int NF, int OUT_MODE>
__global__ __launch_bounds__(256) void gemm_gll(const unsigned short* __restrict__ A,
                                                const unsigned short* __restrict__ B,
                                                void* __restrict__ outp,
                                                int M, int N, int K, int kper,
                                                long az, long bz) {
    constexpr int BM = MF * 32, BN = NF * 32;
    constexpr int ROWS = BM + BN;
    constexpr int RPAD = (ROWS + 63) & ~63;  // NCALL%4==0 -> uniform loads/wave
    constexpr int NCALL = RPAD / 16;
    constexpr int LPW = NCALL / 4;           // loads per wave per tile
    __shared__ unsigned short lds[3][RPAD][32];
    int m0 = blockIdx.y * BM, n0 = blockIdx.x * BN;
    int z = blockIdx.z;
    const unsigned short* Ab = A + (size_t)z * az;
    const unsigned short* Bb = B + (size_t)z * bz;
    int kb = (az == 0 && bz == 0) ? z * kper : 0;
    int nt = kper / 32;
    int tid = threadIdx.x, w = tid >> 6, lane = tid & 63;
    int wm = (w >> 1) * (MF * 16), wn = (w & 1) * (NF * 16);
    int ln = lane & 15;
    int ks = (((lane >> 4) ^ ((lane >> 1) & 3))) * 8;   // T2 read slot
    int srow = lane >> 2;
    int skc = (((lane & 3) ^ ((lane >> 3) & 3))) * 8;   // T2 source chunk

    auto STAGE = [&](int buf, int t) {
        int k0 = kb + t * 32;
#pragma unroll
        for (int j = 0; j < LPW; j++) {
            int jj = w + j * 4;
            int r = jj * 16 + srow;
            const unsigned short* src;
            if (r < BM) src = Ab + (size_t)(m0 + r) * K + k0 + skc;
            else if (r < ROWS) src = Bb + (size_t)(n0 + r - BM) * K + k0 + skc;
            else src = Ab + (size_t)m0 * K + k0 + skc;  // dummy (uniform vmcnt), L2-hit
            __builtin_amdgcn_global_load_lds((gas1_t)(const void*)src,
                                             (las3_t)(void*)&lds[buf][jj * 16][0], 16, 0, 0);
        }
    };

    STAGE(0, 0);
    if (nt > 1) STAGE(1, 1);
    f32x4 acc[MF][NF] = {};
    for (int t = 0; t < nt; ++t) {
        // wait tile t's LPW loads; tile t+1's LPW may stay in flight (T4)
        if (t + 1 < nt) {
            if constexpr (LPW == 4) asm volatile("s_waitcnt vmcnt(4) lgkmcnt(0)" ::: "memory");
            else if constexpr (LPW == 5) asm volatile("s_waitcnt vmcnt(5) lgkmcnt(0)" ::: "memory");
            else if constexpr (LPW == 6) asm volatile("s_waitcnt vmcnt(6) lgkmcnt(0)" ::: "memory");
            else asm volatile("s_waitcnt vmcnt(0) lgkmcnt(0)" ::: "memory");
        } else {
            asm volatile("s_waitcnt vmcnt(0) lgkmcnt(0)" ::: "memory");
        }
        __builtin_amdgcn_s_barrier();
        __builtin_amdgcn_sched_barrier(0);  // rule #18
        if (t + 2 < nt) STAGE((t + 2) % 3, t + 2);
        const unsigned short(*buf)[32] = lds[t % 3];
        short8 af[MF], bfv[NF];
#pragma unroll
        for (int mf = 0; mf < MF; mf++)
            af[mf] = *(const short8*)&buf[wm + mf * 16 + ln][ks];
#pragma unroll
        for (int nf = 0; nf < NF; nf++)
            bfv[nf] = *(const short8*)&buf[BM + wn + nf * 16 + ln][ks];
        __builtin_amdgcn_s_setprio(1);  // T5
#pragma unroll
        for (int mf = 0; mf < MF; mf++)
#pragma unroll
            for (int nf = 0; nf < NF; nf++)
                acc[mf][nf] = __builtin_amdgcn_mfma_f32_16x16x32_bf16(af[mf], bfv[nf],
                                                                      acc[mf][nf], 0, 0, 0);
        __builtin_amdgcn_s_setprio(0);
    }
#pragma unroll
    for (int mf = 0; mf < MF; mf++) {
#pragma unroll
        for (int nf = 0; nf < NF; nf++) {
#pragma unroll
            for (int rr = 0; rr < 4; rr++) {
                int row = m0 + wm + mf * 16 + (lane >> 4) * 4 + rr;
                int col = n0 + wn + nf * 16 + ln;
                float v = acc[mf][nf][rr];
                if (OUT_MODE == 0) {
                    ((unsigned short*)outp)[(size_t)row * N + col] = f2bf(fabsf(v));
                } else if (OUT_MODE == 2) {
                    ((float*)outp)[(size_t)z * M * N + (size_t)row * N + col] = v;
                } else {
                    ((unsigned short*)outp)[(size_t)z * M * N + (size_t)row * N + col] = f2bf(v);
                }
            }
        }
    }
}

// ======== fallback reg-staged NT GEMM (used only if ws too small for wbf) ========
__device__ inline uint4 load8(const unsigned short* p) { return *(const uint4*)p; }
__device__ inline uint4 load8(const float* p) {
    float4 a = *(const float4*)p;
    float4 b = *(const float4*)(p + 4);
    uint4 r;
    r.x = (unsigned)f2bf(a.x) | ((unsigned)f2bf(a.y) << 16);
    r.y = (unsigned)f2bf(a.z) | ((unsigned)f2bf(a.w) << 16);
    r.z = (unsigned)f2bf(b.x) | ((unsigned)f2bf(b.y) << 16);
    r.w = (unsigned)f2bf(b.z) | ((unsigned)f2bf(b.w) << 16);
    return r;
}

template <int MF, int NF, int OUT_MODE, typename TA, typename TB>
__global__ __launch_bounds__(256) void mfma_gemm_nt(const TA* __restrict__ A,
                                                    const TB* __restrict__ B,
                                                    const float* __restrict__ bias,
                                                    void* __restrict__ outp,
                                                    int M, int N, int K, int kper) {
    constexpr int BM = MF * 32, BN = NF * 32;
    constexpr int nA = BM * 4, nTot = (BM + BN) * 4;
    constexpr int NCH = (nTot + 255) / 256;
    __shared__ unsigned short As[BM][40];
    __shared__ unsigned short Bs[BN][40];
    int m0 = blockIdx.y * BM, n0 = blockIdx.x * BN;
    int sk = blockIdx.z;
    int kb = sk * kper, ke = kb + kper;
    int tid = threadIdx.x;
    int w = tid >> 6, lane = tid & 63;
    int wm = (w >> 1) * (MF * 16), wn = (w & 1) * (NF * 16);
    int ln = lane & 15, ks = (lane >> 4) * 8;
    uint4 r[NCH];
#pragma unroll
    for (int j = 0; j < NCH; j++) {
        int c = tid + 256 * j;
        if (c < nTot) {
            if (c < nA) {
                int row = c >> 2, kc = c & 3;
                r[j] = load8(A + (size_t)(m0 + row) * K + kb + kc * 8);
            } else {
                int cc = c - nA, row = cc >> 2, kc = cc & 3;
                r[j] = load8(B + (size_t)(n0 + row) * K + kb + kc * 8);
            }
        }
    }
    f32x4 acc[MF][NF] = {};
    for (int k0 = kb; k0 < ke; k0 += 32) {
#pragma unroll
        for (int j = 0; j < NCH; j++) {
            int c = tid + 256 * j;
            if (c < nTot) {
                if (c < nA) {
                    int row = c >> 2, kc = c & 3;
                    *(uint4*)&As[row][kc * 8] = r[j];
                } else {
                    int cc = c - nA, row = cc >> 2, kc = cc & 3;
                    *(uint4*)&Bs[row][kc * 8] = r[j];
                }
            }
        }
        __syncthreads();
        if (k0 + 32 < ke) {
#pragma unroll
            for (int j = 0; j < NCH; j++) {
                int c = tid + 256 * j;
                if (c < nTot) {
                    if (c < nA) {
                        int row = c >> 2, kc = c & 3;
                        r[j] = load8(A + (size_t)(m0 + row) * K + (k0 + 32) + kc * 8);
                    } else {
                        int cc = c - nA, row = cc >> 2, kc = cc & 3;
                        r[j] = load8(B + (size_t)(n0 + row) * K + (k0 + 32) + kc * 8);
                    }
                }
            }
        }
        short8 af[MF], bfv[NF];
#pragma unroll
        for (int mf = 0; mf < MF; mf++)
            af[mf] = *(const short8*)&As[wm + mf * 16 + ln][ks];
#pragma unroll
        for (int nf = 0; nf < NF; nf++)
            bfv[nf] = *(const short8*)&Bs[wn + nf * 16 + ln][ks];
#pragma unroll
        for (int mf = 0; mf < MF; mf++)
#pragma unroll
            for (int nf = 0; nf < NF; nf++)
                acc[mf][nf] = __builtin_amdgcn_mfma_f32_16x16x32_bf16(af[mf], bfv[nf],
                                                                      acc[mf][nf], 0, 0, 0);
        __syncthreads();
    }
#pragma unroll
    for (int mf = 0; mf < MF; mf++) {
#pragma unroll
        for (int nf = 0; nf < NF; nf++) {
#pragma unroll
            for (int rr = 0; rr < 4; rr++) {
                int row = m0 + wm + mf * 16 + (lane >> 4) * 4 + rr;
                int col = n0 + wn + nf * 16 + ln;
                float v = acc[mf][nf][rr];
                if (OUT_MODE == 0) {
                    ((unsigned short*)outp)[(size_t)row * N + col] = f2bf(fabsf(v));
                } else if (OUT_MODE == 2) {
                    ((float*)outp)[(size_t)sk * M * N + (size_t)row * N + col] = v;
                }
            }
        }
    }
}

// ---------------- reduce 3 split-K partials + bias -> xa_out ----------------
__global__ void reduce3_kernel(const float* __restrict__ p, const float* __restrict__ bias,
                               float* __restrict__ out) {
    int i = (blockIdx.x * 256 + threadIdx.x) * 4;
    if (i >= IMGS * CAPS * EMB) return;
    float4 a = *(const float4*)&p[i];
    float4 b = *(const float4*)&p[i + IMGS * CAPS * EMB];
    float4 c = *(const float4*)&p[i + 2 * IMGS * CAPS * EMB];
    float4 bb = *(const float4*)&bias[i % EMB];
    float4 r = {a.x + b.x + c.x + bb.x, a.y + b.y + c.y + bb.y,
                a.z + b.z + c.z + bb.z, a.w + b.w + c.w + bb.w};
    *(float4*)&out[i] = r;
}

// ---------------- heat v2: 1 col/thread, 832 blocks (r11: 256 blocks = 1 wave/SIMD,
// latency-bound on 180 dependent scattered loads). j-unroll 4 for MLP. ----------------
__global__ __launch_bounds__(256) void heat_kernel(const int* __restrict__ idxs,
                                                   const float* __restrict__ vals,
                                                   const unsigned short* __restrict__ A,
                                                   float* __restrict__ H) {
    __shared__ int sidx[ATTK];
    __shared__ float sval[ATTK];
    int c = blockIdx.y;
    int tid = threadIdx.x;
    if (tid < ATTK) {
        sidx[tid] = idxs[c * ATTK + tid];
        sval[tid] = vals[c * ATTK + tid];
    }
    __syncthreads();
    int n = blockIdx.x * 256 + tid;
    if (n >= NCOLS) return;
    float a0 = 0.f, a1 = 0.f, a2 = 0.f, a3 = 0.f;
#pragma unroll 1
    for (int j = 0; j < ATTK; j += 4) {  // 180 = 4*45
        a0 += sval[j + 0] * bf2f(A[(size_t)sidx[j + 0] * NCOLS + n]);
        a1 += sval[j + 1] * bf2f(A[(size_t)sidx[j + 1] * NCOLS + n]);
        a2 += sval[j + 2] * bf2f(A[(size_t)sidx[j + 2] * NCOLS + n]);
        a3 += sval[j + 3] * bf2f(A[(size_t)sidx[j + 3] * NCOLS + n]);
    }
    H[(size_t)c * NCOLS + n] = (a0 + a1) + (a2 + a3);
}

// ---------------- norm: Hbf[i][c][KPAD] = bf16(H / rowsum), zero-padded ----------------
__global__ void norm_kernel(const float* __restrict__ H, unsigned short* __restrict__ Hbf) {
    int c = blockIdx.x / IMGS, i = blockIdx.x % IMGS;
    const float* p = H + (size_t)c * NCOLS + i * HW;
    int lane = threadIdx.x;  // 64
    float s = 0.f;
    for (int hw = lane; hw < HW; hw += 64) s += p[hw];
#pragma unroll
    for (int d = 32; d > 0; d >>= 1) s += __shfl_xor(s, d, 64);
    float inv = 1.0f / s;
    unsigned short* dst = Hbf + ((size_t)i * CAPS + c) * KPAD;
    for (int hw = lane; hw < KPAD; hw += 64)
        dst[hw] = (hw < HW) ? f2bf(p[hw] * inv) : (unsigned short)0;
}

extern "C" void kernel_launch(void* const* d_in, const int* in_sizes, int n_in,
                              void* d_out, int out_size, void* d_ws, size_t ws_size,
                              hipStream_t stream) {
    const float* g = (const float*)d_in[0];
    const float* caps = (const float*)d_in[1];
    const float* fc_w = (const float*)d_in[2];
    const float* fc_b = (const float*)d_in[3];

    float* out = (float*)d_out;
    float* x_out = out;                    // 38400
    float* xa_out = out + 38400;           // 2457600
    float* g_out = out + 38400 + 2457600;  // 7526400 floats = 30.1 MB scratch until final copy
    unsigned short* Abf = (unsigned short*)g_out;
    unsigned short* gT = Abf + (size_t)EMB * NCOLS;
    unsigned short* gbf = (unsigned short*)g_out;
    unsigned short* Hbf = gbf + (size_t)IMGS * EMB * KPAD;
    float* Ppart = g_out;

    float* ws = (float*)d_ws;
    float* hpool = ws;                                      // 38400 f
    int* idxs = (int*)(ws + 38400);                         // 11520
    float* vals = ws + 49920;                               // 11520
    float* H = ws + 61440;                                  // 200704 f
    unsigned short* Pbf = (unsigned short*)(ws + 262144);   // ends byte 5963776
    unsigned short* wbf = (unsigned short*)(ws + 1490944);  // ends byte 17483776
    bool use_wbf = ws_size >= (size_t)17483776;

    weldon_kernel<<<(IMGS * EMB) / 4, 256, 0, stream>>>(g, hpool);
    x_kernel<<<EMB, 64, 0, stream>>>(hpool, fc_w, fc_b, x_out);
    topk_kernel<<<CAPS, 256, 0, stream>>>(caps, idxs, vals);
    transpose_g_kernel<<<dim3(4, 25, IMGS), 256, 0, stream>>>(g, gT);

    if (use_wbf) {
        convert_w_kernel<<<(EMB * EMB / 4 + 255) / 256, 256, 0, stream>>>(fc_w, wbf);
        // gemm1 (5,7): BM=160 (2400/160=15), BN=224 (3136/224=14) -> 210 blocks, 2/CU
        gemm_gll<5, 7, 0><<<dim3(NCOLS / 224, EMB / 160, 1), 256, 0, stream>>>(
            wbf, gT, Abf, EMB, NCOLS, EMB, EMB, 0, 0);
    } else {
        mfma_gemm_nt<5, 2, 0, float, unsigned short>
            <<<dim3(NCOLS / 64, EMB / 160), 256, 0, stream>>>(fc_w, gT, nullptr, Abf,
                                                              EMB, NCOLS, EMB, EMB);
    }
    heat_kernel<<<dim3((NCOLS + 255) / 256, CAPS), 256, 0, stream>>>(idxs, vals, Abf, H);
    norm_kernel<<<CAPS * IMGS, 64, 0, stream>>>(H, Hbf);
    convert_g_kernel<<<(IMGS * EMB) / 4, 256, 0, stream>>>(g, gbf);
    gemm_gll<2, 5, 3><<<dim3(EMB / 160, 1, IMGS), 256, 0, stream>>>(
        Hbf, gbf, Pbf, CAPS, EMB, KPAD, KPAD, (long)CAPS * KPAD, (long)EMB * KPAD);
    if (use_wbf) {
        gemm_gll<4, 5, 2><<<dim3(EMB / 160, (IMGS * CAPS) / 128, 3), 256, 0, stream>>>(
            Pbf, wbf, Ppart, IMGS * CAPS, EMB, EMB, 800, 0, 0);
    } else {
        mfma_gemm_nt<2, 3, 2, unsigned short, float>
            <<<dim3(EMB / 96, (IMGS * CAPS) / 64, 3), 256, 0, stream>>>(Pbf, fc_w, nullptr, Ppart,
                                                                        IMGS * CAPS, EMB, EMB, 800);
    }
    reduce3_kernel<<<(IMGS * CAPS * EMB / 4) / 256, 256, 0, stream>>>(Ppart, fc_b, xa_out);
    hipMemcpyAsync(g_out, g, sizeof(float) * (size_t)IMGS * EMB * HW,
                   hipMemcpyDeviceToDevice, stream);
}

// Round 13
// 207.863 us; speedup vs baseline: 1.3278x; 1.1259x over previous
//
#include <hip/hip_runtime.h>
#include <math.h>

#define IMGS 16
#define EMB 2400
#define HW 196
#define CAPS 64
#define ATTK 180
#define NPOOL 15
#define NCOLS (IMGS * HW)  // 3136
#define KPAD 224           // 196 padded to multiple of 32

typedef __attribute__((ext_vector_type(8))) short short8;
typedef __attribute__((ext_vector_type(4))) float f32x4;
typedef const __attribute__((address_space(1))) unsigned int* gas1_t;
typedef __attribute__((address_space(3))) unsigned int* las3_t;
typedef unsigned long long ull;

__device__ inline unsigned short f2bf(float f) {
    unsigned int u = __builtin_bit_cast(unsigned int, f);
    u += 0x7fffu + ((u >> 16) & 1u);  // round-to-nearest-even
    return (unsigned short)(u >> 16);
}
__device__ inline float bf2f(unsigned int lo16) {
    return __builtin_bit_cast(float, lo16 << 16);
}
__device__ inline unsigned f2sort(float f) {
    unsigned u = __builtin_bit_cast(unsigned, f);
    int msk = ((int)u) >> 31;
    return u ^ (unsigned)(msk | 0x80000000);
}

// ---------------- Weldon pooling v6: sorted-head extraction ----------------
// v5 half-wave split kept (lanes 0-31 row, 32-63 negated row; one max chain serves
// top and bottom). NEW: per-lane 7 values sorted DESC once (16-CE Bose-Nelson
// network, ~32 ops); each iteration reduces only the HEADS (s[0]) and the winning
// lane pops via 7 cndmask shift. ~23 VALU/iter vs ~34 in v5.
__global__ __launch_bounds__(256) void weldon_kernel(const float* __restrict__ g,
                                                     float* __restrict__ hpool) {
    int wid = (blockIdx.x * 256 + threadIdx.x) >> 6;
    int tlane = threadIdx.x & 63;
    int hl = tlane & 31;
    bool neg = tlane >= 32;
    const float* row = g + (size_t)wid * HW;
    float s[7];
#pragma unroll
    for (int q = 0; q < 7; q++) {
        int e = hl + 32 * q;
        if (e < HW) {
            unsigned u = __builtin_bit_cast(unsigned, row[e]);
            if (neg) u ^= 0x80000000u;                       // negate for bottom-15
            u = (u & 0xFFFFFF00u) | (unsigned)(q * 32 + hl); // unique id within half
            s[q] = __builtin_bit_cast(float, u);
        } else {
            s[q] = -INFINITY;
        }
    }
    // sort s[0..6] descending (Bose-Nelson 7-element, 16 CEs)
#define CS(a, b)                                   \
    {                                              \
        float hi = fmaxf(s[a], s[b]);              \
        float lo = fminf(s[a], s[b]);              \
        s[a] = hi; s[b] = lo;                      \
    }
    CS(1, 2) CS(3, 4) CS(5, 6)
    CS(0, 2) CS(3, 5) CS(4, 6)
    CS(0, 1) CS(4, 5) CS(2, 6)
    CS(0, 4) CS(1, 5)
    CS(0, 3) CS(2, 5)
    CS(1, 3) CS(2, 4)
    CS(2, 3)
#undef CS
    float acc = 0.f;
#pragma unroll
    for (int it = 0; it < NPOOL; ++it) {
        int x = __builtin_bit_cast(int, s[0]);
#define ST(c)                                                                  \
    {                                                                          \
        int y = __builtin_amdgcn_update_dpp(x, x, c, 0xf, 0xf, false);         \
        float a = fmaxf(__builtin_bit_cast(float, x), __builtin_bit_cast(float, y)); \
        x = __builtin_bit_cast(int, a);                                        \
    }
        ST(0x111) ST(0x112) ST(0x114) ST(0x118) ST(0x142)
#undef ST
        int m31 = __builtin_amdgcn_readlane(x, 31);  // max of lanes 0-31
        int m63 = __builtin_amdgcn_readlane(x, 63);  // max of lanes 32-63
        float msel = __builtin_bit_cast(float, neg ? m63 : m31);
        acc += msel;
        bool won = (__builtin_bit_cast(unsigned, s[0]) ==
                    __builtin_bit_cast(unsigned, msel));
        s[0] = won ? s[1] : s[0];
        s[1] = won ? s[2] : s[1];
        s[2] = won ? s[3] : s[2];
        s[3] = won ? s[4] : s[3];
        s[4] = won ? s[5] : s[4];
        s[5] = won ? s[6] : s[5];
        s[6] = won ? -INFINITY : s[6];
    }
    // lane0 acc = top-15 sum; lane32 acc = sum of max(-x) = -(bottom-15 sum)
    int ai = __builtin_bit_cast(int, acc);
    float a0 = __builtin_bit_cast(float, __builtin_amdgcn_readlane(ai, 0));
    float a32 = __builtin_bit_cast(float, __builtin_amdgcn_readlane(ai, 32));
    if (tlane == 0) hpool[wid] = (a0 - a32) / 15.0f;
}

// ---------------- fused: x = hpool @ fc_w.T + fc_b  AND  wbf = bf16(fc_w) ----------------
// One block per output column o: reads fc_w row o ONCE (float4), writes wbf row,
// accumulates x for all 16 images. Replaces x_kernel + convert_w (one fewer 23MB read).
__global__ void xw_kernel(const float* __restrict__ hpool, const float* __restrict__ fc_w,
                          const float* __restrict__ fc_b, float* __restrict__ x_out,
                          unsigned short* __restrict__ wbf) {
    int o = blockIdx.x;
    int lane = threadIdx.x;  // 64
    float acc[IMGS];
#pragma unroll
    for (int i = 0; i < IMGS; i++) acc[i] = 0.f;
    const float* wrow = fc_w + (size_t)o * EMB;
    unsigned short* wdst = wbf + (size_t)o * EMB;
    for (int e = lane * 4; e < EMB; e += 256) {
        float4 wv = *(const float4*)&wrow[e];
        ushort4 r;
        r.x = f2bf(wv.x); r.y = f2bf(wv.y); r.z = f2bf(wv.z); r.w = f2bf(wv.w);
        *(ushort4*)&wdst[e] = r;
#pragma unroll
        for (int i = 0; i < IMGS; i++) {
            const float* hp = hpool + i * EMB + e;
            acc[i] += hp[0] * wv.x + hp[1] * wv.y + hp[2] * wv.z + hp[3] * wv.w;
        }
    }
#pragma unroll
    for (int i = 0; i < IMGS; i++) {
#pragma unroll
        for (int sdx = 32; sdx > 0; sdx >>= 1) acc[i] += __shfl_xor(acc[i], sdx, 64);
    }
    if (lane == 0) {
        float bo = fc_b[o];
#pragma unroll
        for (int i = 0; i < IMGS; i++) x_out[i * EMB + o] = acc[i] + bo;
    }
}

// ---------------- x = hpool @ fc_w.T + fc_b (fallback, no wbf) ----------------
__global__ void x_kernel(const float* __restrict__ hpool, const float* __restrict__ fc_w,
                         const float* __restrict__ fc_b, float* __restrict__ x_out) {
    int o = blockIdx.x;
    int lane = threadIdx.x;  // 64
    float acc[IMGS];
#pragma unroll
    for (int i = 0; i < IMGS; i++) acc[i] = 0.f;
    const float* wrow = fc_w + (size_t)o * EMB;
    for (int e = lane; e < EMB; e += 64) {
        float wv = wrow[e];
#pragma unroll
        for (int i = 0; i < IMGS; i++) acc[i] += hpool[i * EMB + e] * wv;
    }
#pragma unroll
    for (int i = 0; i < IMGS; i++) {
#pragma unroll
        for (int sdx = 32; sdx > 0; sdx >>= 1) acc[i] += __shfl_xor(acc[i], sdx, 64);
    }
    if (lane == 0) {
        float bo = fc_b[o];
#pragma unroll
        for (int i = 0; i < IMGS; i++) x_out[i * EMB + o] = acc[i] + bo;
    }
}

// ---------------- topk v4: radix select with parallel bucket scan ----------------
__global__ __launch_bounds__(256) void topk_kernel(const float* __restrict__ caps,
                                                   int* __restrict__ idxs,
                                                   float* __restrict__ vals) {
    __shared__ float rowf[EMB];
    __shared__ unsigned hist[4][256];
    __shared__ unsigned scanbuf[256];
    __shared__ unsigned cnts[256];
    __shared__ ull sprefix;
    __shared__ int srank;
    int c = blockIdx.x;
    int tid = threadIdx.x;
    const float4* src = (const float4*)(caps + (size_t)c * EMB);
    for (int j = tid; j < EMB / 4; j += 256) {
        float4 v = src[j];
        *(float4*)&rowf[j * 4] = v;
    }
    if (tid == 0) { sprefix = 0ull; srank = ATTK; }

#pragma unroll 1
    for (int pass = 0; pass < 6; ++pass) {
        __syncthreads();
        ull pref = sprefix;
        int rk = srank;
        int shift = 40 - pass * 8;
        ull pmaskhi = (pass == 0) ? 0ull : ~((1ull << (shift + 8)) - 1ull);
        hist[0][tid] = 0; hist[1][tid] = 0; hist[2][tid] = 0; hist[3][tid] = 0;
        __syncthreads();
        unsigned* myhist = hist[tid >> 6];
#pragma unroll 1
        for (int s = 0; s < 10; s++) {
            int e = tid + s * 256;
            if (e < EMB) {
                ull key = ((ull)f2sort(rowf[e]) << 16) | ((unsigned)(2399 - e) << 4);
                if ((key & pmaskhi) == pref)
                    atomicAdd(&myhist[(unsigned)(key >> shift) & 255u], 1u);
            }
        }
        __syncthreads();
        unsigned h = hist[0][tid] + hist[1][tid] + hist[2][tid] + hist[3][tid];
        scanbuf[255 - tid] = h;
        __syncthreads();
#pragma unroll
        for (int d = 1; d < 256; d <<= 1) {
            unsigned add = (tid >= d) ? scanbuf[tid - d] : 0u;
            __syncthreads();
            scanbuf[tid] += add;
            __syncthreads();
        }
        unsigned incl = scanbuf[255 - tid];
        unsigned excl = incl - h;
        if (h > 0u && excl < (unsigned)rk && incl >= (unsigned)rk) {
            srank = rk - (int)excl;
            sprefix = pref | ((ull)tid << shift);
        }
    }
    __syncthreads();
    ull T = sprefix;
    unsigned selmask = 0, cnt = 0;
#pragma unroll 1
    for (int s = 0; s < 10; s++) {
        int e = tid + s * 256;
        if (e < EMB) {
            ull key = ((ull)f2sort(rowf[e]) << 16) | ((unsigned)(2399 - e) << 4);
            if (key >= T) { selmask |= 1u << s; cnt++; }
        }
    }
    cnts[tid] = cnt;
    __syncthreads();
#pragma unroll
    for (int d = 1; d < 256; d <<= 1) {
        unsigned add = (tid >= d) ? cnts[tid - d] : 0u;
        __syncthreads();
        cnts[tid] += add;
        __syncthreads();
    }
    unsigned slot = cnts[tid] - cnt;
#pragma unroll 1
    for (int s = 0; s < 10; s++) {
        if (selmask & (1u << s)) {
            int e = tid + s * 256;
            idxs[c * ATTK + slot] = e;
            vals[c * ATTK + slot] = fabsf(rowf[e]);
            slot++;
        }
    }
}

// ---------------- fc_w fp32 -> bf16 (fallback path only) ----------------
__global__ void convert_w_kernel(const float* __restrict__ w, unsigned short* __restrict__ wbf) {
    int i = (blockIdx.x * 256 + threadIdx.x) * 4;
    if (i >= EMB * EMB) return;
    float4 a = *(const float4*)&w[i];
    ushort4 r;
    r.x = f2bf(a.x); r.y = f2bf(a.y); r.z = f2bf(a.z); r.w = f2bf(a.w);
    *(ushort4*)&wbf[i] = r;
}

// ---------------- gbf[i][e][KPAD] = bf16(g[i][e][hw]), zero-padded ----------------
__global__ __launch_bounds__(256) void convert_g_kernel(const float* __restrict__ g,
                                                        unsigned short* __restrict__ gbf) {
    int row = blockIdx.x * 4 + (threadIdx.x >> 6);
    int l = threadIdx.x & 63;
    const float* src = g + (size_t)row * HW;
    unsigned short* dst = gbf + (size_t)row * KPAD;
    if (l < KPAD / 4) {
        ushort4 o = {0, 0, 0, 0};
        if (l < HW / 4) {
            float4 v = ((const float4*)src)[l];
            o.x = f2bf(v.x); o.y = f2bf(v.y); o.z = f2bf(v.z); o.w = f2bf(v.w);
        }
        ((ushort4*)dst)[l] = o;
    }
}

// ---------------- gT[n][e] = bf16(g[i(n)][e][hw(n)]) ----------------
__global__ void transpose_g_kernel(const float* __restrict__ g, unsigned short* __restrict__ gT) {
    __shared__ float t[96][50];
    int i = blockIdx.z;
    int e0 = blockIdx.y * 96;
    int h0 = blockIdx.x * 49;
    int tid = threadIdx.x;
    for (int f = tid; f < 96 * 49; f += 256) {
        int e = f / 49, hh = f % 49;
        t[e][hh] = g[(size_t)i * EMB * HW + (size_t)(e0 + e) * HW + h0 + hh];
    }
    __syncthreads();
    for (int f = tid; f < 49 * 96; f += 256) {
        int hh = f / 96, e = f % 96;
        gT[(size_t)(i * HW + h0 + hh) * EMB + e0 + e] = f2bf(t[e][hh]);
    }
}

// ======== NT bf16 MFMA GEMM, gll staging, 3-buffer counted-vmcnt pipeline ========
// r12 lesson: gemm1 time == FETCH/1.45TB/s (75MB HBM vs 26.5MB inputs) -> panel
// re-fetch bound. r13: T1 bijective XCD swizzle (m204) + y-major decode so each
// XCD's contiguous chunk shares B panels in its private L2. Pure index bijection.
// T2 swizzle + T4 counted vmcnt + T5 setprio kept.
template <int MF, int NF, int OUT_MODE>
__global__ __launch_bounds__(256) void gemm_gll(const unsigned short* __restrict__ A,
                                                const unsigned short* __restrict__ B,
                                                void* __restrict__ outp,
                                                int M, int N, int K, int kper,
                                                long az, long bz) {
    constexpr int BM = MF * 32, BN = NF * 32;
    constexpr int ROWS = BM + BN;
    constexpr int RPAD = (ROWS + 63) & ~63;  // NCALL%4==0 -> uniform loads/wave
    constexpr int NCALL = RPAD / 16;
    constexpr int LPW = NCALL / 4;           // loads per wave per tile
    __shared__ unsigned short lds[3][RPAD][32];
    // ---- T1: bijective XCD chunking + y-major decode (within z-slice) ----
    int gx = gridDim.x, gy = gridDim.y;
    int nwg = gx * gy;
    int flat = blockIdx.y * gx + blockIdx.x;
    int qq = nwg >> 3, rr8 = nwg & 7;
    int xcd = flat & 7, idx = flat >> 3;
    int base = (xcd < rr8) ? xcd * (qq + 1) : rr8 * (qq + 1) + (xcd - rr8) * qq;
    int nf = base + idx;
    int m0 = (nf % gy) * BM;      // m walks within chunk -> chunk shares B panel
    int n0 = (nf / gy) * BN;
    int z = blockIdx.z;
    const unsigned short* Ab = A + (size_t)z * az;
    const unsigned short* Bb = B + (size_t)z * bz;
    int kb = (az == 0 && bz == 0) ? z * kper : 0;
    int nt = kper / 32;
    int tid = threadIdx.x, w = tid >> 6, lane = tid & 63;
    int wm = (w >> 1) * (MF * 16), wn = (w & 1) * (NF * 16);
    int ln = lane & 15;
    int ks = (((lane >> 4) ^ ((lane >> 1) & 3))) * 8;   // T2 read slot
    int srow = lane >> 2;
    int skc = (((lane & 3) ^ ((lane >> 3) & 3))) * 8;   // T2 source chunk

    auto STAGE = [&](int buf, int t) {
        int k0 = kb + t * 32;
#pragma unroll
        for (int j = 0; j < LPW; j++) {
            int jj = w + j * 4;
            int r = jj * 16 + srow;
            const unsigned short* src;
            if (r < BM) src = Ab + (size_t)(m0 + r) * K + k0 + skc;
            else if (r < ROWS) src = Bb + (size_t)(n0 + r - BM) * K + k0 + skc;
            else src = Ab + (size_t)m0 * K + k0 + skc;  // dummy (uniform vmcnt), L2-hit
            __builtin_amdgcn_global_load_lds((gas1_t)(const void*)src,
                                             (las3_t)(void*)&lds[buf][jj * 16][0], 16, 0, 0);
        }
    };

    STAGE(0, 0);
    if (nt > 1) STAGE(1, 1);
    f32x4 acc[MF][NF] = {};
    for (int t = 0; t < nt; ++t) {
        // wait tile t's LPW loads; tile t+1's LPW may stay in flight (T4)
        if (t + 1 < nt) {
            if constexpr (LPW == 4) asm volatile("s_waitcnt vmcnt(4) lgkmcnt(0)" ::: "memory");
            else if constexpr (LPW == 5) asm volatile("s_waitcnt vmcnt(5) lgkmcnt(0)" ::: "memory");
            else if constexpr (LPW == 6) asm volatile("s_waitcnt vmcnt(6) lgkmcnt(0)" ::: "memory");
            else asm volatile("s_waitcnt vmcnt(0) lgkmcnt(0)" ::: "memory");
        } else {
            asm volatile("s_waitcnt vmcnt(0) lgkmcnt(0)" ::: "memory");
        }
        __builtin_amdgcn_s_barrier();
        __builtin_amdgcn_sched_barrier(0);  // rule #18
        if (t + 2 < nt) STAGE((t + 2) % 3, t + 2);
        const unsigned short(*buf)[32] = lds[t % 3];
        short8 af[MF], bfv[NF];
#pragma unroll
        for (int mf = 0; mf < MF; mf++)
            af[mf] = *(const short8*)&buf[wm + mf * 16 + ln][ks];
#pragma unroll
        for (int nfi = 0; nfi < NF; nfi++)
            bfv[nfi] = *(const short8*)&buf[BM + wn + nfi * 16 + ln][ks];
        __builtin_amdgcn_s_setprio(1);  // T5
#pragma unroll
        for (int mf = 0; mf < MF; mf++)
#pragma unroll
            for (int nfi = 0; nfi < NF; nfi++)
                acc[mf][nfi] = __builtin_amdgcn_mfma_f32_16x16x32_bf16(af[mf], bfv[nfi],
                                                                       acc[mf][nfi], 0, 0, 0);
        __builtin_amdgcn_s_setprio(0);
    }
#pragma unroll
    for (int mf = 0; mf < MF; mf++) {
#pragma unroll
        for (int nfi = 0; nfi < NF; nfi++) {
#pragma unroll
            for (int rr = 0; rr < 4; rr++) {
                int row = m0 + wm + mf * 16 + (lane >> 4) * 4 + rr;
                int col = n0 + wn + nfi * 16 + ln;
                float v = acc[mf][nfi][rr];
                if (OUT_MODE == 0) {
                    ((unsigned short*)outp)[(size_t)row * N + col] = f2bf(fabsf(v));
                } else if (OUT_MODE == 2) {
                    ((float*)outp)[(size_t)z * M * N + (size_t)row * N + col] = v;
                } else {
                    ((unsigned short*)outp)[(size_t)z * M * N + (size_t)row * N + col] = f2bf(v);
                }
            }
        }
    }
}

// ======== fallback reg-staged NT GEMM (used only if ws too small for wbf) ========
__device__ inline uint4 load8(const unsigned short* p) { return *(const uint4*)p; }
__device__ inline uint4 load8(const float* p) {
    float4 a = *(const float4*)p;
    float4 b = *(const float4*)(p + 4);
    uint4 r;
    r.x = (unsigned)f2bf(a.x) | ((unsigned)f2bf(a.y) << 16);
    r.y = (unsigned)f2bf(a.z) | ((unsigned)f2bf(a.w) << 16);
    r.z = (unsigned)f2bf(b.x) | ((unsigned)f2bf(b.y) << 16);
    r.w = (unsigned)f2bf(b.z) | ((unsigned)f2bf(b.w) << 16);
    return r;
}

template <int MF, int NF, int OUT_MODE, typename TA, typename TB>
__global__ __launch_bounds__(256) void mfma_gemm_nt(const TA* __restrict__ A,
                                                    const TB* __restrict__ B,
                                                    const float* __restrict__ bias,
                                                    void* __restrict__ outp,
                                                    int M, int N, int K, int kper) {
    constexpr int BM = MF * 32, BN = NF * 32;
    constexpr int nA = BM * 4, nTot = (BM + BN) * 4;
    constexpr int NCH = (nTot + 255) / 256;
    __shared__ unsigned short As[BM][40];
    __shared__ unsigned short Bs[BN][40];
    int m0 = blockIdx.y * BM, n0 = blockIdx.x * BN;
    int sk = blockIdx.z;
    int kb = sk * kper, ke = kb + kper;
    int tid = threadIdx.x;
    int w = tid >> 6, lane = tid & 63;
    int wm = (w >> 1) * (MF * 16), wn = (w & 1) * (NF * 16);
    int ln = lane & 15, ks = (lane >> 4) * 8;
    uint4 r[NCH];
#pragma unroll
    for (int j = 0; j < NCH; j++) {
        int c = tid + 256 * j;
        if (c < nTot) {
            if (c < nA) {
                int row = c >> 2, kc = c & 3;
                r[j] = load8(A + (size_t)(m0 + row) * K + kb + kc * 8);
            } else {
                int cc = c - nA, row = cc >> 2, kc = cc & 3;
                r[j] = load8(B + (size_t)(n0 + row) * K + kb + kc * 8);
            }
        }
    }
    f32x4 acc[MF][NF] = {};
    for (int k0 = kb; k0 < ke; k0 += 32) {
#pragma unroll
        for (int j = 0; j < NCH; j++) {
            int c = tid + 256 * j;
            if (c < nTot) {
                if (c < nA) {
                    int row = c >> 2, kc = c & 3;
                    *(uint4*)&As[row][kc * 8] = r[j];
                } else {
                    int cc = c - nA, row = cc >> 2, kc = cc & 3;
                    *(uint4*)&Bs[row][kc * 8] = r[j];
                }
            }
        }
        __syncthreads();
        if (k0 + 32 < ke) {
#pragma unroll
            for (int j = 0; j < NCH; j++) {
                int c = tid + 256 * j;
                if (c < nTot) {
                    if (c < nA) {
                        int row = c >> 2, kc = c & 3;
                        r[j] = load8(A + (size_t)(m0 + row) * K + (k0 + 32) + kc * 8);
                    } else {
                        int cc = c - nA, row = cc >> 2, kc = cc & 3;
                        r[j] = load8(B + (size_t)(n0 + row) * K + (k0 + 32) + kc * 8);
                    }
                }
            }
        }
        short8 af[MF], bfv[NF];
#pragma unroll
        for (int mf = 0; mf < MF; mf++)
            af[mf] = *(const short8*)&As[wm + mf * 16 + ln][ks];
#pragma unroll
        for (int nfi = 0; nfi < NF; nfi++)
            bfv[nfi] = *(const short8*)&Bs[wn + nfi * 16 + ln][ks];
#pragma unroll
        for (int mf = 0; mf < MF; mf++)
#pragma unroll
            for (int nfi = 0; nfi < NF; nfi++)
                acc[mf][nfi] = __builtin_amdgcn_mfma_f32_16x16x32_bf16(af[mf], bfv[nfi],
                                                                       acc[mf][nfi], 0, 0, 0);
        __syncthreads();
    }
#pragma unroll
    for (int mf = 0; mf < MF; mf++) {
#pragma unroll
        for (int nfi = 0; nfi < NF; nfi++) {
#pragma unroll
            for (int rr = 0; rr < 4; rr++) {
                int row = m0 + wm + mf * 16 + (lane >> 4) * 4 + rr;
                int col = n0 + wn + nfi * 16 + ln;
                float v = acc[mf][nfi][rr];
                if (OUT_MODE == 0) {
                    ((unsigned short*)outp)[(size_t)row * N + col] = f2bf(fabsf(v));
                } else if (OUT_MODE == 2) {
                    ((float*)outp)[(size_t)sk * M * N + (size_t)row * N + col] = v;
                }
            }
        }
    }
}

// ---------------- reduce 3 split-K partials + bias -> xa_out ----------------
__global__ void reduce3_kernel(const float* __restrict__ p, const float* __restrict__ bias,
                               float* __restrict__ out) {
    int i = (blockIdx.x * 256 + threadIdx.x) * 4;
    if (i >= IMGS * CAPS * EMB) return;
    float4 a = *(const float4*)&p[i];
    float4 b = *(const float4*)&p[i + IMGS * CAPS * EMB];
    float4 c = *(const float4*)&p[i + 2 * IMGS * CAPS * EMB];
    float4 bb = *(const float4*)&bias[i % EMB];
    float4 r = {a.x + b.x + c.x + bb.x, a.y + b.y + c.y + bb.y,
                a.z + b.z + c.z + bb.z, a.w + b.w + c.w + bb.w};
    *(float4*)&out[i] = r;
}

// ---------------- heat v2: 1 col/thread, 832 blocks ----------------
__global__ __launch_bounds__(256) void heat_kernel(const int* __restrict__ idxs,
                                                   const float* __restrict__ vals,
                                                   const unsigned short* __restrict__ A,
                                                   float* __restrict__ H) {
    __shared__ int sidx[ATTK];
    __shared__ float sval[ATTK];
    int c = blockIdx.y;
    int tid = threadIdx.x;
    if (tid < ATTK) {
        sidx[tid] = idxs[c * ATTK + tid];
        sval[tid] = vals[c * ATTK + tid];
    }
    __syncthreads();
    int n = blockIdx.x * 256 + tid;
    if (n >= NCOLS) return;
    float a0 = 0.f, a1 = 0.f, a2 = 0.f, a3 = 0.f;
#pragma unroll 1
    for (int j = 0; j < ATTK; j += 4) {  // 180 = 4*45
        a0 += sval[j + 0] * bf2f(A[(size_t)sidx[j + 0] * NCOLS + n]);
        a1 += sval[j + 1] * bf2f(A[(size_t)sidx[j + 1] * NCOLS + n]);
        a2 += sval[j + 2] * bf2f(A[(size_t)sidx[j + 2] * NCOLS + n]);
        a3 += sval[j + 3] * bf2f(A[(size_t)sidx[j + 3] * NCOLS + n]);
    }
    H[(size_t)c * NCOLS + n] = (a0 + a1) + (a2 + a3);
}

// ---------------- norm: Hbf[i][c][KPAD] = bf16(H / rowsum), zero-padded ----------------
__global__ void norm_kernel(const float* __restrict__ H, unsigned short* __restrict__ Hbf) {
    int c = blockIdx.x / IMGS, i = blockIdx.x % IMGS;
    const float* p = H + (size_t)c * NCOLS + i * HW;
    int lane = threadIdx.x;  // 64
    float s = 0.f;
    for (int hw = lane; hw < HW; hw += 64) s += p[hw];
#pragma unroll
    for (int d = 32; d > 0; d >>= 1) s += __shfl_xor(s, d, 64);
    float inv = 1.0f / s;
    unsigned short* dst = Hbf + ((size_t)i * CAPS + c) * KPAD;
    for (int hw = lane; hw < KPAD; hw += 64)
        dst[hw] = (hw < HW) ? f2bf(p[hw] * inv) : (unsigned short)0;
}

extern "C" void kernel_launch(void* const* d_in, const int* in_sizes, int n_in,
                              void* d_out, int out_size, void* d_ws, size_t ws_size,
                              hipStream_t stream) {
    const float* g = (const float*)d_in[0];
    const float* caps = (const float*)d_in[1];
    const float* fc_w = (const float*)d_in[2];
    const float* fc_b = (const float*)d_in[3];

    float* out = (float*)d_out;
    float* x_out = out;                    // 38400
    float* xa_out = out + 38400;           // 2457600
    float* g_out = out + 38400 + 2457600;  // 7526400 floats = 30.1 MB scratch until final copy
    unsigned short* Abf = (unsigned short*)g_out;
    unsigned short* gT = Abf + (size_t)EMB * NCOLS;
    unsigned short* gbf = (unsigned short*)g_out;
    unsigned short* Hbf = gbf + (size_t)IMGS * EMB * KPAD;
    float* Ppart = g_out;

    float* ws = (float*)d_ws;
    float* hpool = ws;                                      // 38400 f
    int* idxs = (int*)(ws + 38400);                         // 11520
    float* vals = ws + 49920;                               // 11520
    float* H = ws + 61440;                                  // 200704 f
    unsigned short* Pbf = (unsigned short*)(ws + 262144);   // ends byte 5963776
    unsigned short* wbf = (unsigned short*)(ws + 1490944);  // ends byte 17483776
    bool use_wbf = ws_size >= (size_t)17483776;

    weldon_kernel<<<(IMGS * EMB) / 4, 256, 0, stream>>>(g, hpool);
    topk_kernel<<<CAPS, 256, 0, stream>>>(caps, idxs, vals);
    transpose_g_kernel<<<dim3(4, 25, IMGS), 256, 0, stream>>>(g, gT);

    if (use_wbf) {
        xw_kernel<<<EMB, 64, 0, stream>>>(hpool, fc_w, fc_b, x_out, wbf);
        // gemm1 (5,7): BM=160 (2400/160=15), BN=224 (3136/224=14) -> 210 blocks
        gemm_gll<5, 7, 0><<<dim3(NCOLS / 224, EMB / 160, 1), 256, 0, stream>>>(
            wbf, gT, Abf, EMB, NCOLS, EMB, EMB, 0, 0);
    } else {
        x_kernel<<<EMB, 64, 0, stream>>>(hpool, fc_w, fc_b, x_out);
        mfma_gemm_nt<5, 2, 0, float, unsigned short>
            <<<dim3(NCOLS / 64, EMB / 160), 256, 0, stream>>>(fc_w, gT, nullptr, Abf,
                                                              EMB, NCOLS, EMB, EMB);
    }
    heat_kernel<<<dim3((NCOLS + 255) / 256, CAPS), 256, 0, stream>>>(idxs, vals, Abf, H);
    norm_kernel<<<CAPS * IMGS, 64, 0, stream>>>(H, Hbf);
    convert_g_kernel<<<(IMGS * EMB) / 4, 256, 0, stream>>>(g, gbf);
    gemm_gll<2, 5, 3><<<dim3(EMB / 160, 1, IMGS), 256, 0, stream>>>(
        Hbf, gbf, Pbf, CAPS, EMB, KPAD, KPAD, (long)CAPS * KPAD, (long)EMB * KPAD);
    if (use_wbf) {
        gemm_gll<4, 5, 2><<<dim3(EMB / 160, (IMGS * CAPS) / 128, 3), 256, 0, stream>>>(
            Pbf, wbf, Ppart, IMGS * CAPS, EMB, EMB, 800, 0, 0);
    } else {
        mfma_gemm_nt<2, 3, 2, unsigned short, float>
            <<<dim3(EMB / 96, (IMGS * CAPS) / 64, 3), 256, 0, stream>>>(Pbf, fc_w, nullptr, Ppart,
                                                                        IMGS * CAPS, EMB, EMB, 800);
    }
    reduce3_kernel<<<(IMGS * CAPS * EMB / 4) / 256, 256, 0, stream>>>(Ppart, fc_b, xa_out);
    hipMemcpyAsync(g_out, g, sizeof(float) * (size_t)IMGS * EMB * HW,
                   hipMemcpyDeviceToDevice, stream);
}

// Round 14
// 202.928 us; speedup vs baseline: 1.3601x; 1.0243x over previous
//
#include <hip/hip_runtime.h>
#include <math.h>

#define IMGS 16
#define EMB 2400
#define HW 196
#define CAPS 64
#define ATTK 180
#define NPOOL 15
#define NCOLS (IMGS * HW)  // 3136
#define KPAD 224           // 196 padded to multiple of 32

typedef __attribute__((ext_vector_type(8))) short short8;
typedef __attribute__((ext_vector_type(4))) float f32x4;
typedef const __attribute__((address_space(1))) unsigned int* gas1_t;
typedef __attribute__((address_space(3))) unsigned int* las3_t;
typedef unsigned long long ull;

__device__ inline unsigned short f2bf(float f) {
    unsigned int u = __builtin_bit_cast(unsigned int, f);
    u += 0x7fffu + ((u >> 16) & 1u);  // round-to-nearest-even
    return (unsigned short)(u >> 16);
}
__device__ inline float bf2f(unsigned int lo16) {
    return __builtin_bit_cast(float, lo16 << 16);
}
__device__ inline unsigned f2sort(float f) {
    unsigned u = __builtin_bit_cast(unsigned, f);
    int msk = ((int)u) >> 31;
    return u ^ (unsigned)(msk | 0x80000000);
}

// ---------------- Weldon pooling v6 + optional fused gbf emit ----------------
// Half-wave split (lanes 0-31 row, 32-63 negated); per-lane sort (Bose-Nelson 7);
// 15 head-extractions via 5-step DPP. NEW (r14): if gbf!=null, lanes 0-31 also
// write bf16(g) zero-padded to KPAD -- kills convert_g's separate 60MB re-read.
__global__ __launch_bounds__(256) void weldon_kernel(const float* __restrict__ g,
                                                     float* __restrict__ hpool,
                                                     unsigned short* __restrict__ gbf) {
    int wid = (blockIdx.x * 256 + threadIdx.x) >> 6;
    int tlane = threadIdx.x & 63;
    int hl = tlane & 31;
    bool neg = tlane >= 32;
    const float* row = g + (size_t)wid * HW;
    float s[7];
#pragma unroll
    for (int q = 0; q < 7; q++) {
        int e = hl + 32 * q;  // spans exactly 0..223 = KPAD
        float v0 = (e < HW) ? row[e] : 0.f;
        if (gbf != nullptr && !neg)
            gbf[(size_t)wid * KPAD + e] = (e < HW) ? f2bf(v0) : (unsigned short)0;
        if (e < HW) {
            unsigned u = __builtin_bit_cast(unsigned, v0);
            if (neg) u ^= 0x80000000u;                       // negate for bottom-15
            u = (u & 0xFFFFFF00u) | (unsigned)(q * 32 + hl); // unique id within half
            s[q] = __builtin_bit_cast(float, u);
        } else {
            s[q] = -INFINITY;
        }
    }
#define CS(a, b)                                   \
    {                                              \
        float hi = fmaxf(s[a], s[b]);              \
        float lo = fminf(s[a], s[b]);              \
        s[a] = hi; s[b] = lo;                      \
    }
    CS(1, 2) CS(3, 4) CS(5, 6)
    CS(0, 2) CS(3, 5) CS(4, 6)
    CS(0, 1) CS(4, 5) CS(2, 6)
    CS(0, 4) CS(1, 5)
    CS(0, 3) CS(2, 5)
    CS(1, 3) CS(2, 4)
    CS(2, 3)
#undef CS
    float acc = 0.f;
#pragma unroll
    for (int it = 0; it < NPOOL; ++it) {
        int x = __builtin_bit_cast(int, s[0]);
#define ST(c)                                                                  \
    {                                                                          \
        int y = __builtin_amdgcn_update_dpp(x, x, c, 0xf, 0xf, false);         \
        float a = fmaxf(__builtin_bit_cast(float, x), __builtin_bit_cast(float, y)); \
        x = __builtin_bit_cast(int, a);                                        \
    }
        ST(0x111) ST(0x112) ST(0x114) ST(0x118) ST(0x142)
#undef ST
        int m31 = __builtin_amdgcn_readlane(x, 31);
        int m63 = __builtin_amdgcn_readlane(x, 63);
        float msel = __builtin_bit_cast(float, neg ? m63 : m31);
        acc += msel;
        bool won = (__builtin_bit_cast(unsigned, s[0]) ==
                    __builtin_bit_cast(unsigned, msel));
        s[0] = won ? s[1] : s[0];
        s[1] = won ? s[2] : s[1];
        s[2] = won ? s[3] : s[2];
        s[3] = won ? s[4] : s[3];
        s[4] = won ? s[5] : s[4];
        s[5] = won ? s[6] : s[5];
        s[6] = won ? -INFINITY : s[6];
    }
    int ai = __builtin_bit_cast(int, acc);
    float a0 = __builtin_bit_cast(float, __builtin_amdgcn_readlane(ai, 0));
    float a32 = __builtin_bit_cast(float, __builtin_amdgcn_readlane(ai, 32));
    if (tlane == 0) hpool[wid] = (a0 - a32) / 15.0f;
}

// ---------------- fused: x = hpool @ fc_w.T + fc_b  AND  wbf = bf16(fc_w) ----------------
__global__ void xw_kernel(const float* __restrict__ hpool, const float* __restrict__ fc_w,
                          const float* __restrict__ fc_b, float* __restrict__ x_out,
                          unsigned short* __restrict__ wbf) {
    int o = blockIdx.x;
    int lane = threadIdx.x;  // 64
    float acc[IMGS];
#pragma unroll
    for (int i = 0; i < IMGS; i++) acc[i] = 0.f;
    const float* wrow = fc_w + (size_t)o * EMB;
    unsigned short* wdst = wbf + (size_t)o * EMB;
    for (int e = lane * 4; e < EMB; e += 256) {
        float4 wv = *(const float4*)&wrow[e];
        ushort4 r;
        r.x = f2bf(wv.x); r.y = f2bf(wv.y); r.z = f2bf(wv.z); r.w = f2bf(wv.w);
        *(ushort4*)&wdst[e] = r;
#pragma unroll
        for (int i = 0; i < IMGS; i++) {
            const float* hp = hpool + i * EMB + e;
            acc[i] += hp[0] * wv.x + hp[1] * wv.y + hp[2] * wv.z + hp[3] * wv.w;
        }
    }
#pragma unroll
    for (int i = 0; i < IMGS; i++) {
#pragma unroll
        for (int sdx = 32; sdx > 0; sdx >>= 1) acc[i] += __shfl_xor(acc[i], sdx, 64);
    }
    if (lane == 0) {
        float bo = fc_b[o];
#pragma unroll
        for (int i = 0; i < IMGS; i++) x_out[i * EMB + o] = acc[i] + bo;
    }
}

// ---------------- x = hpool @ fc_w.T + fc_b (fallback, no wbf) ----------------
__global__ void x_kernel(const float* __restrict__ hpool, const float* __restrict__ fc_w,
                         const float* __restrict__ fc_b, float* __restrict__ x_out) {
    int o = blockIdx.x;
    int lane = threadIdx.x;  // 64
    float acc[IMGS];
#pragma unroll
    for (int i = 0; i < IMGS; i++) acc[i] = 0.f;
    const float* wrow = fc_w + (size_t)o * EMB;
    for (int e = lane; e < EMB; e += 64) {
        float wv = wrow[e];
#pragma unroll
        for (int i = 0; i < IMGS; i++) acc[i] += hpool[i * EMB + e] * wv;
    }
#pragma unroll
    for (int i = 0; i < IMGS; i++) {
#pragma unroll
        for (int sdx = 32; sdx > 0; sdx >>= 1) acc[i] += __shfl_xor(acc[i], sdx, 64);
    }
    if (lane == 0) {
        float bo = fc_b[o];
#pragma unroll
        for (int i = 0; i < IMGS; i++) x_out[i * EMB + o] = acc[i] + bo;
    }
}

// ---------------- topk v4: radix select with parallel bucket scan ----------------
__global__ __launch_bounds__(256) void topk_kernel(const float* __restrict__ caps,
                                                   int* __restrict__ idxs,
                                                   float* __restrict__ vals) {
    __shared__ float rowf[EMB];
    __shared__ unsigned hist[4][256];
    __shared__ unsigned scanbuf[256];
    __shared__ unsigned cnts[256];
    __shared__ ull sprefix;
    __shared__ int srank;
    int c = blockIdx.x;
    int tid = threadIdx.x;
    const float4* src = (const float4*)(caps + (size_t)c * EMB);
    for (int j = tid; j < EMB / 4; j += 256) {
        float4 v = src[j];
        *(float4*)&rowf[j * 4] = v;
    }
    if (tid == 0) { sprefix = 0ull; srank = ATTK; }

#pragma unroll 1
    for (int pass = 0; pass < 6; ++pass) {
        __syncthreads();
        ull pref = sprefix;
        int rk = srank;
        int shift = 40 - pass * 8;
        ull pmaskhi = (pass == 0) ? 0ull : ~((1ull << (shift + 8)) - 1ull);
        hist[0][tid] = 0; hist[1][tid] = 0; hist[2][tid] = 0; hist[3][tid] = 0;
        __syncthreads();
        unsigned* myhist = hist[tid >> 6];
#pragma unroll 1
        for (int s = 0; s < 10; s++) {
            int e = tid + s * 256;
            if (e < EMB) {
                ull key = ((ull)f2sort(rowf[e]) << 16) | ((unsigned)(2399 - e) << 4);
                if ((key & pmaskhi) == pref)
                    atomicAdd(&myhist[(unsigned)(key >> shift) & 255u], 1u);
            }
        }
        __syncthreads();
        unsigned h = hist[0][tid] + hist[1][tid] + hist[2][tid] + hist[3][tid];
        scanbuf[255 - tid] = h;
        __syncthreads();
#pragma unroll
        for (int d = 1; d < 256; d <<= 1) {
            unsigned add = (tid >= d) ? scanbuf[tid - d] : 0u;
            __syncthreads();
            scanbuf[tid] += add;
            __syncthreads();
        }
        unsigned incl = scanbuf[255 - tid];
        unsigned excl = incl - h;
        if (h > 0u && excl < (unsigned)rk && incl >= (unsigned)rk) {
            srank = rk - (int)excl;
            sprefix = pref | ((ull)tid << shift);
        }
    }
    __syncthreads();
    ull T = sprefix;
    unsigned selmask = 0, cnt = 0;
#pragma unroll 1
    for (int s = 0; s < 10; s++) {
        int e = tid + s * 256;
        if (e < EMB) {
            ull key = ((ull)f2sort(rowf[e]) << 16) | ((unsigned)(2399 - e) << 4);
            if (key >= T) { selmask |= 1u << s; cnt++; }
        }
    }
    cnts[tid] = cnt;
    __syncthreads();
#pragma unroll
    for (int d = 1; d < 256; d <<= 1) {
        unsigned add = (tid >= d) ? cnts[tid - d] : 0u;
        __syncthreads();
        cnts[tid] += add;
        __syncthreads();
    }
    unsigned slot = cnts[tid] - cnt;
#pragma unroll 1
    for (int s = 0; s < 10; s++) {
        if (selmask & (1u << s)) {
            int e = tid + s * 256;
            idxs[c * ATTK + slot] = e;
            vals[c * ATTK + slot] = fabsf(rowf[e]);
            slot++;
        }
    }
}

// ---------------- fc_w fp32 -> bf16 (fallback path only) ----------------
__global__ void convert_w_kernel(const float* __restrict__ w, unsigned short* __restrict__ wbf) {
    int i = (blockIdx.x * 256 + threadIdx.x) * 4;
    if (i >= EMB * EMB) return;
    float4 a = *(const float4*)&w[i];
    ushort4 r;
    r.x = f2bf(a.x); r.y = f2bf(a.y); r.z = f2bf(a.z); r.w = f2bf(a.w);
    *(ushort4*)&wbf[i] = r;
}

// ---------------- gbf[i][e][KPAD] = bf16(g[i][e][hw]) (small-ws tier only) ----------------
__global__ __launch_bounds__(256) void convert_g_kernel(const float* __restrict__ g,
                                                        unsigned short* __restrict__ gbf) {
    int row = blockIdx.x * 4 + (threadIdx.x >> 6);
    int l = threadIdx.x & 63;
    const float* src = g + (size_t)row * HW;
    unsigned short* dst = gbf + (size_t)row * KPAD;
    if (l < KPAD / 4) {
        ushort4 o = {0, 0, 0, 0};
        if (l < HW / 4) {
            float4 v = ((const float4*)src)[l];
            o.x = f2bf(v.x); o.y = f2bf(v.y); o.z = f2bf(v.z); o.w = f2bf(v.w);
        }
        ((ushort4*)dst)[l] = o;
    }
}

// ---------------- gT[n][e] = bf16(g[i(n)][e][hw(n)]) ----------------
__global__ void transpose_g_kernel(const float* __restrict__ g, unsigned short* __restrict__ gT) {
    __shared__ float t[96][50];
    int i = blockIdx.z;
    int e0 = blockIdx.y * 96;
    int h0 = blockIdx.x * 49;
    int tid = threadIdx.x;
    for (int f = tid; f < 96 * 49; f += 256) {
        int e = f / 49, hh = f % 49;
        t[e][hh] = g[(size_t)i * EMB * HW + (size_t)(e0 + e) * HW + h0 + hh];
    }
    __syncthreads();
    for (int f = tid; f < 49 * 96; f += 256) {
        int hh = f / 96, e = f % 96;
        gT[(size_t)(i * HW + h0 + hh) * EMB + e0 + e] = f2bf(t[e][hh]);
    }
}

// ======== NT bf16 MFMA GEMM, gll staging, 3-buffer counted-vmcnt pipeline ========
// T1 bijective XCD swizzle + y-major decode; T2 source/read swizzle; T4 counted
// vmcnt; T5 setprio. OUT_MODE: 0 bf16 |v|; 2 f32 partial @ z*M*N; 3 bf16 @ z*M*N.
template <int MF, int NF, int OUT_MODE>
__global__ __launch_bounds__(256) void gemm_gll(const unsigned short* __restrict__ A,
                                                const unsigned short* __restrict__ B,
                                                void* __restrict__ outp,
                                                int M, int N, int K, int kper,
                                                long az, long bz) {
    constexpr int BM = MF * 32, BN = NF * 32;
    constexpr int ROWS = BM + BN;
    constexpr int RPAD = (ROWS + 63) & ~63;
    constexpr int NCALL = RPAD / 16;
    constexpr int LPW = NCALL / 4;
    __shared__ unsigned short lds[3][RPAD][32];
    int gx = gridDim.x, gy = gridDim.y;
    int nwg = gx * gy;
    int flat = blockIdx.y * gx + blockIdx.x;
    int qq = nwg >> 3, rr8 = nwg & 7;
    int xcd = flat & 7, idx = flat >> 3;
    int base = (xcd < rr8) ? xcd * (qq + 1) : rr8 * (qq + 1) + (xcd - rr8) * qq;
    int nf = base + idx;
    int m0 = (nf % gy) * BM;
    int n0 = (nf / gy) * BN;
    int z = blockIdx.z;
    const unsigned short* Ab = A + (size_t)z * az;
    const unsigned short* Bb = B + (size_t)z * bz;
    int kb = (az == 0 && bz == 0) ? z * kper : 0;
    int nt = kper / 32;
    int tid = threadIdx.x, w = tid >> 6, lane = tid & 63;
    int wm = (w >> 1) * (MF * 16), wn = (w & 1) * (NF * 16);
    int ln = lane & 15;
    int ks = (((lane >> 4) ^ ((lane >> 1) & 3))) * 8;
    int srow = lane >> 2;
    int skc = (((lane & 3) ^ ((lane >> 3) & 3))) * 8;

    auto STAGE = [&](int buf, int t) {
        int k0 = kb + t * 32;
#pragma unroll
        for (int j = 0; j < LPW; j++) {
            int jj = w + j * 4;
            int r = jj * 16 + srow;
            const unsigned short* src;
            if (r < BM) src = Ab + (size_t)(m0 + r) * K + k0 + skc;
            else if (r < ROWS) src = Bb + (size_t)(n0 + r - BM) * K + k0 + skc;
            else src = Ab + (size_t)m0 * K + k0 + skc;  // dummy (uniform vmcnt), L2-hit
            __builtin_amdgcn_global_load_lds((gas1_t)(const void*)src,
                                             (las3_t)(void*)&lds[buf][jj * 16][0], 16, 0, 0);
        }
    };

    STAGE(0, 0);
    if (nt > 1) STAGE(1, 1);
    f32x4 acc[MF][NF] = {};
    for (int t = 0; t < nt; ++t) {
        if (t + 1 < nt) {
            if constexpr (LPW == 4) asm volatile("s_waitcnt vmcnt(4) lgkmcnt(0)" ::: "memory");
            else if constexpr (LPW == 5) asm volatile("s_waitcnt vmcnt(5) lgkmcnt(0)" ::: "memory");
            else if constexpr (LPW == 6) asm volatile("s_waitcnt vmcnt(6) lgkmcnt(0)" ::: "memory");
            else asm volatile("s_waitcnt vmcnt(0) lgkmcnt(0)" ::: "memory");
        } else {
            asm volatile("s_waitcnt vmcnt(0) lgkmcnt(0)" ::: "memory");
        }
        __builtin_amdgcn_s_barrier();
        __builtin_amdgcn_sched_barrier(0);  // rule #18
        if (t + 2 < nt) STAGE((t + 2) % 3, t + 2);
        const unsigned short(*buf)[32] = lds[t % 3];
        short8 af[MF], bfv[NF];
#pragma unroll
        for (int mf = 0; mf < MF; mf++)
            af[mf] = *(const short8*)&buf[wm + mf * 16 + ln][ks];
#pragma unroll
        for (int nfi = 0; nfi < NF; nfi++)
            bfv[nfi] = *(const short8*)&buf[BM + wn + nfi * 16 + ln][ks];
        __builtin_amdgcn_s_setprio(1);  // T5
#pragma unroll
        for (int mf = 0; mf < MF; mf++)
#pragma unroll
            for (int nfi = 0; nfi < NF; nfi++)
                acc[mf][nfi] = __builtin_amdgcn_mfma_f32_16x16x32_bf16(af[mf], bfv[nfi],
                                                                       acc[mf][nfi], 0, 0, 0);
        __builtin_amdgcn_s_setprio(0);
    }
#pragma unroll
    for (int mf = 0; mf < MF; mf++) {
#pragma unroll
        for (int nfi = 0; nfi < NF; nfi++) {
#pragma unroll
            for (int rr = 0; rr < 4; rr++) {
                int row = m0 + wm + mf * 16 + (lane >> 4) * 4 + rr;
                int col = n0 + wn + nfi * 16 + ln;
                float v = acc[mf][nfi][rr];
                if (OUT_MODE == 0) {
                    ((unsigned short*)outp)[(size_t)row * N + col] = f2bf(fabsf(v));
                } else if (OUT_MODE == 2) {
                    ((float*)outp)[(size_t)z * M * N + (size_t)row * N + col] = v;
                } else {
                    ((unsigned short*)outp)[(size_t)z * M * N + (size_t)row * N + col] = f2bf(v);
                }
            }
        }
    }
}

// ======== fallback reg-staged NT GEMM (used only if ws too small for wbf) ========
__device__ inline uint4 load8(const unsigned short* p) { return *(const uint4*)p; }
__device__ inline uint4 load8(const float* p) {
    float4 a = *(const float4*)p;
    float4 b = *(const float4*)(p + 4);
    uint4 r;
    r.x = (unsigned)f2bf(a.x) | ((unsigned)f2bf(a.y) << 16);
    r.y = (unsigned)f2bf(a.z) | ((unsigned)f2bf(a.w) << 16);
    r.z = (unsigned)f2bf(b.x) | ((unsigned)f2bf(b.y) << 16);
    r.w = (unsigned)f2bf(b.z) | ((unsigned)f2bf(b.w) << 16);
    return r;
}

template <int MF, int NF, int OUT_MODE, typename TA, typename TB>
__global__ __launch_bounds__(256) void mfma_gemm_nt(const TA* __restrict__ A,
                                                    const TB* __restrict__ B,
                                                    const float* __restrict__ bias,
                                                    void* __restrict__ outp,
                                                    int M, int N, int K, int kper) {
    constexpr int BM = MF * 32, BN = NF * 32;
    constexpr int nA = BM * 4, nTot = (BM + BN) * 4;
    constexpr int NCH = (nTot + 255) / 256;
    __shared__ unsigned short As[BM][40];
    __shared__ unsigned short Bs[BN][40];
    int m0 = blockIdx.y * BM, n0 = blockIdx.x * BN;
    int sk = blockIdx.z;
    int kb = sk * kper, ke = kb + kper;
    int tid = threadIdx.x;
    int w = tid >> 6, lane = tid & 63;
    int wm = (w >> 1) * (MF * 16), wn = (w & 1) * (NF * 16);
    int ln = lane & 15, ks = (lane >> 4) * 8;
    uint4 r[NCH];
#pragma unroll
    for (int j = 0; j < NCH; j++) {
        int c = tid + 256 * j;
        if (c < nTot) {
            if (c < nA) {
                int row = c >> 2, kc = c & 3;
                r[j] = load8(A + (size_t)(m0 + row) * K + kb + kc * 8);
            } else {
                int cc = c - nA, row = cc >> 2, kc = cc & 3;
                r[j] = load8(B + (size_t)(n0 + row) * K + kb + kc * 8);
            }
        }
    }
    f32x4 acc[MF][NF] = {};
    for (int k0 = kb; k0 < ke; k0 += 32) {
#pragma unroll
        for (int j = 0; j < NCH; j++) {
            int c = tid + 256 * j;
            if (c < nTot) {
                if (c < nA) {
                    int row = c >> 2, kc = c & 3;
                    *(uint4*)&As[row][kc * 8] = r[j];
                } else {
                    int cc = c - nA, row = cc >> 2, kc = cc & 3;
                    *(uint4*)&Bs[row][kc * 8] = r[j];
                }
            }
        }
        __syncthreads();
        if (k0 + 32 < ke) {
#pragma unroll
            for (int j = 0; j < NCH; j++) {
                int c = tid + 256 * j;
                if (c < nTot) {
                    if (c < nA) {
                        int row = c >> 2, kc = c & 3;
                        r[j] = load8(A + (size_t)(m0 + row) * K + (k0 + 32) + kc * 8);
                    } else {
                        int cc = c - nA, row = cc >> 2, kc = cc & 3;
                        r[j] = load8(B + (size_t)(n0 + row) * K + (k0 + 32) + kc * 8);
                    }
                }
            }
        }
        short8 af[MF], bfv[NF];
#pragma unroll
        for (int mf = 0; mf < MF; mf++)
            af[mf] = *(const short8*)&As[wm + mf * 16 + ln][ks];
#pragma unroll
        for (int nfi = 0; nfi < NF; nfi++)
            bfv[nfi] = *(const short8*)&Bs[wn + nfi * 16 + ln][ks];
#pragma unroll
        for (int mf = 0; mf < MF; mf++)
#pragma unroll
            for (int nfi = 0; nfi < NF; nfi++)
                acc[mf][nfi] = __builtin_amdgcn_mfma_f32_16x16x32_bf16(af[mf], bfv[nfi],
                                                                       acc[mf][nfi], 0, 0, 0);
        __syncthreads();
    }
#pragma unroll
    for (int mf = 0; mf < MF; mf++) {
#pragma unroll
        for (int nfi = 0; nfi < NF; nfi++) {
#pragma unroll
            for (int rr = 0; rr < 4; rr++) {
                int row = m0 + wm + mf * 16 + (lane >> 4) * 4 + rr;
                int col = n0 + wn + nfi * 16 + ln;
                float v = acc[mf][nfi][rr];
                if (OUT_MODE == 0) {
                    ((unsigned short*)outp)[(size_t)row * N + col] = f2bf(fabsf(v));
                } else if (OUT_MODE == 2) {
                    ((float*)outp)[(size_t)sk * M * N + (size_t)row * N + col] = v;
                }
            }
        }
    }
}

// ---------------- reduce 5 bf16 split-K partials + bias -> xa_out ----------------
__global__ void reduce5_kernel(const unsigned short* __restrict__ p,
                               const float* __restrict__ bias, float* __restrict__ out) {
    const size_t S = (size_t)IMGS * CAPS * EMB;
    int i = (blockIdx.x * 256 + threadIdx.x) * 4;
    if (i >= IMGS * CAPS * EMB) return;
    float4 acc = *(const float4*)&bias[i % EMB];
#pragma unroll
    for (int z = 0; z < 5; z++) {
        ushort4 q = *(const ushort4*)&p[z * S + i];
        acc.x += bf2f(q.x);
        acc.y += bf2f(q.y);
        acc.z += bf2f(q.z);
        acc.w += bf2f(q.w);
    }
    *(float4*)&out[i] = acc;
}

// ---------------- reduce 3 f32 partials + bias (fallback tier) ----------------
__global__ void reduce3_kernel(const float* __restrict__ p, const float* __restrict__ bias,
                               float* __restrict__ out) {
    int i = (blockIdx.x * 256 + threadIdx.x) * 4;
    if (i >= IMGS * CAPS * EMB) return;
    float4 a = *(const float4*)&p[i];
    float4 b = *(const float4*)&p[i + IMGS * CAPS * EMB];
    float4 c = *(const float4*)&p[i + 2 * IMGS * CAPS * EMB];
    float4 bb = *(const float4*)&bias[i % EMB];
    float4 r = {a.x + b.x + c.x + bb.x, a.y + b.y + c.y + bb.y,
                a.z + b.z + c.z + bb.z, a.w + b.w + c.w + bb.w};
    *(float4*)&out[i] = r;
}

// ---------------- heat v2: 1 col/thread, 832 blocks ----------------
__global__ __launch_bounds__(256) void heat_kernel(const int* __restrict__ idxs,
                                                   const float* __restrict__ vals,
                                                   const unsigned short* __restrict__ A,
                                                   float* __restrict__ H) {
    __shared__ int sidx[ATTK];
    __shared__ float sval[ATTK];
    int c = blockIdx.y;
    int tid = threadIdx.x;
    if (tid < ATTK) {
        sidx[tid] = idxs[c * ATTK + tid];
        sval[tid] = vals[c * ATTK + tid];
    }
    __syncthreads();
    int n = blockIdx.x * 256 + tid;
    if (n >= NCOLS) return;
    float a0 = 0.f, a1 = 0.f, a2 = 0.f, a3 = 0.f;
#pragma unroll 1
    for (int j = 0; j < ATTK; j += 4) {
        a0 += sval[j + 0] * bf2f(A[(size_t)sidx[j + 0] * NCOLS + n]);
        a1 += sval[j + 1] * bf2f(A[(size_t)sidx[j + 1] * NCOLS + n]);
        a2 += sval[j + 2] * bf2f(A[(size_t)sidx[j + 2] * NCOLS + n]);
        a3 += sval[j + 3] * bf2f(A[(size_t)sidx[j + 3] * NCOLS + n]);
    }
    H[(size_t)c * NCOLS + n] = (a0 + a1) + (a2 + a3);
}

// ---------------- norm: Hbf[i][c][KPAD] = bf16(H / rowsum), zero-padded ----------------
__global__ void norm_kernel(const float* __restrict__ H, unsigned short* __restrict__ Hbf) {
    int c = blockIdx.x / IMGS, i = blockIdx.x % IMGS;
    const float* p = H + (size_t)c * NCOLS + i * HW;
    int lane = threadIdx.x;  // 64
    float s = 0.f;
    for (int hw = lane; hw < HW; hw += 64) s += p[hw];
#pragma unroll
    for (int d = 32; d > 0; d >>= 1) s += __shfl_xor(s, d, 64);
    float inv = 1.0f / s;
    unsigned short* dst = Hbf + ((size_t)i * CAPS + c) * KPAD;
    for (int hw = lane; hw < KPAD; hw += 64)
        dst[hw] = (hw < HW) ? f2bf(p[hw] * inv) : (unsigned short)0;
}

extern "C" void kernel_launch(void* const* d_in, const int* in_sizes, int n_in,
                              void* d_out, int out_size, void* d_ws, size_t ws_size,
                              hipStream_t stream) {
    const float* g = (const float*)d_in[0];
    const float* caps = (const float*)d_in[1];
    const float* fc_w = (const float*)d_in[2];
    const float* fc_b = (const float*)d_in[3];

    float* out = (float*)d_out;
    float* x_out = out;                    // 38400
    float* xa_out = out + 38400;           // 2457600
    float* g_out = out + 38400 + 2457600;  // 7526400 floats = 30.1 MB scratch until final copy
    unsigned short* Abf = (unsigned short*)g_out;
    unsigned short* gT = Abf + (size_t)EMB * NCOLS;

    float* ws = (float*)d_ws;
    float* hpool = ws;                                      // 38400 f
    int* idxs = (int*)(ws + 38400);                         // 11520
    float* vals = ws + 49920;                               // 11520
    float* H = ws + 61440;                                  // 200704 f
    unsigned short* Pbf = (unsigned short*)(ws + 262144);   // ends byte 5963776
    unsigned short* wbf = (unsigned short*)(ws + 1490944);  // ends byte 17483776
    bool use_wbf = ws_size >= (size_t)17483776;
    // tier-big: gbf (16*2400*224*2 = 17,203,200 B) appended in ws after wbf
    bool ws_big = use_wbf && ws_size >= (size_t)(17483776 + 17203200);
    unsigned short* gbf_ws = (unsigned short*)((char*)d_ws + 17483776);

    // gbf/Hbf placement per tier
    unsigned short* gbf = ws_big ? gbf_ws : (unsigned short*)g_out;
    unsigned short* Hbf = ws_big ? (unsigned short*)g_out
                                 : ((unsigned short*)g_out + (size_t)IMGS * EMB * KPAD);
    unsigned short* Ppart5 = (unsigned short*)g_out;  // 5 bf16 slices = 24.6 MB
    float* Ppart3 = g_out;                            // fallback: 3 f32 slices

    weldon_kernel<<<(IMGS * EMB) / 4, 256, 0, stream>>>(g, hpool, ws_big ? gbf : nullptr);
    topk_kernel<<<CAPS, 256, 0, stream>>>(caps, idxs, vals);
    transpose_g_kernel<<<dim3(4, 25, IMGS), 256, 0, stream>>>(g, gT);

    if (use_wbf) {
        xw_kernel<<<EMB, 64, 0, stream>>>(hpool, fc_w, fc_b, x_out, wbf);
        // gemm1 (5,7): BM=160 (15 tiles), BN=224 (14 tiles) -> 210 blocks
        gemm_gll<5, 7, 0><<<dim3(NCOLS / 224, EMB / 160, 1), 256, 0, stream>>>(
            wbf, gT, Abf, EMB, NCOLS, EMB, EMB, 0, 0);
    } else {
        x_kernel<<<EMB, 64, 0, stream>>>(hpool, fc_w, fc_b, x_out);
        mfma_gemm_nt<5, 2, 0, float, unsigned short>
            <<<dim3(NCOLS / 64, EMB / 160), 256, 0, stream>>>(fc_w, gT, nullptr, Abf,
                                                              EMB, NCOLS, EMB, EMB);
    }
    heat_kernel<<<dim3((NCOLS + 255) / 256, CAPS), 256, 0, stream>>>(idxs, vals, Abf, H);
    norm_kernel<<<CAPS * IMGS, 64, 0, stream>>>(H, Hbf);
    if (!ws_big)  // small tier: gbf in g_out, built only after heat freed Abf
        convert_g_kernel<<<(IMGS * EMB) / 4, 256, 0, stream>>>(g, gbf);
    // xapre as batched MFMA GEMM: Pbf[i*64+c][e] = Hn_i @ g_i^T
    gemm_gll<2, 5, 3><<<dim3(EMB / 160, 1, IMGS), 256, 0, stream>>>(
        Hbf, gbf, Pbf, CAPS, EMB, KPAD, KPAD, (long)CAPS * KPAD, (long)EMB * KPAD);
    if (use_wbf) {
        // gemm3 (4,5) split-K x5 (kper=480, nt=15) -> 600 blocks, bf16 partials
        gemm_gll<4, 5, 3><<<dim3(EMB / 160, (IMGS * CAPS) / 128, 5), 256, 0, stream>>>(
            Pbf, wbf, Ppart5, IMGS * CAPS, EMB, EMB, 480, 0, 0);
        reduce5_kernel<<<(IMGS * CAPS * EMB / 4) / 256, 256, 0, stream>>>(Ppart5, fc_b, xa_out);
    } else {
        mfma_gemm_nt<2, 3, 2, unsigned short, float>
            <<<dim3(EMB / 96, (IMGS * CAPS) / 64, 3), 256, 0, stream>>>(Pbf, fc_w, nullptr,
                                                                        Ppart3, IMGS * CAPS,
                                                                        EMB, EMB, 800);
        reduce3_kernel<<<(IMGS * CAPS * EMB / 4) / 256, 256, 0, stream>>>(Ppart3, fc_b, xa_out);
    }
    // g passthrough last (overwrites all g_out scratch)
    hipMemcpyAsync(g_out, g, sizeof(float) * (size_t)IMGS * EMB * HW,
                   hipMemcpyDeviceToDevice, stream);
}

// Round 15
// 173.058 us; speedup vs baseline: 1.5948x; 1.1726x over previous
//
#include <hip/hip_runtime.h>
#include <math.h>

#define IMGS 16
#define EMB 2400
#define HW 196
#define CAPS 64
#define ATTK 180
#define NPOOL 15
#define NCOLS (IMGS * HW)  // 3136
#define KPAD 224           // 196 padded to multiple of 32

typedef __attribute__((ext_vector_type(8))) short short8;
typedef __attribute__((ext_vector_type(4))) float f32x4;
typedef const __attribute__((address_space(1))) unsigned int* gas1_t;
typedef __attribute__((address_space(3))) unsigned int* las3_t;
typedef unsigned long long ull;

__device__ inline unsigned short f2bf(float f) {
    unsigned int u = __builtin_bit_cast(unsigned int, f);
    u += 0x7fffu + ((u >> 16) & 1u);  // round-to-nearest-even
    return (unsigned short)(u >> 16);
}
__device__ inline float bf2f(unsigned int lo16) {
    return __builtin_bit_cast(float, lo16 << 16);
}
__device__ inline unsigned f2sort(float f) {
    unsigned u = __builtin_bit_cast(unsigned, f);
    int msk = ((int)u) >> 31;
    return u ^ (unsigned)(msk | 0x80000000);
}

// ---------------- Weldon pooling v6: half-wave split + sorted heads ----------------
__global__ __launch_bounds__(256) void weldon_kernel(const float* __restrict__ g,
                                                     float* __restrict__ hpool) {
    int wid = (blockIdx.x * 256 + threadIdx.x) >> 6;
    int tlane = threadIdx.x & 63;
    int hl = tlane & 31;
    bool neg = tlane >= 32;
    const float* row = g + (size_t)wid * HW;
    float s[7];
#pragma unroll
    for (int q = 0; q < 7; q++) {
        int e = hl + 32 * q;
        if (e < HW) {
            unsigned u = __builtin_bit_cast(unsigned, row[e]);
            if (neg) u ^= 0x80000000u;                       // negate for bottom-15
            u = (u & 0xFFFFFF00u) | (unsigned)(q * 32 + hl); // unique id within half
            s[q] = __builtin_bit_cast(float, u);
        } else {
            s[q] = -INFINITY;
        }
    }
#define CS(a, b)                                   \
    {                                              \
        float hi = fmaxf(s[a], s[b]);              \
        float lo = fminf(s[a], s[b]);              \
        s[a] = hi; s[b] = lo;                      \
    }
    CS(1, 2) CS(3, 4) CS(5, 6)
    CS(0, 2) CS(3, 5) CS(4, 6)
    CS(0, 1) CS(4, 5) CS(2, 6)
    CS(0, 4) CS(1, 5)
    CS(0, 3) CS(2, 5)
    CS(1, 3) CS(2, 4)
    CS(2, 3)
#undef CS
    float acc = 0.f;
#pragma unroll
    for (int it = 0; it < NPOOL; ++it) {
        int x = __builtin_bit_cast(int, s[0]);
#define ST(c)                                                                  \
    {                                                                          \
        int y = __builtin_amdgcn_update_dpp(x, x, c, 0xf, 0xf, false);         \
        float a = fmaxf(__builtin_bit_cast(float, x), __builtin_bit_cast(float, y)); \
        x = __builtin_bit_cast(int, a);                                        \
    }
        ST(0x111) ST(0x112) ST(0x114) ST(0x118) ST(0x142)
#undef ST
        int m31 = __builtin_amdgcn_readlane(x, 31);
        int m63 = __builtin_amdgcn_readlane(x, 63);
        float msel = __builtin_bit_cast(float, neg ? m63 : m31);
        acc += msel;
        bool won = (__builtin_bit_cast(unsigned, s[0]) ==
                    __builtin_bit_cast(unsigned, msel));
        s[0] = won ? s[1] : s[0];
        s[1] = won ? s[2] : s[1];
        s[2] = won ? s[3] : s[2];
        s[3] = won ? s[4] : s[3];
        s[4] = won ? s[5] : s[4];
        s[5] = won ? s[6] : s[5];
        s[6] = won ? -INFINITY : s[6];
    }
    int ai = __builtin_bit_cast(int, acc);
    float a0 = __builtin_bit_cast(float, __builtin_amdgcn_readlane(ai, 0));
    float a32 = __builtin_bit_cast(float, __builtin_amdgcn_readlane(ai, 32));
    if (tlane == 0) hpool[wid] = (a0 - a32) / 15.0f;
}

// ---------------- fused: x = hpool @ fc_w.T + fc_b  AND  wbf = bf16(fc_w) ----------------
__global__ void xw_kernel(const float* __restrict__ hpool, const float* __restrict__ fc_w,
                          const float* __restrict__ fc_b, float* __restrict__ x_out,
                          unsigned short* __restrict__ wbf) {
    int o = blockIdx.x;
    int lane = threadIdx.x;  // 64
    float acc[IMGS];
#pragma unroll
    for (int i = 0; i < IMGS; i++) acc[i] = 0.f;
    const float* wrow = fc_w + (size_t)o * EMB;
    unsigned short* wdst = wbf + (size_t)o * EMB;
    for (int e = lane * 4; e < EMB; e += 256) {
        float4 wv = *(const float4*)&wrow[e];
        ushort4 r;
        r.x = f2bf(wv.x); r.y = f2bf(wv.y); r.z = f2bf(wv.z); r.w = f2bf(wv.w);
        *(ushort4*)&wdst[e] = r;
#pragma unroll
        for (int i = 0; i < IMGS; i++) {
            const float* hp = hpool + i * EMB + e;
            acc[i] += hp[0] * wv.x + hp[1] * wv.y + hp[2] * wv.z + hp[3] * wv.w;
        }
    }
#pragma unroll
    for (int i = 0; i < IMGS; i++) {
#pragma unroll
        for (int sdx = 32; sdx > 0; sdx >>= 1) acc[i] += __shfl_xor(acc[i], sdx, 64);
    }
    if (lane == 0) {
        float bo = fc_b[o];
#pragma unroll
        for (int i = 0; i < IMGS; i++) x_out[i * EMB + o] = acc[i] + bo;
    }
}

// ---------------- x (fallback, no wbf) ----------------
__global__ void x_kernel(const float* __restrict__ hpool, const float* __restrict__ fc_w,
                         const float* __restrict__ fc_b, float* __restrict__ x_out) {
    int o = blockIdx.x;
    int lane = threadIdx.x;
    float acc[IMGS];
#pragma unroll
    for (int i = 0; i < IMGS; i++) acc[i] = 0.f;
    const float* wrow = fc_w + (size_t)o * EMB;
    for (int e = lane; e < EMB; e += 64) {
        float wv = wrow[e];
#pragma unroll
        for (int i = 0; i < IMGS; i++) acc[i] += hpool[i * EMB + e] * wv;
    }
#pragma unroll
    for (int i = 0; i < IMGS; i++) {
#pragma unroll
        for (int sdx = 32; sdx > 0; sdx >>= 1) acc[i] += __shfl_xor(acc[i], sdx, 64);
    }
    if (lane == 0) {
        float bo = fc_b[o];
#pragma unroll
        for (int i = 0; i < IMGS; i++) x_out[i * EMB + o] = acc[i] + bo;
    }
}

// ---------------- topk v4: radix select with parallel bucket scan ----------------
__global__ __launch_bounds__(256) void topk_kernel(const float* __restrict__ caps,
                                                   int* __restrict__ idxs,
                                                   float* __restrict__ vals) {
    __shared__ float rowf[EMB];
    __shared__ unsigned hist[4][256];
    __shared__ unsigned scanbuf[256];
    __shared__ unsigned cnts[256];
    __shared__ ull sprefix;
    __shared__ int srank;
    int c = blockIdx.x;
    int tid = threadIdx.x;
    const float4* src = (const float4*)(caps + (size_t)c * EMB);
    for (int j = tid; j < EMB / 4; j += 256) {
        float4 v = src[j];
        *(float4*)&rowf[j * 4] = v;
    }
    if (tid == 0) { sprefix = 0ull; srank = ATTK; }

#pragma unroll 1
    for (int pass = 0; pass < 6; ++pass) {
        __syncthreads();
        ull pref = sprefix;
        int rk = srank;
        int shift = 40 - pass * 8;
        ull pmaskhi = (pass == 0) ? 0ull : ~((1ull << (shift + 8)) - 1ull);
        hist[0][tid] = 0; hist[1][tid] = 0; hist[2][tid] = 0; hist[3][tid] = 0;
        __syncthreads();
        unsigned* myhist = hist[tid >> 6];
#pragma unroll 1
        for (int s = 0; s < 10; s++) {
            int e = tid + s * 256;
            if (e < EMB) {
                ull key = ((ull)f2sort(rowf[e]) << 16) | ((unsigned)(2399 - e) << 4);
                if ((key & pmaskhi) == pref)
                    atomicAdd(&myhist[(unsigned)(key >> shift) & 255u], 1u);
            }
        }
        __syncthreads();
        unsigned h = hist[0][tid] + hist[1][tid] + hist[2][tid] + hist[3][tid];
        scanbuf[255 - tid] = h;
        __syncthreads();
#pragma unroll
        for (int d = 1; d < 256; d <<= 1) {
            unsigned add = (tid >= d) ? scanbuf[tid - d] : 0u;
            __syncthreads();
            scanbuf[tid] += add;
            __syncthreads();
        }
        unsigned incl = scanbuf[255 - tid];
        unsigned excl = incl - h;
        if (h > 0u && excl < (unsigned)rk && incl >= (unsigned)rk) {
            srank = rk - (int)excl;
            sprefix = pref | ((ull)tid << shift);
        }
    }
    __syncthreads();
    ull T = sprefix;
    unsigned selmask = 0, cnt = 0;
#pragma unroll 1
    for (int s = 0; s < 10; s++) {
        int e = tid + s * 256;
        if (e < EMB) {
            ull key = ((ull)f2sort(rowf[e]) << 16) | ((unsigned)(2399 - e) << 4);
            if (key >= T) { selmask |= 1u << s; cnt++; }
        }
    }
    cnts[tid] = cnt;
    __syncthreads();
#pragma unroll
    for (int d = 1; d < 256; d <<= 1) {
        unsigned add = (tid >= d) ? cnts[tid - d] : 0u;
        __syncthreads();
        cnts[tid] += add;
        __syncthreads();
    }
    unsigned slot = cnts[tid] - cnt;
#pragma unroll 1
    for (int s = 0; s < 10; s++) {
        if (selmask & (1u << s)) {
            int e = tid + s * 256;
            idxs[c * ATTK + slot] = e;
            vals[c * ATTK + slot] = fabsf(rowf[e]);
            slot++;
        }
    }
}

// ---------------- gT[n][e] = bf16(g[i(n)][e][hw(n)]) ----------------
__global__ void transpose_g_kernel(const float* __restrict__ g, unsigned short* __restrict__ gT) {
    __shared__ float t[96][50];
    int i = blockIdx.z;
    int e0 = blockIdx.y * 96;
    int h0 = blockIdx.x * 49;
    int tid = threadIdx.x;
    for (int f = tid; f < 96 * 49; f += 256) {
        int e = f / 49, hh = f % 49;
        t[e][hh] = g[(size_t)i * EMB * HW + (size_t)(e0 + e) * HW + h0 + hh];
    }
    __syncthreads();
    for (int f = tid; f < 49 * 96; f += 256) {
        int hh = f / 96, e = f % 96;
        gT[(size_t)(i * HW + h0 + hh) * EMB + e0 + e] = f2bf(t[e][hh]);
    }
}

// ======== NT bf16 MFMA GEMM, gll staging, 3-buffer counted-vmcnt pipeline ========
// r15 restructure: xa = Hraw @ Asig^T / S (W distributes over the heat sum), so
// gemm1 emits SIGNED Asig (OUT_MODE 6) and xa is a tiny batched GEMM (OUT_MODE 4:
// f32 v*invS[z*64+row] + bias[col]). ldb decouples B row stride from K so xa can
// read Asig image-slices (ldb=3136, bz=196, K=224; k>=196 reads finite garbage x
// Hn=0 = 0). T1 XCD swizzle + T2 swizzle + T4 counted vmcnt + T5 setprio kept.
template <int MF, int NF, int OUT_MODE>
__global__ __launch_bounds__(256) void gemm_gll(const unsigned short* __restrict__ A,
                                                const unsigned short* __restrict__ B,
                                                void* __restrict__ outp,
                                                const float* __restrict__ bias,
                                                const float* __restrict__ invS,
                                                int M, int N, int K, int ldb, int kper,
                                                long az, long bz) {
    constexpr int BM = MF * 32, BN = NF * 32;
    constexpr int ROWS = BM + BN;
    constexpr int RPAD = (ROWS + 63) & ~63;
    constexpr int NCALL = RPAD / 16;
    constexpr int LPW = NCALL / 4;
    __shared__ unsigned short lds[3][RPAD][32];
    int gx = gridDim.x, gy = gridDim.y;
    int nwg = gx * gy;
    int flat = blockIdx.y * gx + blockIdx.x;
    int qq = nwg >> 3, rr8 = nwg & 7;
    int xcd = flat & 7, idx = flat >> 3;
    int base = (xcd < rr8) ? xcd * (qq + 1) : rr8 * (qq + 1) + (xcd - rr8) * qq;
    int nf = base + idx;
    int m0 = (nf % gy) * BM;
    int n0 = (nf / gy) * BN;
    int z = blockIdx.z;
    const unsigned short* Ab = A + (size_t)z * az;
    const unsigned short* Bb = B + (size_t)z * bz;
    int kb = (az == 0 && bz == 0) ? z * kper : 0;
    int nt = kper / 32;
    int tid = threadIdx.x, w = tid >> 6, lane = tid & 63;
    int wm = (w >> 1) * (MF * 16), wn = (w & 1) * (NF * 16);
    int ln = lane & 15;
    int ks = (((lane >> 4) ^ ((lane >> 1) & 3))) * 8;
    int srow = lane >> 2;
    int skc = (((lane & 3) ^ ((lane >> 3) & 3))) * 8;

    auto STAGE = [&](int buf, int t) {
        int k0 = kb + t * 32;
#pragma unroll
        for (int j = 0; j < LPW; j++) {
            int jj = w + j * 4;
            int r = jj * 16 + srow;
            const unsigned short* src;
            if (r < BM) src = Ab + (size_t)(m0 + r) * K + k0 + skc;
            else if (r < ROWS) src = Bb + (size_t)(n0 + r - BM) * ldb + k0 + skc;
            else src = Ab + (size_t)m0 * K + k0 + skc;  // dummy (uniform vmcnt)
            __builtin_amdgcn_global_load_lds((gas1_t)(const void*)src,
                                             (las3_t)(void*)&lds[buf][jj * 16][0], 16, 0, 0);
        }
    };

    STAGE(0, 0);
    if (nt > 1) STAGE(1, 1);
    f32x4 acc[MF][NF] = {};
    for (int t = 0; t < nt; ++t) {
        if (t + 1 < nt) {
            if constexpr (LPW == 4) asm volatile("s_waitcnt vmcnt(4) lgkmcnt(0)" ::: "memory");
            else if constexpr (LPW == 5) asm volatile("s_waitcnt vmcnt(5) lgkmcnt(0)" ::: "memory");
            else if constexpr (LPW == 6) asm volatile("s_waitcnt vmcnt(6) lgkmcnt(0)" ::: "memory");
            else asm volatile("s_waitcnt vmcnt(0) lgkmcnt(0)" ::: "memory");
        } else {
            asm volatile("s_waitcnt vmcnt(0) lgkmcnt(0)" ::: "memory");
        }
        __builtin_amdgcn_s_barrier();
        __builtin_amdgcn_sched_barrier(0);  // rule #18
        if (t + 2 < nt) STAGE((t + 2) % 3, t + 2);
        const unsigned short(*buf)[32] = lds[t % 3];
        short8 af[MF], bfv[NF];
#pragma unroll
        for (int mf = 0; mf < MF; mf++)
            af[mf] = *(const short8*)&buf[wm + mf * 16 + ln][ks];
#pragma unroll
        for (int nfi = 0; nfi < NF; nfi++)
            bfv[nfi] = *(const short8*)&buf[BM + wn + nfi * 16 + ln][ks];
        __builtin_amdgcn_s_setprio(1);  // T5
#pragma unroll
        for (int mf = 0; mf < MF; mf++)
#pragma unroll
            for (int nfi = 0; nfi < NF; nfi++)
                acc[mf][nfi] = __builtin_amdgcn_mfma_f32_16x16x32_bf16(af[mf], bfv[nfi],
                                                                       acc[mf][nfi], 0, 0, 0);
        __builtin_amdgcn_s_setprio(0);
    }
#pragma unroll
    for (int mf = 0; mf < MF; mf++) {
#pragma unroll
        for (int nfi = 0; nfi < NF; nfi++) {
#pragma unroll
            for (int rr = 0; rr < 4; rr++) {
                int row = m0 + wm + mf * 16 + (lane >> 4) * 4 + rr;
                int col = n0 + wn + nfi * 16 + ln;
                float v = acc[mf][nfi][rr];
                if (OUT_MODE == 6) {
                    ((unsigned short*)outp)[(size_t)row * N + col] = f2bf(v);
                } else if (OUT_MODE == 4) {
                    ((float*)outp)[((size_t)z * CAPS + row) * N + col] =
                        v * invS[z * CAPS + row] + bias[col];
                }
            }
        }
    }
}

// ======== fallback reg-staged NT GEMM (gemm1 only; used if ws too small for wbf) ========
__device__ inline uint4 load8(const unsigned short* p) { return *(const uint4*)p; }
__device__ inline uint4 load8(const float* p) {
    float4 a = *(const float4*)p;
    float4 b = *(const float4*)(p + 4);
    uint4 r;
    r.x = (unsigned)f2bf(a.x) | ((unsigned)f2bf(a.y) << 16);
    r.y = (unsigned)f2bf(a.z) | ((unsigned)f2bf(a.w) << 16);
    r.z = (unsigned)f2bf(b.x) | ((unsigned)f2bf(b.y) << 16);
    r.w = (unsigned)f2bf(b.z) | ((unsigned)f2bf(b.w) << 16);
    return r;
}

template <int MF, int NF, typename TA, typename TB>
__global__ __launch_bounds__(256) void mfma_gemm_nt(const TA* __restrict__ A,
                                                    const TB* __restrict__ B,
                                                    void* __restrict__ outp,
                                                    int M, int N, int K) {
    constexpr int BM = MF * 32, BN = NF * 32;
    constexpr int nA = BM * 4, nTot = (BM + BN) * 4;
    constexpr int NCH = (nTot + 255) / 256;
    __shared__ unsigned short As[BM][40];
    __shared__ unsigned short Bs[BN][40];
    int m0 = blockIdx.y * BM, n0 = blockIdx.x * BN;
    int tid = threadIdx.x;
    int w = tid >> 6, lane = tid & 63;
    int wm = (w >> 1) * (MF * 16), wn = (w & 1) * (NF * 16);
    int ln = lane & 15, ks = (lane >> 4) * 8;
    uint4 r[NCH];
#pragma unroll
    for (int j = 0; j < NCH; j++) {
        int c = tid + 256 * j;
        if (c < nTot) {
            if (c < nA) {
                int row = c >> 2, kc = c & 3;
                r[j] = load8(A + (size_t)(m0 + row) * K + kc * 8);
            } else {
                int cc = c - nA, row = cc >> 2, kc = cc & 3;
                r[j] = load8(B + (size_t)(n0 + row) * K + kc * 8);
            }
        }
    }
    f32x4 acc[MF][NF] = {};
    for (int k0 = 0; k0 < K; k0 += 32) {
#pragma unroll
        for (int j = 0; j < NCH; j++) {
            int c = tid + 256 * j;
            if (c < nTot) {
                if (c < nA) {
                    int row = c >> 2, kc = c & 3;
                    *(uint4*)&As[row][kc * 8] = r[j];
                } else {
                    int cc = c - nA, row = cc >> 2, kc = cc & 3;
                    *(uint4*)&Bs[row][kc * 8] = r[j];
                }
            }
        }
        __syncthreads();
        if (k0 + 32 < K) {
#pragma unroll
            for (int j = 0; j < NCH; j++) {
                int c = tid + 256 * j;
                if (c < nTot) {
                    if (c < nA) {
                        int row = c >> 2, kc = c & 3;
                        r[j] = load8(A + (size_t)(m0 + row) * K + (k0 + 32) + kc * 8);
                    } else {
                        int cc = c - nA, row = cc >> 2, kc = cc & 3;
                        r[j] = load8(B + (size_t)(n0 + row) * K + (k0 + 32) + kc * 8);
                    }
                }
            }
        }
        short8 af[MF], bfv[NF];
#pragma unroll
        for (int mf = 0; mf < MF; mf++)
            af[mf] = *(const short8*)&As[wm + mf * 16 + ln][ks];
#pragma unroll
        for (int nfi = 0; nfi < NF; nfi++)
            bfv[nfi] = *(const short8*)&Bs[wn + nfi * 16 + ln][ks];
#pragma unroll
        for (int mf = 0; mf < MF; mf++)
#pragma unroll
            for (int nfi = 0; nfi < NF; nfi++)
                acc[mf][nfi] = __builtin_amdgcn_mfma_f32_16x16x32_bf16(af[mf], bfv[nfi],
                                                                       acc[mf][nfi], 0, 0, 0);
        __syncthreads();
    }
#pragma unroll
    for (int mf = 0; mf < MF; mf++) {
#pragma unroll
        for (int nfi = 0; nfi < NF; nfi++) {
#pragma unroll
            for (int rr = 0; rr < 4; rr++) {
                int row = m0 + wm + mf * 16 + (lane >> 4) * 4 + rr;
                int col = n0 + wn + nfi * 16 + ln;
                ((unsigned short*)outp)[(size_t)row * N + col] = f2bf(acc[mf][nfi][rr]);
            }
        }
    }
}

// ---------------- heat v3: Hraw[c,n] = sum_j vals*|Asig[idx,n]| -> bf16 padded layout ----------------
// Writes Hnbf[(i*64+c)*224 + hw] (pads pre-zeroed via memset). abs = clear sign bit.
__global__ __launch_bounds__(256) void heat_kernel(const int* __restrict__ idxs,
                                                   const float* __restrict__ vals,
                                                   const unsigned short* __restrict__ A,
                                                   unsigned short* __restrict__ Hnbf) {
    __shared__ int sidx[ATTK];
    __shared__ float sval[ATTK];
    int c = blockIdx.y;
    int tid = threadIdx.x;
    if (tid < ATTK) {
        sidx[tid] = idxs[c * ATTK + tid];
        sval[tid] = vals[c * ATTK + tid];
    }
    __syncthreads();
    int n = blockIdx.x * 256 + tid;
    if (n >= NCOLS) return;
    float a0 = 0.f, a1 = 0.f, a2 = 0.f, a3 = 0.f;
#pragma unroll 1
    for (int j = 0; j < ATTK; j += 4) {
        a0 += sval[j + 0] * bf2f(A[(size_t)sidx[j + 0] * NCOLS + n] & 0x7FFFu);
        a1 += sval[j + 1] * bf2f(A[(size_t)sidx[j + 1] * NCOLS + n] & 0x7FFFu);
        a2 += sval[j + 2] * bf2f(A[(size_t)sidx[j + 2] * NCOLS + n] & 0x7FFFu);
        a3 += sval[j + 3] * bf2f(A[(size_t)sidx[j + 3] * NCOLS + n] & 0x7FFFu);
    }
    int i = n / HW, hw = n % HW;
    Hnbf[((size_t)i * CAPS + c) * KPAD + hw] = f2bf((a0 + a1) + (a2 + a3));
}

// ---------------- rowsum: invS[i*64+c] = 1 / sum_hw Hraw ----------------
__global__ void rowsum_kernel(const unsigned short* __restrict__ Hnbf,
                              float* __restrict__ invS) {
    int b = blockIdx.x;  // i*64+c
    int lane = threadIdx.x;
    const unsigned short* p = Hnbf + (size_t)b * KPAD;
    float s = bf2f(p[lane]) + bf2f(p[lane + 64]) + bf2f(p[lane + 128]);
    if (lane < 32) s += bf2f(p[lane + 192]);  // pads are zero
#pragma unroll
    for (int d = 32; d > 0; d >>= 1) s += __shfl_xor(s, d, 64);
    if (lane == 0) invS[b] = 1.0f / s;
}

extern "C" void kernel_launch(void* const* d_in, const int* in_sizes, int n_in,
                              void* d_out, int out_size, void* d_ws, size_t ws_size,
                              hipStream_t stream) {
    const float* g = (const float*)d_in[0];
    const float* caps = (const float*)d_in[1];
    const float* fc_w = (const float*)d_in[2];
    const float* fc_b = (const float*)d_in[3];

    float* out = (float*)d_out;
    float* x_out = out;                    // 38400
    float* xa_out = out + 38400;           // 2457600
    float* g_out = out + 38400 + 2457600;  // 7526400 floats = 30.1 MB scratch until final copy
    // g_out: [Asig signed bf16 2400x3136 = 15.05MB][gT bf16 3136x2400 = 15.05MB] exact fit.
    // xa-gemm K-tail (k=196..223) reads past image slices: worst case 27 elems into gT
    // (initialized, finite) x Hn-pad=0 -> exact 0. No NaN risk.
    unsigned short* Asig = (unsigned short*)g_out;
    unsigned short* gT = Asig + (size_t)EMB * NCOLS;

    float* ws = (float*)d_ws;
    float* hpool = ws;                                       // 38400 f
    int* idxs = (int*)(ws + 38400);                          // 11520
    float* vals = ws + 49920;                                // 11520
    float* invS = ws + 61440;                                // 1024 f
    unsigned short* Hnbf = (unsigned short*)(ws + 62464);    // 16*64*224 = 229376 us
    unsigned short* wbf = (unsigned short*)(ws + 1490944);   // 5760000 us, ends byte 17483776
    bool use_wbf = ws_size >= (size_t)17483776;

    weldon_kernel<<<(IMGS * EMB) / 4, 256, 0, stream>>>(g, hpool);
    topk_kernel<<<CAPS, 256, 0, stream>>>(caps, idxs, vals);
    transpose_g_kernel<<<dim3(4, 25, IMGS), 256, 0, stream>>>(g, gT);

    if (use_wbf) {
        xw_kernel<<<EMB, 64, 0, stream>>>(hpool, fc_w, fc_b, x_out, wbf);
        // gemm1 (5,7): signed Asig; BM=160 (15), BN=224 (14) -> 210 blocks
        gemm_gll<5, 7, 6><<<dim3(NCOLS / 224, EMB / 160, 1), 256, 0, stream>>>(
            wbf, gT, Asig, nullptr, nullptr, EMB, NCOLS, EMB, EMB, EMB, 0, 0);
    } else {
        x_kernel<<<EMB, 64, 0, stream>>>(hpool, fc_w, fc_b, x_out);
        mfma_gemm_nt<5, 2, float, unsigned short>
            <<<dim3(NCOLS / 64, EMB / 160), 256, 0, stream>>>(fc_w, gT, Asig,
                                                              EMB, NCOLS, EMB);
    }
    // Hnbf pads must be zero (xa-gemm K-tail); memset then heat fills real cols
    hipMemsetAsync(Hnbf, 0, sizeof(unsigned short) * (size_t)IMGS * CAPS * KPAD, stream);
    heat_kernel<<<dim3((NCOLS + 255) / 256, CAPS), 256, 0, stream>>>(idxs, vals, Asig, Hnbf);
    rowsum_kernel<<<IMGS * CAPS, 64, 0, stream>>>(Hnbf, invS);
    // xa = (Hraw_i @ Asig_i^T) * invS + bias : per-image batched GEMM
    // A=Hnbf (stride K=224, az=64*224), B=Asig image slice (ldb=3136, bz=196), K=224
    gemm_gll<2, 5, 4><<<dim3(EMB / 160, 1, IMGS), 256, 0, stream>>>(
        Hnbf, Asig, xa_out, fc_b, invS, CAPS, EMB, KPAD, NCOLS, KPAD,
        (long)CAPS * KPAD, HW);
    // g passthrough last (overwrites Asig/gT)
    hipMemcpyAsync(g_out, g, sizeof(float) * (size_t)IMGS * EMB * HW,
                   hipMemcpyDeviceToDevice, stream);
}

// Round 16
// 165.759 us; speedup vs baseline: 1.6650x; 1.0440x over previous
//
#include <hip/hip_runtime.h>
#include <math.h>

#define IMGS 16
#define EMB 2400
#define HW 196
#define CAPS 64
#define ATTK 180
#define NPOOL 15
#define NCOLS (IMGS * HW)  // 3136
#define KPAD 224           // 196 padded to multiple of 32

typedef __attribute__((ext_vector_type(8))) short short8;
typedef __attribute__((ext_vector_type(4))) float f32x4;
typedef const __attribute__((address_space(1))) unsigned int* gas1_t;
typedef __attribute__((address_space(3))) unsigned int* las3_t;
typedef unsigned long long ull;

__device__ inline unsigned short f2bf(float f) {
    unsigned int u = __builtin_bit_cast(unsigned int, f);
    u += 0x7fffu + ((u >> 16) & 1u);  // round-to-nearest-even
    return (unsigned short)(u >> 16);
}
__device__ inline float bf2f(unsigned int lo16) {
    return __builtin_bit_cast(float, lo16 << 16);
}
__device__ inline unsigned f2sort(float f) {
    unsigned u = __builtin_bit_cast(unsigned, f);
    int msk = ((int)u) >> 31;
    return u ^ (unsigned)(msk | 0x80000000);
}

// ======== transpool: fused transpose_g + weldon (both read all of g; read ONCE) ========
// Block = (32 e-rows, one image) staged in LDS [32][197] (197: gcd with 32 banks = 1).
// Phase 1: coalesced g load. Phase 2: gT[n][e] bf16 write (32-e = 64B segments).
// Phase 3: weldon v6 per row from LDS: half-wave split (lanes 0-31 row, 32-63
// negated), Bose-Nelson sort-7 of per-lane values, 15 head extractions via 5-step
// DPP max; unique low-byte ids -> branch-free knockout. 8 rows/wave serial.
__global__ __launch_bounds__(256) void transpool_kernel(const float* __restrict__ g,
                                                        float* __restrict__ hpool,
                                                        unsigned short* __restrict__ gT) {
    __shared__ float t[32][197];
    int e0 = blockIdx.x * 32;
    int i = blockIdx.y;
    int tid = threadIdx.x;
    const float* base = g + ((size_t)i * EMB + e0) * HW;
    for (int f = tid; f < 32 * HW; f += 256) {
        int e = f / HW, hw = f % HW;
        t[e][hw] = base[(size_t)e * HW + hw];
    }
    __syncthreads();
    for (int f = tid; f < HW * 32; f += 256) {
        int hw = f / 32, e = f % 32;
        gT[((size_t)i * HW + hw) * EMB + e0 + e] = f2bf(t[e][hw]);
    }
    int w = tid >> 6, tl = tid & 63, hl = tl & 31;
    bool negh = tl >= 32;
#pragma unroll 1
    for (int rr = 0; rr < 8; ++rr) {
        int e = w * 8 + rr;
        float s[7];
#pragma unroll
        for (int q = 0; q < 7; q++) {
            int hw = hl + 32 * q;
            if (hw < HW) {
                unsigned u = __builtin_bit_cast(unsigned, t[e][hw]);
                if (negh) u ^= 0x80000000u;                      // negate for bottom-15
                u = (u & 0xFFFFFF00u) | (unsigned)(q * 32 + hl); // unique id within half
                s[q] = __builtin_bit_cast(float, u);
            } else {
                s[q] = -INFINITY;
            }
        }
#define CS(a, b)                                   \
    {                                              \
        float hi = fmaxf(s[a], s[b]);              \
        float lo = fminf(s[a], s[b]);              \
        s[a] = hi; s[b] = lo;                      \
    }
        CS(1, 2) CS(3, 4) CS(5, 6)
        CS(0, 2) CS(3, 5) CS(4, 6)
        CS(0, 1) CS(4, 5) CS(2, 6)
        CS(0, 4) CS(1, 5)
        CS(0, 3) CS(2, 5)
        CS(1, 3) CS(2, 4)
        CS(2, 3)
#undef CS
        float acc = 0.f;
#pragma unroll
        for (int it = 0; it < NPOOL; ++it) {
            int x = __builtin_bit_cast(int, s[0]);
#define ST(c)                                                                  \
    {                                                                          \
        int y = __builtin_amdgcn_update_dpp(x, x, c, 0xf, 0xf, false);         \
        float a = fmaxf(__builtin_bit_cast(float, x), __builtin_bit_cast(float, y)); \
        x = __builtin_bit_cast(int, a);                                        \
    }
            ST(0x111) ST(0x112) ST(0x114) ST(0x118) ST(0x142)
#undef ST
            int m31 = __builtin_amdgcn_readlane(x, 31);
            int m63 = __builtin_amdgcn_readlane(x, 63);
            float msel = __builtin_bit_cast(float, negh ? m63 : m31);
            acc += msel;
            bool won = (__builtin_bit_cast(unsigned, s[0]) ==
                        __builtin_bit_cast(unsigned, msel));
            s[0] = won ? s[1] : s[0];
            s[1] = won ? s[2] : s[1];
            s[2] = won ? s[3] : s[2];
            s[3] = won ? s[4] : s[3];
            s[4] = won ? s[5] : s[4];
            s[5] = won ? s[6] : s[5];
            s[6] = won ? -INFINITY : s[6];
        }
        int ai = __builtin_bit_cast(int, acc);
        float a0 = __builtin_bit_cast(float, __builtin_amdgcn_readlane(ai, 0));
        float a32 = __builtin_bit_cast(float, __builtin_amdgcn_readlane(ai, 32));
        if (tl == 0) hpool[(size_t)i * EMB + e0 + e] = (a0 - a32) / 15.0f;
    }
}

// ---------------- fused: x = hpool @ fc_w.T + fc_b  AND  wbf = bf16(fc_w) ----------------
__global__ void xw_kernel(const float* __restrict__ hpool, const float* __restrict__ fc_w,
                          const float* __restrict__ fc_b, float* __restrict__ x_out,
                          unsigned short* __restrict__ wbf) {
    int o = blockIdx.x;
    int lane = threadIdx.x;  // 64
    float acc[IMGS];
#pragma unroll
    for (int i = 0; i < IMGS; i++) acc[i] = 0.f;
    const float* wrow = fc_w + (size_t)o * EMB;
    unsigned short* wdst = wbf + (size_t)o * EMB;
    for (int e = lane * 4; e < EMB; e += 256) {
        float4 wv = *(const float4*)&wrow[e];
        ushort4 r;
        r.x = f2bf(wv.x); r.y = f2bf(wv.y); r.z = f2bf(wv.z); r.w = f2bf(wv.w);
        *(ushort4*)&wdst[e] = r;
#pragma unroll
        for (int i = 0; i < IMGS; i++) {
            const float* hp = hpool + i * EMB + e;
            acc[i] += hp[0] * wv.x + hp[1] * wv.y + hp[2] * wv.z + hp[3] * wv.w;
        }
    }
#pragma unroll
    for (int i = 0; i < IMGS; i++) {
#pragma unroll
        for (int sdx = 32; sdx > 0; sdx >>= 1) acc[i] += __shfl_xor(acc[i], sdx, 64);
    }
    if (lane == 0) {
        float bo = fc_b[o];
#pragma unroll
        for (int i = 0; i < IMGS; i++) x_out[i * EMB + o] = acc[i] + bo;
    }
}

// ---------------- x (fallback, no wbf) ----------------
__global__ void x_kernel(const float* __restrict__ hpool, const float* __restrict__ fc_w,
                         const float* __restrict__ fc_b, float* __restrict__ x_out) {
    int o = blockIdx.x;
    int lane = threadIdx.x;
    float acc[IMGS];
#pragma unroll
    for (int i = 0; i < IMGS; i++) acc[i] = 0.f;
    const float* wrow = fc_w + (size_t)o * EMB;
    for (int e = lane; e < EMB; e += 64) {
        float wv = wrow[e];
#pragma unroll
        for (int i = 0; i < IMGS; i++) acc[i] += hpool[i * EMB + e] * wv;
    }
#pragma unroll
    for (int i = 0; i < IMGS; i++) {
#pragma unroll
        for (int sdx = 32; sdx > 0; sdx >>= 1) acc[i] += __shfl_xor(acc[i], sdx, 64);
    }
    if (lane == 0) {
        float bo = fc_b[o];
#pragma unroll
        for (int i = 0; i < IMGS; i++) x_out[i * EMB + o] = acc[i] + bo;
    }
}

// ---------------- topk v5: radix select, wave-level scans (r15: ~18 barriers/pass -> ~6) ----------------
__global__ __launch_bounds__(256) void topk_kernel(const float* __restrict__ caps,
                                                   int* __restrict__ idxs,
                                                   float* __restrict__ vals) {
    __shared__ float rowf[EMB];
    __shared__ unsigned hist[4][256];
    __shared__ unsigned scanbuf[256];
    __shared__ unsigned wtot[4];
    __shared__ ull sprefix;
    __shared__ int srank;
    int c = blockIdx.x;
    int tid = threadIdx.x;
    int w = tid >> 6, lane = tid & 63;
    const float4* src = (const float4*)(caps + (size_t)c * EMB);
    for (int j = tid; j < EMB / 4; j += 256) {
        float4 v = src[j];
        *(float4*)&rowf[j * 4] = v;
    }
    if (tid == 0) { sprefix = 0ull; srank = ATTK; }

#pragma unroll 1
    for (int pass = 0; pass < 6; ++pass) {
        __syncthreads();
        ull pref = sprefix;
        int rk = srank;
        int shift = 40 - pass * 8;
        ull pmaskhi = (pass == 0) ? 0ull : ~((1ull << (shift + 8)) - 1ull);
        hist[0][tid] = 0; hist[1][tid] = 0; hist[2][tid] = 0; hist[3][tid] = 0;
        __syncthreads();
        unsigned* myhist = hist[w];
#pragma unroll 1
        for (int s = 0; s < 10; s++) {
            int e = tid + s * 256;
            if (e < EMB) {
                ull key = ((ull)f2sort(rowf[e]) << 16) | ((unsigned)(2399 - e) << 4);
                if ((key & pmaskhi) == pref)
                    atomicAdd(&myhist[(unsigned)(key >> shift) & 255u], 1u);
            }
        }
        __syncthreads();
        unsigned h = hist[0][tid] + hist[1][tid] + hist[2][tid] + hist[3][tid];
        scanbuf[255 - tid] = h;  // r-order: position tid holds bucket 255-tid
        __syncthreads();
        unsigned x = scanbuf[tid];
#pragma unroll
        for (int d = 1; d < 64; d <<= 1) {
            unsigned u = __shfl_up(x, d, 64);
            if (lane >= d) x += u;
        }
        if (lane == 63) wtot[w] = x;
        __syncthreads();
        unsigned off = 0;
        for (int ww = 0; ww < w; ww++) off += wtot[ww];
        scanbuf[tid] = x + off;  // inclusive scan in r-order
        __syncthreads();
        unsigned incl = scanbuf[255 - tid];  // sum of h over buckets >= tid
        unsigned excl = incl - h;
        if (h > 0u && excl < (unsigned)rk && incl >= (unsigned)rk) {
            srank = rk - (int)excl;
            sprefix = pref | ((ull)tid << shift);
        }
    }
    __syncthreads();
    ull T = sprefix;  // exact 180th-largest key
    unsigned selmask = 0, cnt = 0;
#pragma unroll 1
    for (int s = 0; s < 10; s++) {
        int e = tid + s * 256;
        if (e < EMB) {
            ull key = ((ull)f2sort(rowf[e]) << 16) | ((unsigned)(2399 - e) << 4);
            if (key >= T) { selmask |= 1u << s; cnt++; }
        }
    }
    unsigned x = cnt;
#pragma unroll
    for (int d = 1; d < 64; d <<= 1) {
        unsigned u = __shfl_up(x, d, 64);
        if (lane >= d) x += u;
    }
    if (lane == 63) wtot[w] = x;
    __syncthreads();
    unsigned off = 0;
    for (int ww = 0; ww < w; ww++) off += wtot[ww];
    unsigned slot = x + off - cnt;
#pragma unroll 1
    for (int s = 0; s < 10; s++) {
        if (selmask & (1u << s)) {
            int e = tid + s * 256;
            idxs[c * ATTK + slot] = e;
            vals[c * ATTK + slot] = fabsf(rowf[e]);
            slot++;
        }
    }
}

// ======== NT bf16 MFMA GEMM, gll staging, 3-buffer counted-vmcnt pipeline ========
// T1 bijective XCD swizzle + y-major; T2 source/read swizzle; T4 counted vmcnt;
// T5 setprio. OUT_MODE 6: signed bf16. OUT_MODE 4: f32 v*invS[z*64+row]+bias[col].
template <int MF, int NF, int OUT_MODE>
__global__ __launch_bounds__(256) void gemm_gll(const unsigned short* __restrict__ A,
                                                const unsigned short* __restrict__ B,
                                                void* __restrict__ outp,
                                                const float* __restrict__ bias,
                                                const float* __restrict__ invS,
                                                int M, int N, int K, int ldb, int kper,
                                                long az, long bz) {
    constexpr int BM = MF * 32, BN = NF * 32;
    constexpr int ROWS = BM + BN;
    constexpr int RPAD = (ROWS + 63) & ~63;
    constexpr int NCALL = RPAD / 16;
    constexpr int LPW = NCALL / 4;
    __shared__ unsigned short lds[3][RPAD][32];
    int gx = gridDim.x, gy = gridDim.y;
    int nwg = gx * gy;
    int flat = blockIdx.y * gx + blockIdx.x;
    int qq = nwg >> 3, rr8 = nwg & 7;
    int xcd = flat & 7, idx = flat >> 3;
    int base = (xcd < rr8) ? xcd * (qq + 1) : rr8 * (qq + 1) + (xcd - rr8) * qq;
    int nf = base + idx;
    int m0 = (nf % gy) * BM;
    int n0 = (nf / gy) * BN;
    int z = blockIdx.z;
    const unsigned short* Ab = A + (size_t)z * az;
    const unsigned short* Bb = B + (size_t)z * bz;
    int kb = (az == 0 && bz == 0) ? z * kper : 0;
    int nt = kper / 32;
    int tid = threadIdx.x, w = tid >> 6, lane = tid & 63;
    int wm = (w >> 1) * (MF * 16), wn = (w & 1) * (NF * 16);
    int ln = lane & 15;
    int ks = (((lane >> 4) ^ ((lane >> 1) & 3))) * 8;
    int srow = lane >> 2;
    int skc = (((lane & 3) ^ ((lane >> 3) & 3))) * 8;

    auto STAGE = [&](int buf, int t) {
        int k0 = kb + t * 32;
#pragma unroll
        for (int j = 0; j < LPW; j++) {
            int jj = w + j * 4;
            int r = jj * 16 + srow;
            const unsigned short* src;
            if (r < BM) src = Ab + (size_t)(m0 + r) * K + k0 + skc;
            else if (r < ROWS) src = Bb + (size_t)(n0 + r - BM) * ldb + k0 + skc;
            else src = Ab + (size_t)m0 * K + k0 + skc;  // dummy (uniform vmcnt)
            __builtin_amdgcn_global_load_lds((gas1_t)(const void*)src,
                                             (las3_t)(void*)&lds[buf][jj * 16][0], 16, 0, 0);
        }
    };

    STAGE(0, 0);
    if (nt > 1) STAGE(1, 1);
    f32x4 acc[MF][NF] = {};
    for (int t = 0; t < nt; ++t) {
        if (t + 1 < nt) {
            if constexpr (LPW == 4) asm volatile("s_waitcnt vmcnt(4) lgkmcnt(0)" ::: "memory");
            else if constexpr (LPW == 5) asm volatile("s_waitcnt vmcnt(5) lgkmcnt(0)" ::: "memory");
            else if constexpr (LPW == 6) asm volatile("s_waitcnt vmcnt(6) lgkmcnt(0)" ::: "memory");
            else asm volatile("s_waitcnt vmcnt(0) lgkmcnt(0)" ::: "memory");
        } else {
            asm volatile("s_waitcnt vmcnt(0) lgkmcnt(0)" ::: "memory");
        }
        __builtin_amdgcn_s_barrier();
        __builtin_amdgcn_sched_barrier(0);  // rule #18
        if (t + 2 < nt) STAGE((t + 2) % 3, t + 2);
        const unsigned short(*buf)[32] = lds[t % 3];
        short8 af[MF], bfv[NF];
#pragma unroll
        for (int mf = 0; mf < MF; mf++)
            af[mf] = *(const short8*)&buf[wm + mf * 16 + ln][ks];
#pragma unroll
        for (int nfi = 0; nfi < NF; nfi++)
            bfv[nfi] = *(const short8*)&buf[BM + wn + nfi * 16 + ln][ks];
        __builtin_amdgcn_s_setprio(1);  // T5
#pragma unroll
        for (int mf = 0; mf < MF; mf++)
#pragma unroll
            for (int nfi = 0; nfi < NF; nfi++)
                acc[mf][nfi] = __builtin_amdgcn_mfma_f32_16x16x32_bf16(af[mf], bfv[nfi],
                                                                       acc[mf][nfi], 0, 0, 0);
        __builtin_amdgcn_s_setprio(0);
    }
#pragma unroll
    for (int mf = 0; mf < MF; mf++) {
#pragma unroll
        for (int nfi = 0; nfi < NF; nfi++) {
#pragma unroll
            for (int rr = 0; rr < 4; rr++) {
                int row = m0 + wm + mf * 16 + (lane >> 4) * 4 + rr;
                int col = n0 + wn + nfi * 16 + ln;
                float v = acc[mf][nfi][rr];
                if (OUT_MODE == 6) {
                    ((unsigned short*)outp)[(size_t)row * N + col] = f2bf(v);
                } else if (OUT_MODE == 4) {
                    ((float*)outp)[((size_t)z * CAPS + row) * N + col] =
                        v * invS[z * CAPS + row] + bias[col];
                }
            }
        }
    }
}

// ======== fallback reg-staged NT GEMM (gemm1 only; used if ws too small for wbf) ========
__device__ inline uint4 load8(const unsigned short* p) { return *(const uint4*)p; }
__device__ inline uint4 load8(const float* p) {
    float4 a = *(const float4*)p;
    float4 b = *(const float4*)(p + 4);
    uint4 r;
    r.x = (unsigned)f2bf(a.x) | ((unsigned)f2bf(a.y) << 16);
    r.y = (unsigned)f2bf(a.z) | ((unsigned)f2bf(a.w) << 16);
    r.z = (unsigned)f2bf(b.x) | ((unsigned)f2bf(b.y) << 16);
    r.w = (unsigned)f2bf(b.z) | ((unsigned)f2bf(b.w) << 16);
    return r;
}

template <int MF, int NF, typename TA, typename TB>
__global__ __launch_bounds__(256) void mfma_gemm_nt(const TA* __restrict__ A,
                                                    const TB* __restrict__ B,
                                                    void* __restrict__ outp,
                                                    int M, int N, int K) {
    constexpr int BM = MF * 32, BN = NF * 32;
    constexpr int nA = BM * 4, nTot = (BM + BN) * 4;
    constexpr int NCH = (nTot + 255) / 256;
    __shared__ unsigned short As[BM][40];
    __shared__ unsigned short Bs[BN][40];
    int m0 = blockIdx.y * BM, n0 = blockIdx.x * BN;
    int tid = threadIdx.x;
    int w = tid >> 6, lane = tid & 63;
    int wm = (w >> 1) * (MF * 16), wn = (w & 1) * (NF * 16);
    int ln = lane & 15, ks = (lane >> 4) * 8;
    uint4 r[NCH];
#pragma unroll
    for (int j = 0; j < NCH; j++) {
        int c = tid + 256 * j;
        if (c < nTot) {
            if (c < nA) {
                int row = c >> 2, kc = c & 3;
                r[j] = load8(A + (size_t)(m0 + row) * K + kc * 8);
            } else {
                int cc = c - nA, row = cc >> 2, kc = cc & 3;
                r[j] = load8(B + (size_t)(n0 + row) * K + kc * 8);
            }
        }
    }
    f32x4 acc[MF][NF] = {};
    for (int k0 = 0; k0 < K; k0 += 32) {
#pragma unroll
        for (int j = 0; j < NCH; j++) {
            int c = tid + 256 * j;
            if (c < nTot) {
                if (c < nA) {
                    int row = c >> 2, kc = c & 3;
                    *(uint4*)&As[row][kc * 8] = r[j];
                } else {
                    int cc = c - nA, row = cc >> 2, kc = cc & 3;
                    *(uint4*)&Bs[row][kc * 8] = r[j];
                }
            }
        }
        __syncthreads();
        if (k0 + 32 < K) {
#pragma unroll
            for (int j = 0; j < NCH; j++) {
                int c = tid + 256 * j;
                if (c < nTot) {
                    if (c < nA) {
                        int row = c >> 2, kc = c & 3;
                        r[j] = load8(A + (size_t)(m0 + row) * K + (k0 + 32) + kc * 8);
                    } else {
                        int cc = c - nA, row = cc >> 2, kc = cc & 3;
                        r[j] = load8(B + (size_t)(n0 + row) * K + (k0 + 32) + kc * 8);
                    }
                }
            }
        }
        short8 af[MF], bfv[NF];
#pragma unroll
        for (int mf = 0; mf < MF; mf++)
            af[mf] = *(const short8*)&As[wm + mf * 16 + ln][ks];
#pragma unroll
        for (int nfi = 0; nfi < NF; nfi++)
            bfv[nfi] = *(const short8*)&Bs[wn + nfi * 16 + ln][ks];
#pragma unroll
        for (int mf = 0; mf < MF; mf++)
#pragma unroll
            for (int nfi = 0; nfi < NF; nfi++)
                acc[mf][nfi] = __builtin_amdgcn_mfma_f32_16x16x32_bf16(af[mf], bfv[nfi],
                                                                       acc[mf][nfi], 0, 0, 0);
        __syncthreads();
    }
#pragma unroll
    for (int mf = 0; mf < MF; mf++) {
#pragma unroll
        for (int nfi = 0; nfi < NF; nfi++) {
#pragma unroll
            for (int rr = 0; rr < 4; rr++) {
                int row = m0 + wm + mf * 16 + (lane >> 4) * 4 + rr;
                int col = n0 + wn + nfi * 16 + ln;
                ((unsigned short*)outp)[(size_t)row * N + col] = f2bf(acc[mf][nfi][rr]);
            }
        }
    }
}

// ---------------- heat v4: (i,c)-block; fused pad-zero + invS (kills memset+rowsum) ----------------
__global__ __launch_bounds__(256) void heat_kernel(const int* __restrict__ idxs,
                                                   const float* __restrict__ vals,
                                                   const unsigned short* __restrict__ A,
                                                   unsigned short* __restrict__ Hnbf,
                                                   float* __restrict__ invS) {
    __shared__ int sidx[ATTK];
    __shared__ float sval[ATTK];
    __shared__ float wsum[4];
    int i = blockIdx.x, c = blockIdx.y;
    int tid = threadIdx.x;
    int w = tid >> 6, lane = tid & 63;
    if (tid < ATTK) {
        sidx[tid] = idxs[c * ATTK + tid];
        sval[tid] = vals[c * ATTK + tid];
    }
    __syncthreads();
    int hw = tid;
    float v = 0.f;
    if (hw < HW) {
        int n = i * HW + hw;
        float a0 = 0.f, a1 = 0.f, a2 = 0.f, a3 = 0.f;
#pragma unroll 1
        for (int j = 0; j < ATTK; j += 4) {
            a0 += sval[j + 0] * bf2f(A[(size_t)sidx[j + 0] * NCOLS + n] & 0x7FFFu);
            a1 += sval[j + 1] * bf2f(A[(size_t)sidx[j + 1] * NCOLS + n] & 0x7FFFu);
            a2 += sval[j + 2] * bf2f(A[(size_t)sidx[j + 2] * NCOLS + n] & 0x7FFFu);
            a3 += sval[j + 3] * bf2f(A[(size_t)sidx[j + 3] * NCOLS + n] & 0x7FFFu);
        }
        v = (a0 + a1) + (a2 + a3);
    }
    if (hw < KPAD)
        Hnbf[((size_t)i * CAPS + c) * KPAD + hw] = (hw < HW) ? f2bf(v) : (unsigned short)0;
    // block-reduce f32 row sum -> invS
    float s = v;
#pragma unroll
    for (int d = 32; d > 0; d >>= 1) s += __shfl_xor(s, d, 64);
    if (lane == 0) wsum[w] = s;
    __syncthreads();
    if (tid == 0)
        invS[i * CAPS + c] = 1.0f / (wsum[0] + wsum[1] + wsum[2] + wsum[3]);
}

extern "C" void kernel_launch(void* const* d_in, const int* in_sizes, int n_in,
                              void* d_out, int out_size, void* d_ws, size_t ws_size,
                              hipStream_t stream) {
    const float* g = (const float*)d_in[0];
    const float* caps = (const float*)d_in[1];
    const float* fc_w = (const float*)d_in[2];
    const float* fc_b = (const float*)d_in[3];

    float* out = (float*)d_out;
    float* x_out = out;                    // 38400
    float* xa_out = out + 38400;           // 2457600
    float* g_out = out + 38400 + 2457600;  // 7526400 floats = 30.1 MB scratch until final copy
    // g_out: [Asig signed bf16 2400x3136][gT bf16 3136x2400] exact fit. xa-gemm K-tail
    // (k=196..223) reads <=27 elems past an image slice into initialized finite data
    // x Hn-pad=0 -> exact 0.
    unsigned short* Asig = (unsigned short*)g_out;
    unsigned short* gT = Asig + (size_t)EMB * NCOLS;

    float* ws = (float*)d_ws;
    float* hpool = ws;                                       // 38400 f
    int* idxs = (int*)(ws + 38400);                          // 11520
    float* vals = ws + 49920;                                // 11520
    float* invS = ws + 61440;                                // 1024 f
    unsigned short* Hnbf = (unsigned short*)(ws + 62464);    // 16*64*224 us
    unsigned short* wbf = (unsigned short*)(ws + 1490944);   // ends byte 17483776
    bool use_wbf = ws_size >= (size_t)17483776;

    transpool_kernel<<<dim3(EMB / 32, IMGS), 256, 0, stream>>>(g, hpool, gT);
    topk_kernel<<<CAPS, 256, 0, stream>>>(caps, idxs, vals);

    if (use_wbf) {
        xw_kernel<<<EMB, 64, 0, stream>>>(hpool, fc_w, fc_b, x_out, wbf);
        // gemm1 (5,7): signed Asig; BM=160 (15), BN=224 (14) -> 210 blocks
        gemm_gll<5, 7, 6><<<dim3(NCOLS / 224, EMB / 160, 1), 256, 0, stream>>>(
            wbf, gT, Asig, nullptr, nullptr, EMB, NCOLS, EMB, EMB, EMB, 0, 0);
    } else {
        x_kernel<<<EMB, 64, 0, stream>>>(hpool, fc_w, fc_b, x_out);
        mfma_gemm_nt<5, 2, float, unsigned short>
            <<<dim3(NCOLS / 64, EMB / 160), 256, 0, stream>>>(fc_w, gT, Asig,
                                                              EMB, NCOLS, EMB);
    }
    heat_kernel<<<dim3(IMGS, CAPS), 256, 0, stream>>>(idxs, vals, Asig, Hnbf, invS);
    // xa = (Hraw_i @ Asig_i^T) * invS + bias : per-image batched GEMM
    gemm_gll<2, 5, 4><<<dim3(EMB / 160, 1, IMGS), 256, 0, stream>>>(
        Hnbf, Asig, xa_out, fc_b, invS, CAPS, EMB, KPAD, NCOLS, KPAD,
        (long)CAPS * KPAD, HW);
    // g passthrough last (overwrites Asig/gT)
    hipMemcpyAsync(g_out, g, sizeof(float) * (size_t)IMGS * EMB * HW,
                   hipMemcpyDeviceToDevice, stream);
}

// Round 17
// 158.828 us; speedup vs baseline: 1.7377x; 1.0436x over previous
//
#include <hip/hip_runtime.h>
#include <math.h>

#define IMGS 16
#define EMB 2400
#define HW 196
#define CAPS 64
#define ATTK 180
#define NPOOL 15
#define NCOLS (IMGS * HW)  // 3136
#define KPAD 224           // 196 padded to multiple of 32

typedef __attribute__((ext_vector_type(8))) short short8;
typedef __attribute__((ext_vector_type(4))) float f32x4;
typedef const __attribute__((address_space(1))) unsigned int* gas1_t;
typedef __attribute__((address_space(3))) unsigned int* las3_t;
typedef unsigned long long ull;

__device__ inline unsigned short f2bf(float f) {
    unsigned int u = __builtin_bit_cast(unsigned int, f);
    u += 0x7fffu + ((u >> 16) & 1u);  // round-to-nearest-even
    return (unsigned short)(u >> 16);
}
__device__ inline float bf2f(unsigned int lo16) {
    return __builtin_bit_cast(float, lo16 << 16);
}
__device__ inline unsigned f2sort(float f) {
    unsigned u = __builtin_bit_cast(unsigned, f);
    int msk = ((int)u) >> 31;
    return u ^ (unsigned)(msk | 0x80000000);
}

// ======== transpool: fused transpose_g + weldon (+ optional g passthrough) ========
// Block = (32 e-rows, one image) in LDS [32][197] (stride 197 -> conflict-free cols).
// If gout != null, the staged values are also written to g_out (fp32 copy) --
// eliminates the end-of-pipeline 60MB memcpy (big-ws tier).
__global__ __launch_bounds__(256) void transpool_kernel(const float* __restrict__ g,
                                                        float* __restrict__ hpool,
                                                        unsigned short* __restrict__ gT,
                                                        float* __restrict__ gout) {
    __shared__ float t[32][197];
    int e0 = blockIdx.x * 32;
    int i = blockIdx.y;
    int tid = threadIdx.x;
    const float* base = g + ((size_t)i * EMB + e0) * HW;
    float* obase = gout ? gout + ((size_t)i * EMB + e0) * HW : nullptr;
    for (int f = tid; f < 32 * HW; f += 256) {
        int e = f / HW, hw = f % HW;
        float v = base[(size_t)e * HW + hw];
        t[e][hw] = v;
        if (obase) obase[(size_t)e * HW + hw] = v;
    }
    __syncthreads();
    for (int f = tid; f < HW * 32; f += 256) {
        int hw = f / 32, e = f % 32;
        gT[((size_t)i * HW + hw) * EMB + e0 + e] = f2bf(t[e][hw]);
    }
    int w = tid >> 6, tl = tid & 63, hl = tl & 31;
    bool negh = tl >= 32;
#pragma unroll 1
    for (int rr = 0; rr < 8; ++rr) {
        int e = w * 8 + rr;
        float s[7];
#pragma unroll
        for (int q = 0; q < 7; q++) {
            int hw = hl + 32 * q;
            if (hw < HW) {
                unsigned u = __builtin_bit_cast(unsigned, t[e][hw]);
                if (negh) u ^= 0x80000000u;                      // negate for bottom-15
                u = (u & 0xFFFFFF00u) | (unsigned)(q * 32 + hl); // unique id within half
                s[q] = __builtin_bit_cast(float, u);
            } else {
                s[q] = -INFINITY;
            }
        }
#define CS(a, b)                                   \
    {                                              \
        float hi = fmaxf(s[a], s[b]);              \
        float lo = fminf(s[a], s[b]);              \
        s[a] = hi; s[b] = lo;                      \
    }
        CS(1, 2) CS(3, 4) CS(5, 6)
        CS(0, 2) CS(3, 5) CS(4, 6)
        CS(0, 1) CS(4, 5) CS(2, 6)
        CS(0, 4) CS(1, 5)
        CS(0, 3) CS(2, 5)
        CS(1, 3) CS(2, 4)
        CS(2, 3)
#undef CS
        float acc = 0.f;
#pragma unroll
        for (int it = 0; it < NPOOL; ++it) {
            int x = __builtin_bit_cast(int, s[0]);
#define ST(c)                                                                  \
    {                                                                          \
        int y = __builtin_amdgcn_update_dpp(x, x, c, 0xf, 0xf, false);         \
        float a = fmaxf(__builtin_bit_cast(float, x), __builtin_bit_cast(float, y)); \
        x = __builtin_bit_cast(int, a);                                        \
    }
            ST(0x111) ST(0x112) ST(0x114) ST(0x118) ST(0x142)
#undef ST
            int m31 = __builtin_amdgcn_readlane(x, 31);
            int m63 = __builtin_amdgcn_readlane(x, 63);
            float msel = __builtin_bit_cast(float, negh ? m63 : m31);
            acc += msel;
            bool won = (__builtin_bit_cast(unsigned, s[0]) ==
                        __builtin_bit_cast(unsigned, msel));
            s[0] = won ? s[1] : s[0];
            s[1] = won ? s[2] : s[1];
            s[2] = won ? s[3] : s[2];
            s[3] = won ? s[4] : s[3];
            s[4] = won ? s[5] : s[4];
            s[5] = won ? s[6] : s[5];
            s[6] = won ? -INFINITY : s[6];
        }
        int ai = __builtin_bit_cast(int, acc);
        float a0 = __builtin_bit_cast(float, __builtin_amdgcn_readlane(ai, 0));
        float a32 = __builtin_bit_cast(float, __builtin_amdgcn_readlane(ai, 32));
        if (tl == 0) hpool[(size_t)i * EMB + e0 + e] = (a0 - a32) / 15.0f;
    }
}

// ---------------- fused: x = hpool @ fc_w.T + fc_b  AND  wbf = bf16(fc_w) ----------------
// 256 threads = 4 waves; wave w owns output column o0+w. 600 blocks (was 2400x1-wave).
__global__ __launch_bounds__(256) void xw_kernel(const float* __restrict__ hpool,
                                                 const float* __restrict__ fc_w,
                                                 const float* __restrict__ fc_b,
                                                 float* __restrict__ x_out,
                                                 unsigned short* __restrict__ wbf) {
    int o = blockIdx.x * 4 + (threadIdx.x >> 6);
    int lane = threadIdx.x & 63;
    float acc[IMGS];
#pragma unroll
    for (int i = 0; i < IMGS; i++) acc[i] = 0.f;
    const float* wrow = fc_w + (size_t)o * EMB;
    unsigned short* wdst = wbf + (size_t)o * EMB;
    for (int e = lane * 4; e < EMB; e += 256) {
        float4 wv = *(const float4*)&wrow[e];
        ushort4 r;
        r.x = f2bf(wv.x); r.y = f2bf(wv.y); r.z = f2bf(wv.z); r.w = f2bf(wv.w);
        *(ushort4*)&wdst[e] = r;
#pragma unroll
        for (int i = 0; i < IMGS; i++) {
            const float* hp = hpool + i * EMB + e;
            acc[i] += hp[0] * wv.x + hp[1] * wv.y + hp[2] * wv.z + hp[3] * wv.w;
        }
    }
#pragma unroll
    for (int i = 0; i < IMGS; i++) {
#pragma unroll
        for (int sdx = 32; sdx > 0; sdx >>= 1) acc[i] += __shfl_xor(acc[i], sdx, 64);
    }
    if (lane == 0) {
        float bo = fc_b[o];
#pragma unroll
        for (int i = 0; i < IMGS; i++) x_out[i * EMB + o] = acc[i] + bo;
    }
}

// ---------------- x (fallback, no wbf) ----------------
__global__ void x_kernel(const float* __restrict__ hpool, const float* __restrict__ fc_w,
                         const float* __restrict__ fc_b, float* __restrict__ x_out) {
    int o = blockIdx.x;
    int lane = threadIdx.x;
    float acc[IMGS];
#pragma unroll
    for (int i = 0; i < IMGS; i++) acc[i] = 0.f;
    const float* wrow = fc_w + (size_t)o * EMB;
    for (int e = lane; e < EMB; e += 64) {
        float wv = wrow[e];
#pragma unroll
        for (int i = 0; i < IMGS; i++) acc[i] += hpool[i * EMB + e] * wv;
    }
#pragma unroll
    for (int i = 0; i < IMGS; i++) {
#pragma unroll
        for (int sdx = 32; sdx > 0; sdx >>= 1) acc[i] += __shfl_xor(acc[i], sdx, 64);
    }
    if (lane == 0) {
        float bo = fc_b[o];
#pragma unroll
        for (int i = 0; i < IMGS; i++) x_out[i * EMB + o] = acc[i] + bo;
    }
}

// ---------------- topk v5: radix select, wave-level scans ----------------
__global__ __launch_bounds__(256) void topk_kernel(const float* __restrict__ caps,
                                                   int* __restrict__ idxs,
                                                   float* __restrict__ vals) {
    __shared__ float rowf[EMB];
    __shared__ unsigned hist[4][256];
    __shared__ unsigned scanbuf[256];
    __shared__ unsigned wtot[4];
    __shared__ ull sprefix;
    __shared__ int srank;
    int c = blockIdx.x;
    int tid = threadIdx.x;
    int w = tid >> 6, lane = tid & 63;
    const float4* src = (const float4*)(caps + (size_t)c * EMB);
    for (int j = tid; j < EMB / 4; j += 256) {
        float4 v = src[j];
        *(float4*)&rowf[j * 4] = v;
    }
    if (tid == 0) { sprefix = 0ull; srank = ATTK; }

#pragma unroll 1
    for (int pass = 0; pass < 6; ++pass) {
        __syncthreads();
        ull pref = sprefix;
        int rk = srank;
        int shift = 40 - pass * 8;
        ull pmaskhi = (pass == 0) ? 0ull : ~((1ull << (shift + 8)) - 1ull);
        hist[0][tid] = 0; hist[1][tid] = 0; hist[2][tid] = 0; hist[3][tid] = 0;
        __syncthreads();
        unsigned* myhist = hist[w];
#pragma unroll 1
        for (int s = 0; s < 10; s++) {
            int e = tid + s * 256;
            if (e < EMB) {
                ull key = ((ull)f2sort(rowf[e]) << 16) | ((unsigned)(2399 - e) << 4);
                if ((key & pmaskhi) == pref)
                    atomicAdd(&myhist[(unsigned)(key >> shift) & 255u], 1u);
            }
        }
        __syncthreads();
        unsigned h = hist[0][tid] + hist[1][tid] + hist[2][tid] + hist[3][tid];
        scanbuf[255 - tid] = h;
        __syncthreads();
        unsigned x = scanbuf[tid];
#pragma unroll
        for (int d = 1; d < 64; d <<= 1) {
            unsigned u = __shfl_up(x, d, 64);
            if (lane >= d) x += u;
        }
        if (lane == 63) wtot[w] = x;
        __syncthreads();
        unsigned off = 0;
        for (int ww = 0; ww < w; ww++) off += wtot[ww];
        scanbuf[tid] = x + off;
        __syncthreads();
        unsigned incl = scanbuf[255 - tid];
        unsigned excl = incl - h;
        if (h > 0u && excl < (unsigned)rk && incl >= (unsigned)rk) {
            srank = rk - (int)excl;
            sprefix = pref | ((ull)tid << shift);
        }
    }
    __syncthreads();
    ull T = sprefix;
    unsigned selmask = 0, cnt = 0;
#pragma unroll 1
    for (int s = 0; s < 10; s++) {
        int e = tid + s * 256;
        if (e < EMB) {
            ull key = ((ull)f2sort(rowf[e]) << 16) | ((unsigned)(2399 - e) << 4);
            if (key >= T) { selmask |= 1u << s; cnt++; }
        }
    }
    unsigned x = cnt;
#pragma unroll
    for (int d = 1; d < 64; d <<= 1) {
        unsigned u = __shfl_up(x, d, 64);
        if (lane >= d) x += u;
    }
    if (lane == 63) wtot[w] = x;
    __syncthreads();
    unsigned off = 0;
    for (int ww = 0; ww < w; ww++) off += wtot[ww];
    unsigned slot = x + off - cnt;
#pragma unroll 1
    for (int s = 0; s < 10; s++) {
        if (selmask & (1u << s)) {
            int e = tid + s * 256;
            idxs[c * ATTK + slot] = e;
            vals[c * ATTK + slot] = fabsf(rowf[e]);
            slot++;
        }
    }
}

// ======== NT bf16 MFMA GEMM, gll staging, 3-buffer counted-vmcnt pipeline ========
// T1 bijective XCD swizzle + y-major; T2 source/read swizzle; T4 counted vmcnt;
// T5 setprio. OUT_MODE 6: signed bf16. OUT_MODE 4: f32 v*invS[z*64+row]+bias[col].
template <int MF, int NF, int OUT_MODE>
__global__ __launch_bounds__(256) void gemm_gll(const unsigned short* __restrict__ A,
                                                const unsigned short* __restrict__ B,
                                                void* __restrict__ outp,
                                                const float* __restrict__ bias,
                                                const float* __restrict__ invS,
                                                int M, int N, int K, int ldb, int kper,
                                                long az, long bz) {
    constexpr int BM = MF * 32, BN = NF * 32;
    constexpr int ROWS = BM + BN;
    constexpr int RPAD = (ROWS + 63) & ~63;
    constexpr int NCALL = RPAD / 16;
    constexpr int LPW = NCALL / 4;
    __shared__ unsigned short lds[3][RPAD][32];
    int gx = gridDim.x, gy = gridDim.y;
    int nwg = gx * gy;
    int flat = blockIdx.y * gx + blockIdx.x;
    int qq = nwg >> 3, rr8 = nwg & 7;
    int xcd = flat & 7, idx = flat >> 3;
    int base = (xcd < rr8) ? xcd * (qq + 1) : rr8 * (qq + 1) + (xcd - rr8) * qq;
    int nf = base + idx;
    int m0 = (nf % gy) * BM;
    int n0 = (nf / gy) * BN;
    int z = blockIdx.z;
    const unsigned short* Ab = A + (size_t)z * az;
    const unsigned short* Bb = B + (size_t)z * bz;
    int kb = (az == 0 && bz == 0) ? z * kper : 0;
    int nt = kper / 32;
    int tid = threadIdx.x, w = tid >> 6, lane = tid & 63;
    int wm = (w >> 1) * (MF * 16), wn = (w & 1) * (NF * 16);
    int ln = lane & 15;
    int ks = (((lane >> 4) ^ ((lane >> 1) & 3))) * 8;
    int srow = lane >> 2;
    int skc = (((lane & 3) ^ ((lane >> 3) & 3))) * 8;

    auto STAGE = [&](int buf, int t) {
        int k0 = kb + t * 32;
#pragma unroll
        for (int j = 0; j < LPW; j++) {
            int jj = w + j * 4;
            int r = jj * 16 + srow;
            const unsigned short* src;
            if (r < BM) src = Ab + (size_t)(m0 + r) * K + k0 + skc;
            else if (r < ROWS) src = Bb + (size_t)(n0 + r - BM) * ldb + k0 + skc;
            else src = Ab + (size_t)m0 * K + k0 + skc;  // dummy (uniform vmcnt)
            __builtin_amdgcn_global_load_lds((gas1_t)(const void*)src,
                                             (las3_t)(void*)&lds[buf][jj * 16][0], 16, 0, 0);
        }
    };

    STAGE(0, 0);
    if (nt > 1) STAGE(1, 1);
    f32x4 acc[MF][NF] = {};
    for (int t = 0; t < nt; ++t) {
        if (t + 1 < nt) {
            if constexpr (LPW == 4) asm volatile("s_waitcnt vmcnt(4) lgkmcnt(0)" ::: "memory");
            else if constexpr (LPW == 5) asm volatile("s_waitcnt vmcnt(5) lgkmcnt(0)" ::: "memory");
            else if constexpr (LPW == 6) asm volatile("s_waitcnt vmcnt(6) lgkmcnt(0)" ::: "memory");
            else asm volatile("s_waitcnt vmcnt(0) lgkmcnt(0)" ::: "memory");
        } else {
            asm volatile("s_waitcnt vmcnt(0) lgkmcnt(0)" ::: "memory");
        }
        __builtin_amdgcn_s_barrier();
        __builtin_amdgcn_sched_barrier(0);  // rule #18
        if (t + 2 < nt) STAGE((t + 2) % 3, t + 2);
        const unsigned short(*buf)[32] = lds[t % 3];
        short8 af[MF], bfv[NF];
#pragma unroll
        for (int mf = 0; mf < MF; mf++)
            af[mf] = *(const short8*)&buf[wm + mf * 16 + ln][ks];
#pragma unroll
        for (int nfi = 0; nfi < NF; nfi++)
            bfv[nfi] = *(const short8*)&buf[BM + wn + nfi * 16 + ln][ks];
        __builtin_amdgcn_s_setprio(1);  // T5
#pragma unroll
        for (int mf = 0; mf < MF; mf++)
#pragma unroll
            for (int nfi = 0; nfi < NF; nfi++)
                acc[mf][nfi] = __builtin_amdgcn_mfma_f32_16x16x32_bf16(af[mf], bfv[nfi],
                                                                       acc[mf][nfi], 0, 0, 0);
        __builtin_amdgcn_s_setprio(0);
    }
#pragma unroll
    for (int mf = 0; mf < MF; mf++) {
#pragma unroll
        for (int nfi = 0; nfi < NF; nfi++) {
#pragma unroll
            for (int rr = 0; rr < 4; rr++) {
                int row = m0 + wm + mf * 16 + (lane >> 4) * 4 + rr;
                int col = n0 + wn + nfi * 16 + ln;
                float v = acc[mf][nfi][rr];
                if (OUT_MODE == 6) {
                    ((unsigned short*)outp)[(size_t)row * N + col] = f2bf(v);
                } else if (OUT_MODE == 4) {
                    ((float*)outp)[((size_t)z * CAPS + row) * N + col] =
                        v * invS[z * CAPS + row] + bias[col];
                }
            }
        }
    }
}

// ======== fallback reg-staged NT GEMM (gemm1 only; used if ws too small for wbf) ========
__device__ inline uint4 load8(const unsigned short* p) { return *(const uint4*)p; }
__device__ inline uint4 load8(const float* p) {
    float4 a = *(const float4*)p;
    float4 b = *(const float4*)(p + 4);
    uint4 r;
    r.x = (unsigned)f2bf(a.x) | ((unsigned)f2bf(a.y) << 16);
    r.y = (unsigned)f2bf(a.z) | ((unsigned)f2bf(a.w) << 16);
    r.z = (unsigned)f2bf(b.x) | ((unsigned)f2bf(b.y) << 16);
    r.w = (unsigned)f2bf(b.z) | ((unsigned)f2bf(b.w) << 16);
    return r;
}

template <int MF, int NF, typename TA, typename TB>
__global__ __launch_bounds__(256) void mfma_gemm_nt(const TA* __restrict__ A,
                                                    const TB* __restrict__ B,
                                                    void* __restrict__ outp,
                                                    int M, int N, int K) {
    constexpr int BM = MF * 32, BN = NF * 32;
    constexpr int nA = BM * 4, nTot = (BM + BN) * 4;
    constexpr int NCH = (nTot + 255) / 256;
    __shared__ unsigned short As[BM][40];
    __shared__ unsigned short Bs[BN][40];
    int m0 = blockIdx.y * BM, n0 = blockIdx.x * BN;
    int tid = threadIdx.x;
    int w = tid >> 6, lane = tid & 63;
    int wm = (w >> 1) * (MF * 16), wn = (w & 1) * (NF * 16);
    int ln = lane & 15, ks = (lane >> 4) * 8;
    uint4 r[NCH];
#pragma unroll
    for (int j = 0; j < NCH; j++) {
        int c = tid + 256 * j;
        if (c < nTot) {
            if (c < nA) {
                int row = c >> 2, kc = c & 3;
                r[j] = load8(A + (size_t)(m0 + row) * K + kc * 8);
            } else {
                int cc = c - nA, row = cc >> 2, kc = cc & 3;
                r[j] = load8(B + (size_t)(n0 + row) * K + kc * 8);
            }
        }
    }
    f32x4 acc[MF][NF] = {};
    for (int k0 = 0; k0 < K; k0 += 32) {
#pragma unroll
        for (int j = 0; j < NCH; j++) {
            int c = tid + 256 * j;
            if (c < nTot) {
                if (c < nA) {
                    int row = c >> 2, kc = c & 3;
                    *(uint4*)&As[row][kc * 8] = r[j];
                } else {
                    int cc = c - nA, row = cc >> 2, kc = cc & 3;
                    *(uint4*)&Bs[row][kc * 8] = r[j];
                }
            }
        }
        __syncthreads();
        if (k0 + 32 < K) {
#pragma unroll
            for (int j = 0; j < NCH; j++) {
                int c = tid + 256 * j;
                if (c < nTot) {
                    if (c < nA) {
                        int row = c >> 2, kc = c & 3;
                        r[j] = load8(A + (size_t)(m0 + row) * K + (k0 + 32) + kc * 8);
                    } else {
                        int cc = c - nA, row = cc >> 2, kc = cc & 3;
                        r[j] = load8(B + (size_t)(n0 + row) * K + (k0 + 32) + kc * 8);
                    }
                }
            }
        }
        short8 af[MF], bfv[NF];
#pragma unroll
        for (int mf = 0; mf < MF; mf++)
            af[mf] = *(const short8*)&As[wm + mf * 16 + ln][ks];
#pragma unroll
        for (int nfi = 0; nfi < NF; nfi++)
            bfv[nfi] = *(const short8*)&Bs[wn + nfi * 16 + ln][ks];
#pragma unroll
        for (int mf = 0; mf < MF; mf++)
#pragma unroll
            for (int nfi = 0; nfi < NF; nfi++)
                acc[mf][nfi] = __builtin_amdgcn_mfma_f32_16x16x32_bf16(af[mf], bfv[nfi],
                                                                       acc[mf][nfi], 0, 0, 0);
        __syncthreads();
    }
#pragma unroll
    for (int mf = 0; mf < MF; mf++) {
#pragma unroll
        for (int nfi = 0; nfi < NF; nfi++) {
#pragma unroll
            for (int rr = 0; rr < 4; rr++) {
                int row = m0 + wm + mf * 16 + (lane >> 4) * 4 + rr;
                int col = n0 + wn + nfi * 16 + ln;
                ((unsigned short*)outp)[(size_t)row * N + col] = f2bf(acc[mf][nfi][rr]);
            }
        }
    }
}

// ---------------- heat v4: (i,c)-block; fused pad-zero + invS ----------------
__global__ __launch_bounds__(256) void heat_kernel(const int* __restrict__ idxs,
                                                   const float* __restrict__ vals,
                                                   const unsigned short* __restrict__ A,
                                                   unsigned short* __restrict__ Hnbf,
                                                   float* __restrict__ invS) {
    __shared__ int sidx[ATTK];
    __shared__ float sval[ATTK];
    __shared__ float wsum[4];
    int i = blockIdx.x, c = blockIdx.y;
    int tid = threadIdx.x;
    int w = tid >> 6, lane = tid & 63;
    if (tid < ATTK) {
        sidx[tid] = idxs[c * ATTK + tid];
        sval[tid] = vals[c * ATTK + tid];
    }
    __syncthreads();
    int hw = tid;
    float v = 0.f;
    if (hw < HW) {
        int n = i * HW + hw;
        float a0 = 0.f, a1 = 0.f, a2 = 0.f, a3 = 0.f;
#pragma unroll 1
        for (int j = 0; j < ATTK; j += 4) {
            a0 += sval[j + 0] * bf2f(A[(size_t)sidx[j + 0] * NCOLS + n] & 0x7FFFu);
            a1 += sval[j + 1] * bf2f(A[(size_t)sidx[j + 1] * NCOLS + n] & 0x7FFFu);
            a2 += sval[j + 2] * bf2f(A[(size_t)sidx[j + 2] * NCOLS + n] & 0x7FFFu);
            a3 += sval[j + 3] * bf2f(A[(size_t)sidx[j + 3] * NCOLS + n] & 0x7FFFu);
        }
        v = (a0 + a1) + (a2 + a3);
    }
    if (hw < KPAD)
        Hnbf[((size_t)i * CAPS + c) * KPAD + hw] = (hw < HW) ? f2bf(v) : (unsigned short)0;
    float s = v;
#pragma unroll
    for (int d = 32; d > 0; d >>= 1) s += __shfl_xor(s, d, 64);
    if (lane == 0) wsum[w] = s;
    __syncthreads();
    if (tid == 0)
        invS[i * CAPS + c] = 1.0f / (wsum[0] + wsum[1] + wsum[2] + wsum[3]);
}

extern "C" void kernel_launch(void* const* d_in, const int* in_sizes, int n_in,
                              void* d_out, int out_size, void* d_ws, size_t ws_size,
                              hipStream_t stream) {
    const float* g = (const float*)d_in[0];
    const float* caps = (const float*)d_in[1];
    const float* fc_w = (const float*)d_in[2];
    const float* fc_b = (const float*)d_in[3];

    float* out = (float*)d_out;
    float* x_out = out;                    // 38400
    float* xa_out = out + 38400;           // 2457600
    float* g_out = out + 38400 + 2457600;  // 7526400 floats = 30.1 MB

    float* ws = (float*)d_ws;
    float* hpool = ws;                                       // 38400 f
    int* idxs = (int*)(ws + 38400);                          // 11520
    float* vals = ws + 49920;                                // 11520
    float* invS = ws + 61440;                                // 1024 f
    unsigned short* Hnbf = (unsigned short*)(ws + 62464);    // 16*64*224 us
    unsigned short* wbf = (unsigned short*)(ws + 1490944);   // ends byte 17483776
    bool use_wbf = ws_size >= (size_t)17483776;
    // big tier: gT (15052800 B) + Asig (15052800 B) appended in ws -> no g_out
    // scratch -> transpool writes g passthrough inline, memcpy eliminated.
    bool ws_big = use_wbf && ws_size >= (size_t)(17483776 + 2 * 15052800);
    unsigned short* gT_big = (unsigned short*)((char*)d_ws + 17483776);
    unsigned short* Asig_big = (unsigned short*)((char*)d_ws + 17483776 + 15052800);

    // fallback tier: scratch in g_out ([Asig][gT] exact fit), memcpy at end.
    // xa-gemm K-tail (k=196..223) reads <=27 elems past an image slice into
    // initialized finite data x Hn-pad=0 -> exact 0 (both tiers: gT follows Asig
    // in fallback; Asig_big is followed by valid ws or is self-contained in-bounds).
    unsigned short* Asig = ws_big ? Asig_big : (unsigned short*)g_out;
    unsigned short* gT = ws_big ? gT_big : ((unsigned short*)g_out + (size_t)EMB * NCOLS);

    transpool_kernel<<<dim3(EMB / 32, IMGS), 256, 0, stream>>>(
        g, hpool, gT, ws_big ? g_out : nullptr);
    topk_kernel<<<CAPS, 256, 0, stream>>>(caps, idxs, vals);

    if (use_wbf) {
        xw_kernel<<<EMB / 4, 256, 0, stream>>>(hpool, fc_w, fc_b, x_out, wbf);
        // gemm1 (5,7): signed Asig; BM=160 (15), BN=224 (14) -> 210 blocks
        gemm_gll<5, 7, 6><<<dim3(NCOLS / 224, EMB / 160, 1), 256, 0, stream>>>(
            wbf, gT, Asig, nullptr, nullptr, EMB, NCOLS, EMB, EMB, EMB, 0, 0);
    } else {
        x_kernel<<<EMB, 64, 0, stream>>>(hpool, fc_w, fc_b, x_out);
        mfma_gemm_nt<5, 2, float, unsigned short>
            <<<dim3(NCOLS / 64, EMB / 160), 256, 0, stream>>>(fc_w, gT, Asig,
                                                              EMB, NCOLS, EMB);
    }
    heat_kernel<<<dim3(IMGS, CAPS), 256, 0, stream>>>(idxs, vals, Asig, Hnbf, invS);
    // xa = (Hraw_i @ Asig_i^T) * invS + bias : per-image batched GEMM
    gemm_gll<2, 5, 4><<<dim3(EMB / 160, 1, IMGS), 256, 0, stream>>>(
        Hnbf, Asig, xa_out, fc_b, invS, CAPS, EMB, KPAD, NCOLS, KPAD,
        (long)CAPS * KPAD, HW);
    if (!ws_big) {
        // g passthrough last (overwrites Asig/gT scratch in g_out)
        hipMemcpyAsync(g_out, g, sizeof(float) * (size_t)IMGS * EMB * HW,
                       hipMemcpyDeviceToDevice, stream);
    }
}

// Round 18
// 151.530 us; speedup vs baseline: 1.8214x; 1.0482x over previous
//
#include <hip/hip_runtime.h>
#include <math.h>

#define IMGS 16
#define EMB 2400
#define HW 196
#define CAPS 64
#define ATTK 180
#define NPOOL 15
#define NCOLS (IMGS * HW)  // 3136
#define KPAD 224           // 196 padded to multiple of 32

typedef __attribute__((ext_vector_type(8))) short short8;
typedef __attribute__((ext_vector_type(4))) float f32x4;
typedef const __attribute__((address_space(1))) unsigned int* gas1_t;
typedef __attribute__((address_space(3))) unsigned int* las3_t;
typedef unsigned long long ull;

__device__ inline unsigned short f2bf(float f) {
    unsigned int u = __builtin_bit_cast(unsigned int, f);
    u += 0x7fffu + ((u >> 16) & 1u);  // round-to-nearest-even
    return (unsigned short)(u >> 16);
}
__device__ inline float bf2f(unsigned int lo16) {
    return __builtin_bit_cast(float, lo16 << 16);
}
__device__ inline unsigned f2sort(float f) {
    unsigned u = __builtin_bit_cast(unsigned, f);
    int msk = ((int)u) >> 31;
    return u ^ (unsigned)(msk | 0x80000000);
}

// ================= combo bodies (independent roles, one dispatch) =================
// r18: transpool (VALU-bound) + topk + convw (mem-bound) are mutually independent;
// single-stream serialization cost 68us; co-scheduled blocks overlap to ~max (m114).

// ---- transpool body: transpose+weldon (+optional g passthrough), LDS [32][197] ----
__device__ __forceinline__ void transpool_body(char* smem, int bx, int i,
                                               const float* __restrict__ g,
                                               float* __restrict__ hpool,
                                               unsigned short* __restrict__ gT,
                                               float* __restrict__ gout) {
    float(*t)[197] = (float(*)[197])smem;
    int e0 = bx * 32;
    int tid = threadIdx.x;
    const float* base = g + ((size_t)i * EMB + e0) * HW;
    float* obase = gout ? gout + ((size_t)i * EMB + e0) * HW : nullptr;
    for (int f = tid; f < 32 * HW; f += 256) {
        int e = f / HW, hw = f % HW;
        float v = base[(size_t)e * HW + hw];
        t[e][hw] = v;
        if (obase) obase[(size_t)e * HW + hw] = v;
    }
    __syncthreads();
    for (int f = tid; f < HW * 32; f += 256) {
        int hw = f / 32, e = f % 32;
        gT[((size_t)i * HW + hw) * EMB + e0 + e] = f2bf(t[e][hw]);
    }
    int w = tid >> 6, tl = tid & 63, hl = tl & 31;
    bool negh = tl >= 32;
#pragma unroll 1
    for (int rr = 0; rr < 8; ++rr) {
        int e = w * 8 + rr;
        float s[7];
#pragma unroll
        for (int q = 0; q < 7; q++) {
            int hw = hl + 32 * q;
            if (hw < HW) {
                unsigned u = __builtin_bit_cast(unsigned, t[e][hw]);
                if (negh) u ^= 0x80000000u;                      // negate for bottom-15
                u = (u & 0xFFFFFF00u) | (unsigned)(q * 32 + hl); // unique id within half
                s[q] = __builtin_bit_cast(float, u);
            } else {
                s[q] = -INFINITY;
            }
        }
#define CS(a, b)                                   \
    {                                              \
        float hi = fmaxf(s[a], s[b]);              \
        float lo = fminf(s[a], s[b]);              \
        s[a] = hi; s[b] = lo;                      \
    }
        CS(1, 2) CS(3, 4) CS(5, 6)
        CS(0, 2) CS(3, 5) CS(4, 6)
        CS(0, 1) CS(4, 5) CS(2, 6)
        CS(0, 4) CS(1, 5)
        CS(0, 3) CS(2, 5)
        CS(1, 3) CS(2, 4)
        CS(2, 3)
#undef CS
        float acc = 0.f;
#pragma unroll
        for (int it = 0; it < NPOOL; ++it) {
            int x = __builtin_bit_cast(int, s[0]);
#define ST(c)                                                                  \
    {                                                                          \
        int y = __builtin_amdgcn_update_dpp(x, x, c, 0xf, 0xf, false);         \
        float a = fmaxf(__builtin_bit_cast(float, x), __builtin_bit_cast(float, y)); \
        x = __builtin_bit_cast(int, a);                                        \
    }
            ST(0x111) ST(0x112) ST(0x114) ST(0x118) ST(0x142)
#undef ST
            int m31 = __builtin_amdgcn_readlane(x, 31);
            int m63 = __builtin_amdgcn_readlane(x, 63);
            float msel = __builtin_bit_cast(float, negh ? m63 : m31);
            acc += msel;
            bool won = (__builtin_bit_cast(unsigned, s[0]) ==
                        __builtin_bit_cast(unsigned, msel));
            s[0] = won ? s[1] : s[0];
            s[1] = won ? s[2] : s[1];
            s[2] = won ? s[3] : s[2];
            s[3] = won ? s[4] : s[3];
            s[4] = won ? s[5] : s[4];
            s[5] = won ? s[6] : s[5];
            s[6] = won ? -INFINITY : s[6];
        }
        int ai = __builtin_bit_cast(int, acc);
        float a0 = __builtin_bit_cast(float, __builtin_amdgcn_readlane(ai, 0));
        float a32 = __builtin_bit_cast(float, __builtin_amdgcn_readlane(ai, 32));
        if (tl == 0) hpool[(size_t)i * EMB + e0 + e] = (a0 - a32) / 15.0f;
    }
}

// ---- topk body: radix select, wave-level scans (shared layout in smem) ----
__device__ __forceinline__ void topk_body(char* smem, int c,
                                          const float* __restrict__ caps,
                                          int* __restrict__ idxs,
                                          float* __restrict__ vals) {
    float* rowf = (float*)smem;                                // 9600 B
    unsigned(*hist)[256] = (unsigned(*)[256])(smem + 9600);    // 4096 B
    unsigned* scanbuf = (unsigned*)(smem + 13696);             // 1024 B
    unsigned* wtot = (unsigned*)(smem + 14720);                // 16 B
    ull* sprefix = (ull*)(smem + 14744);                       // 8 B
    int* srank = (int*)(smem + 14752);                         // 4 B
    int tid = threadIdx.x;
    int w = tid >> 6, lane = tid & 63;
    const float4* src = (const float4*)(caps + (size_t)c * EMB);
    for (int j = tid; j < EMB / 4; j += 256) {
        float4 v = src[j];
        *(float4*)&rowf[j * 4] = v;
    }
    if (tid == 0) { *sprefix = 0ull; *srank = ATTK; }
#pragma unroll 1
    for (int pass = 0; pass < 6; ++pass) {
        __syncthreads();
        ull pref = *sprefix;
        int rk = *srank;
        int shift = 40 - pass * 8;
        ull pmaskhi = (pass == 0) ? 0ull : ~((1ull << (shift + 8)) - 1ull);
        hist[0][tid] = 0; hist[1][tid] = 0; hist[2][tid] = 0; hist[3][tid] = 0;
        __syncthreads();
        unsigned* myhist = hist[w];
#pragma unroll 1
        for (int s = 0; s < 10; s++) {
            int e = tid + s * 256;
            if (e < EMB) {
                ull key = ((ull)f2sort(rowf[e]) << 16) | ((unsigned)(2399 - e) << 4);
                if ((key & pmaskhi) == pref)
                    atomicAdd(&myhist[(unsigned)(key >> shift) & 255u], 1u);
            }
        }
        __syncthreads();
        unsigned h = hist[0][tid] + hist[1][tid] + hist[2][tid] + hist[3][tid];
        scanbuf[255 - tid] = h;
        __syncthreads();
        unsigned x = scanbuf[tid];
#pragma unroll
        for (int d = 1; d < 64; d <<= 1) {
            unsigned u = __shfl_up(x, d, 64);
            if (lane >= d) x += u;
        }
        if (lane == 63) wtot[w] = x;
        __syncthreads();
        unsigned off = 0;
        for (int ww = 0; ww < w; ww++) off += wtot[ww];
        scanbuf[tid] = x + off;
        __syncthreads();
        unsigned incl = scanbuf[255 - tid];
        unsigned excl = incl - h;
        if (h > 0u && excl < (unsigned)rk && incl >= (unsigned)rk) {
            *srank = rk - (int)excl;
            *sprefix = pref | ((ull)tid << shift);
        }
    }
    __syncthreads();
    ull T = *sprefix;
    unsigned selmask = 0, cnt = 0;
#pragma unroll 1
    for (int s = 0; s < 10; s++) {
        int e = tid + s * 256;
        if (e < EMB) {
            ull key = ((ull)f2sort(rowf[e]) << 16) | ((unsigned)(2399 - e) << 4);
            if (key >= T) { selmask |= 1u << s; cnt++; }
        }
    }
    unsigned x = cnt;
#pragma unroll
    for (int d = 1; d < 64; d <<= 1) {
        unsigned u = __shfl_up(x, d, 64);
        if (lane >= d) x += u;
    }
    if (lane == 63) wtot[w] = x;
    __syncthreads();
    unsigned off = 0;
    for (int ww = 0; ww < w; ww++) off += wtot[ww];
    unsigned slot = x + off - cnt;
#pragma unroll 1
    for (int s = 0; s < 10; s++) {
        if (selmask & (1u << s)) {
            int e = tid + s * 256;
            idxs[c * ATTK + slot] = e;
            vals[c * ATTK + slot] = fabsf(rowf[e]);
            slot++;
        }
    }
}

// ---- convw body: wbf = bf16(fc_w), 4 rows/block (wave per row) ----
__device__ __forceinline__ void convw_body(int b, const float* __restrict__ fc_w,
                                           unsigned short* __restrict__ wbf) {
    int o = b * 4 + (threadIdx.x >> 6);
    int lane = threadIdx.x & 63;
    const float* wrow = fc_w + (size_t)o * EMB;
    unsigned short* wdst = wbf + (size_t)o * EMB;
    for (int e = lane * 4; e < EMB; e += 256) {
        float4 wv = *(const float4*)&wrow[e];
        ushort4 r;
        r.x = f2bf(wv.x); r.y = f2bf(wv.y); r.z = f2bf(wv.z); r.w = f2bf(wv.w);
        *(ushort4*)&wdst[e] = r;
    }
}

// ---- combo dispatcher: [topk 64][convw 600][transpool 1200] ----
__global__ __launch_bounds__(256) void combo_kernel(const float* __restrict__ g,
                                                    float* __restrict__ hpool,
                                                    unsigned short* __restrict__ gT,
                                                    float* __restrict__ gout,
                                                    const float* __restrict__ caps,
                                                    int* __restrict__ idxs,
                                                    float* __restrict__ vals,
                                                    const float* __restrict__ fc_w,
                                                    unsigned short* __restrict__ wbf,
                                                    int nconv) {
    __shared__ __align__(16) char smem[25664];
    int b = blockIdx.x;
    if (b < CAPS) {
        topk_body(smem, b, caps, idxs, vals);
    } else if (b < CAPS + nconv) {
        convw_body(b - CAPS, fc_w, wbf);
    } else {
        int tb = b - CAPS - nconv;
        transpool_body(smem, tb % (EMB / 32), tb / (EMB / 32), g, hpool, gT, gout);
    }
}

// ---------------- x from bf16 weights: x = hpool @ wbf^T + fc_b ----------------
// 4 waves/block, wave per output column. Runs after combo (needs hpool + wbf).
__global__ __launch_bounds__(256) void x_bf_kernel(const float* __restrict__ hpool,
                                                   const unsigned short* __restrict__ wbf,
                                                   const float* __restrict__ fc_b,
                                                   float* __restrict__ x_out) {
    int o = blockIdx.x * 4 + (threadIdx.x >> 6);
    int lane = threadIdx.x & 63;
    float acc[IMGS];
#pragma unroll
    for (int i = 0; i < IMGS; i++) acc[i] = 0.f;
    const unsigned short* wrow = wbf + (size_t)o * EMB;
    for (int e = lane * 4; e < EMB; e += 256) {
        ushort4 wq = *(const ushort4*)&wrow[e];
        float w0 = bf2f(wq.x), w1 = bf2f(wq.y), w2 = bf2f(wq.z), w3 = bf2f(wq.w);
#pragma unroll
        for (int i = 0; i < IMGS; i++) {
            const float* hp = hpool + i * EMB + e;
            acc[i] += hp[0] * w0 + hp[1] * w1 + hp[2] * w2 + hp[3] * w3;
        }
    }
#pragma unroll
    for (int i = 0; i < IMGS; i++) {
#pragma unroll
        for (int sdx = 32; sdx > 0; sdx >>= 1) acc[i] += __shfl_xor(acc[i], sdx, 64);
    }
    if (lane == 0) {
        float bo = fc_b[o];
#pragma unroll
        for (int i = 0; i < IMGS; i++) x_out[i * EMB + o] = acc[i] + bo;
    }
}

// ---------------- x (fallback, fp32 weights) ----------------
__global__ void x_kernel(const float* __restrict__ hpool, const float* __restrict__ fc_w,
                         const float* __restrict__ fc_b, float* __restrict__ x_out) {
    int o = blockIdx.x;
    int lane = threadIdx.x;
    float acc[IMGS];
#pragma unroll
    for (int i = 0; i < IMGS; i++) acc[i] = 0.f;
    const float* wrow = fc_w + (size_t)o * EMB;
    for (int e = lane; e < EMB; e += 64) {
        float wv = wrow[e];
#pragma unroll
        for (int i = 0; i < IMGS; i++) acc[i] += hpool[i * EMB + e] * wv;
    }
#pragma unroll
    for (int i = 0; i < IMGS; i++) {
#pragma unroll
        for (int sdx = 32; sdx > 0; sdx >>= 1) acc[i] += __shfl_xor(acc[i], sdx, 64);
    }
    if (lane == 0) {
        float bo = fc_b[o];
#pragma unroll
        for (int i = 0; i < IMGS; i++) x_out[i * EMB + o] = acc[i] + bo;
    }
}

// ======== NT bf16 MFMA GEMM, gll staging, 3-buffer counted-vmcnt pipeline ========
// T1 bijective XCD swizzle + y-major; T2 source/read swizzle; T4 counted vmcnt;
// T5 setprio. OUT_MODE 6: signed bf16. OUT_MODE 4: f32 v*invS[z*64+row]+bias[col].
template <int MF, int NF, int OUT_MODE>
__global__ __launch_bounds__(256) void gemm_gll(const unsigned short* __restrict__ A,
                                                const unsigned short* __restrict__ B,
                                                void* __restrict__ outp,
                                                const float* __restrict__ bias,
                                                const float* __restrict__ invS,
                                                int M, int N, int K, int ldb, int kper,
                                                long az, long bz) {
    constexpr int BM = MF * 32, BN = NF * 32;
    constexpr int ROWS = BM + BN;
    constexpr int RPAD = (ROWS + 63) & ~63;
    constexpr int NCALL = RPAD / 16;
    constexpr int LPW = NCALL / 4;
    __shared__ unsigned short lds[3][RPAD][32];
    int gx = gridDim.x, gy = gridDim.y;
    int nwg = gx * gy;
    int flat = blockIdx.y * gx + blockIdx.x;
    int qq = nwg >> 3, rr8 = nwg & 7;
    int xcd = flat & 7, idx = flat >> 3;
    int base = (xcd < rr8) ? xcd * (qq + 1) : rr8 * (qq + 1) + (xcd - rr8) * qq;
    int nf = base + idx;
    int m0 = (nf % gy) * BM;
    int n0 = (nf / gy) * BN;
    int z = blockIdx.z;
    const unsigned short* Ab = A + (size_t)z * az;
    const unsigned short* Bb = B + (size_t)z * bz;
    int kb = (az == 0 && bz == 0) ? z * kper : 0;
    int nt = kper / 32;
    int tid = threadIdx.x, w = tid >> 6, lane = tid & 63;
    int wm = (w >> 1) * (MF * 16), wn = (w & 1) * (NF * 16);
    int ln = lane & 15;
    int ks = (((lane >> 4) ^ ((lane >> 1) & 3))) * 8;
    int srow = lane >> 2;
    int skc = (((lane & 3) ^ ((lane >> 3) & 3))) * 8;

    auto STAGE = [&](int buf, int t) {
        int k0 = kb + t * 32;
#pragma unroll
        for (int j = 0; j < LPW; j++) {
            int jj = w + j * 4;
            int r = jj * 16 + srow;
            const unsigned short* src;
            if (r < BM) src = Ab + (size_t)(m0 + r) * K + k0 + skc;
            else if (r < ROWS) src = Bb + (size_t)(n0 + r - BM) * ldb + k0 + skc;
            else src = Ab + (size_t)m0 * K + k0 + skc;  // dummy (uniform vmcnt)
            __builtin_amdgcn_global_load_lds((gas1_t)(const void*)src,
                                             (las3_t)(void*)&lds[buf][jj * 16][0], 16, 0, 0);
        }
    };

    STAGE(0, 0);
    if (nt > 1) STAGE(1, 1);
    f32x4 acc[MF][NF] = {};
    for (int t = 0; t < nt; ++t) {
        if (t + 1 < nt) {
            if constexpr (LPW == 4) asm volatile("s_waitcnt vmcnt(4) lgkmcnt(0)" ::: "memory");
            else if constexpr (LPW == 5) asm volatile("s_waitcnt vmcnt(5) lgkmcnt(0)" ::: "memory");
            else if constexpr (LPW == 6) asm volatile("s_waitcnt vmcnt(6) lgkmcnt(0)" ::: "memory");
            else asm volatile("s_waitcnt vmcnt(0) lgkmcnt(0)" ::: "memory");
        } else {
            asm volatile("s_waitcnt vmcnt(0) lgkmcnt(0)" ::: "memory");
        }
        __builtin_amdgcn_s_barrier();
        __builtin_amdgcn_sched_barrier(0);  // rule #18
        if (t + 2 < nt) STAGE((t + 2) % 3, t + 2);
        const unsigned short(*buf)[32] = lds[t % 3];
        short8 af[MF], bfv[NF];
#pragma unroll
        for (int mf = 0; mf < MF; mf++)
            af[mf] = *(const short8*)&buf[wm + mf * 16 + ln][ks];
#pragma unroll
        for (int nfi = 0; nfi < NF; nfi++)
            bfv[nfi] = *(const short8*)&buf[BM + wn + nfi * 16 + ln][ks];
        __builtin_amdgcn_s_setprio(1);  // T5
#pragma unroll
        for (int mf = 0; mf < MF; mf++)
#pragma unroll
            for (int nfi = 0; nfi < NF; nfi++)
                acc[mf][nfi] = __builtin_amdgcn_mfma_f32_16x16x32_bf16(af[mf], bfv[nfi],
                                                                       acc[mf][nfi], 0, 0, 0);
        __builtin_amdgcn_s_setprio(0);
    }
#pragma unroll
    for (int mf = 0; mf < MF; mf++) {
#pragma unroll
        for (int nfi = 0; nfi < NF; nfi++) {
#pragma unroll
            for (int rr = 0; rr < 4; rr++) {
                int row = m0 + wm + mf * 16 + (lane >> 4) * 4 + rr;
                int col = n0 + wn + nfi * 16 + ln;
                float v = acc[mf][nfi][rr];
                if (OUT_MODE == 6) {
                    ((unsigned short*)outp)[(size_t)row * N + col] = f2bf(v);
                } else if (OUT_MODE == 4) {
                    ((float*)outp)[((size_t)z * CAPS + row) * N + col] =
                        v * invS[z * CAPS + row] + bias[col];
                }
            }
        }
    }
}

// ======== fallback reg-staged NT GEMM (gemm1 only; used if ws too small for wbf) ========
__device__ inline uint4 load8(const unsigned short* p) { return *(const uint4*)p; }
__device__ inline uint4 load8(const float* p) {
    float4 a = *(const float4*)p;
    float4 b = *(const float4*)(p + 4);
    uint4 r;
    r.x = (unsigned)f2bf(a.x) | ((unsigned)f2bf(a.y) << 16);
    r.y = (unsigned)f2bf(a.z) | ((unsigned)f2bf(a.w) << 16);
    r.z = (unsigned)f2bf(b.x) | ((unsigned)f2bf(b.y) << 16);
    r.w = (unsigned)f2bf(b.z) | ((unsigned)f2bf(b.w) << 16);
    return r;
}

template <int MF, int NF, typename TA, typename TB>
__global__ __launch_bounds__(256) void mfma_gemm_nt(const TA* __restrict__ A,
                                                    const TB* __restrict__ B,
                                                    void* __restrict__ outp,
                                                    int M, int N, int K) {
    constexpr int BM = MF * 32, BN = NF * 32;
    constexpr int nA = BM * 4, nTot = (BM + BN) * 4;
    constexpr int NCH = (nTot + 255) / 256;
    __shared__ unsigned short As[BM][40];
    __shared__ unsigned short Bs[BN][40];
    int m0 = blockIdx.y * BM, n0 = blockIdx.x * BN;
    int tid = threadIdx.x;
    int w = tid >> 6, lane = tid & 63;
    int wm = (w >> 1) * (MF * 16), wn = (w & 1) * (NF * 16);
    int ln = lane & 15, ks = (lane >> 4) * 8;
    uint4 r[NCH];
#pragma unroll
    for (int j = 0; j < NCH; j++) {
        int c = tid + 256 * j;
        if (c < nTot) {
            if (c < nA) {
                int row = c >> 2, kc = c & 3;
                r[j] = load8(A + (size_t)(m0 + row) * K + kc * 8);
            } else {
                int cc = c - nA, row = cc >> 2, kc = cc & 3;
                r[j] = load8(B + (size_t)(n0 + row) * K + kc * 8);
            }
        }
    }
    f32x4 acc[MF][NF] = {};
    for (int k0 = 0; k0 < K; k0 += 32) {
#pragma unroll
        for (int j = 0; j < NCH; j++) {
            int c = tid + 256 * j;
            if (c < nTot) {
                if (c < nA) {
                    int row = c >> 2, kc = c & 3;
                    *(uint4*)&As[row][kc * 8] = r[j];
                } else {
                    int cc = c - nA, row = cc >> 2, kc = cc & 3;
                    *(uint4*)&Bs[row][kc * 8] = r[j];
                }
            }
        }
        __syncthreads();
        if (k0 + 32 < K) {
#pragma unroll
            for (int j = 0; j < NCH; j++) {
                int c = tid + 256 * j;
                if (c < nTot) {
                    if (c < nA) {
                        int row = c >> 2, kc = c & 3;
                        r[j] = load8(A + (size_t)(m0 + row) * K + (k0 + 32) + kc * 8);
                    } else {
                        int cc = c - nA, row = cc >> 2, kc = cc & 3;
                        r[j] = load8(B + (size_t)(n0 + row) * K + (k0 + 32) + kc * 8);
                    }
                }
            }
        }
        short8 af[MF], bfv[NF];
#pragma unroll
        for (int mf = 0; mf < MF; mf++)
            af[mf] = *(const short8*)&As[wm + mf * 16 + ln][ks];
#pragma unroll
        for (int nfi = 0; nfi < NF; nfi++)
            bfv[nfi] = *(const short8*)&Bs[wn + nfi * 16 + ln][ks];
#pragma unroll
        for (int mf = 0; mf < MF; mf++)
#pragma unroll
            for (int nfi = 0; nfi < NF; nfi++)
                acc[mf][nfi] = __builtin_amdgcn_mfma_f32_16x16x32_bf16(af[mf], bfv[nfi],
                                                                       acc[mf][nfi], 0, 0, 0);
        __syncthreads();
    }
#pragma unroll
    for (int mf = 0; mf < MF; mf++) {
#pragma unroll
        for (int nfi = 0; nfi < NF; nfi++) {
#pragma unroll
            for (int rr = 0; rr < 4; rr++) {
                int row = m0 + wm + mf * 16 + (lane >> 4) * 4 + rr;
                int col = n0 + wn + nfi * 16 + ln;
                ((unsigned short*)outp)[(size_t)row * N + col] = f2bf(acc[mf][nfi][rr]);
            }
        }
    }
}

// ---------------- heat v4: (i,c)-block; fused pad-zero + invS ----------------
__global__ __launch_bounds__(256) void heat_kernel(const int* __restrict__ idxs,
                                                   const float* __restrict__ vals,
                                                   const unsigned short* __restrict__ A,
                                                   unsigned short* __restrict__ Hnbf,
                                                   float* __restrict__ invS) {
    __shared__ int sidx[ATTK];
    __shared__ float sval[ATTK];
    __shared__ float wsum[4];
    int i = blockIdx.x, c = blockIdx.y;
    int tid = threadIdx.x;
    int w = tid >> 6, lane = tid & 63;
    if (tid < ATTK) {
        sidx[tid] = idxs[c * ATTK + tid];
        sval[tid] = vals[c * ATTK + tid];
    }
    __syncthreads();
    int hw = tid;
    float v = 0.f;
    if (hw < HW) {
        int n = i * HW + hw;
        float a0 = 0.f, a1 = 0.f, a2 = 0.f, a3 = 0.f;
#pragma unroll 1
        for (int j = 0; j < ATTK; j += 4) {
            a0 += sval[j + 0] * bf2f(A[(size_t)sidx[j + 0] * NCOLS + n] & 0x7FFFu);
            a1 += sval[j + 1] * bf2f(A[(size_t)sidx[j + 1] * NCOLS + n] & 0x7FFFu);
            a2 += sval[j + 2] * bf2f(A[(size_t)sidx[j + 2] * NCOLS + n] & 0x7FFFu);
            a3 += sval[j + 3] * bf2f(A[(size_t)sidx[j + 3] * NCOLS + n] & 0x7FFFu);
        }
        v = (a0 + a1) + (a2 + a3);
    }
    if (hw < KPAD)
        Hnbf[((size_t)i * CAPS + c) * KPAD + hw] = (hw < HW) ? f2bf(v) : (unsigned short)0;
    float s = v;
#pragma unroll
    for (int d = 32; d > 0; d >>= 1) s += __shfl_xor(s, d, 64);
    if (lane == 0) wsum[w] = s;
    __syncthreads();
    if (tid == 0)
        invS[i * CAPS + c] = 1.0f / (wsum[0] + wsum[1] + wsum[2] + wsum[3]);
}

extern "C" void kernel_launch(void* const* d_in, const int* in_sizes, int n_in,
                              void* d_out, int out_size, void* d_ws, size_t ws_size,
                              hipStream_t stream) {
    const float* g = (const float*)d_in[0];
    const float* caps = (const float*)d_in[1];
    const float* fc_w = (const float*)d_in[2];
    const float* fc_b = (const float*)d_in[3];

    float* out = (float*)d_out;
    float* x_out = out;                    // 38400
    float* xa_out = out + 38400;           // 2457600
    float* g_out = out + 38400 + 2457600;  // 7526400 floats = 30.1 MB

    float* ws = (float*)d_ws;
    float* hpool = ws;                                       // 38400 f
    int* idxs = (int*)(ws + 38400);                          // 11520
    float* vals = ws + 49920;                                // 11520
    float* invS = ws + 61440;                                // 1024 f
    unsigned short* Hnbf = (unsigned short*)(ws + 62464);    // 16*64*224 us
    unsigned short* wbf = (unsigned short*)(ws + 1490944);   // ends byte 17483776
    bool use_wbf = ws_size >= (size_t)17483776;
    bool ws_big = use_wbf && ws_size >= (size_t)(17483776 + 2 * 15052800);
    unsigned short* gT_big = (unsigned short*)((char*)d_ws + 17483776);
    unsigned short* Asig_big = (unsigned short*)((char*)d_ws + 17483776 + 15052800);

    // fallback tier: scratch in g_out ([Asig][gT] exact fit), memcpy at end.
    // xa-gemm K-tail (k=196..223) reads <=27 elems past an image slice into
    // initialized finite data x Hn-pad=0 -> exact 0 (both tiers).
    unsigned short* Asig = ws_big ? Asig_big : (unsigned short*)g_out;
    unsigned short* gT = ws_big ? gT_big : ((unsigned short*)g_out + (size_t)EMB * NCOLS);

    if (use_wbf) {
        // combo: [topk 64][convw 600][transpool 1200] -- independent roles co-scheduled
        combo_kernel<<<CAPS + EMB / 4 + (EMB / 32) * IMGS, 256, 0, stream>>>(
            g, hpool, gT, ws_big ? g_out : nullptr, caps, idxs, vals, fc_w, wbf, EMB / 4);
        x_bf_kernel<<<EMB / 4, 256, 0, stream>>>(hpool, wbf, fc_b, x_out);
        // gemm1 (5,7): signed Asig; BM=160 (15), BN=224 (14) -> 210 blocks
        gemm_gll<5, 7, 6><<<dim3(NCOLS / 224, EMB / 160, 1), 256, 0, stream>>>(
            wbf, gT, Asig, nullptr, nullptr, EMB, NCOLS, EMB, EMB, EMB, 0, 0);
    } else {
        combo_kernel<<<CAPS + (EMB / 32) * IMGS, 256, 0, stream>>>(
            g, hpool, gT, nullptr, caps, idxs, vals, fc_w, nullptr, 0);
        x_kernel<<<EMB, 64, 0, stream>>>(hpool, fc_w, fc_b, x_out);
        mfma_gemm_nt<5, 2, float, unsigned short>
            <<<dim3(NCOLS / 64, EMB / 160), 256, 0, stream>>>(fc_w, gT, Asig,
                                                              EMB, NCOLS, EMB);
    }
    heat_kernel<<<dim3(IMGS, CAPS), 256, 0, stream>>>(idxs, vals, Asig, Hnbf, invS);
    // xa = (Hraw_i @ Asig_i^T) * invS + bias : per-image batched GEMM
    gemm_gll<2, 5, 4><<<dim3(EMB / 160, 1, IMGS), 256, 0, stream>>>(
        Hnbf, Asig, xa_out, fc_b, invS, CAPS, EMB, KPAD, NCOLS, KPAD,
        (long)CAPS * KPAD, HW);
    if (!ws_big) {
        hipMemcpyAsync(g_out, g, sizeof(float) * (size_t)IMGS * EMB * HW,
                       hipMemcpyDeviceToDevice, stream);
    }
}

// Round 19
// 147.891 us; speedup vs baseline: 1.8662x; 1.0246x over previous
//
#include <hip/hip_runtime.h>
#include <math.h>

#define IMGS 16
#define EMB 2400
#define HW 196
#define CAPS 64
#define ATTK 180
#define NPOOL 15
#define NCOLS (IMGS * HW)  // 3136
#define KPAD 224           // 196 padded to multiple of 32

typedef __attribute__((ext_vector_type(8))) short short8;
typedef __attribute__((ext_vector_type(4))) float f32x4;
typedef const __attribute__((address_space(1))) unsigned int* gas1_t;
typedef __attribute__((address_space(3))) unsigned int* las3_t;
typedef unsigned long long ull;

__device__ inline unsigned short f2bf(float f) {
    unsigned int u = __builtin_bit_cast(unsigned int, f);
    u += 0x7fffu + ((u >> 16) & 1u);  // round-to-nearest-even
    return (unsigned short)(u >> 16);
}
__device__ inline float bf2f(unsigned int lo16) {
    return __builtin_bit_cast(float, lo16 << 16);
}
__device__ inline unsigned f2sort(float f) {
    unsigned u = __builtin_bit_cast(unsigned, f);
    int msk = ((int)u) >> 31;
    return u ^ (unsigned)(msk | 0x80000000);
}

// ================= combo bodies (independent roles, one dispatch) =================
// r19: role order [transpool][convw][topk] so VALU-heavy blocks are resident first
// and mem-bound roles cover the tail. Weldon extraction now processes ROW PAIRS
// with independent DPP chains (2x ILP on the latency-bound extraction chain).

// ---- transpool body: transpose+weldon (+optional g passthrough), LDS [32][197] ----
__device__ __forceinline__ void transpool_body(char* smem, int bx, int i,
                                               const float* __restrict__ g,
                                               float* __restrict__ hpool,
                                               unsigned short* __restrict__ gT,
                                               float* __restrict__ gout) {
    float(*t)[197] = (float(*)[197])smem;
    int e0 = bx * 32;
    int tid = threadIdx.x;
    const float* base = g + ((size_t)i * EMB + e0) * HW;
    float* obase = gout ? gout + ((size_t)i * EMB + e0) * HW : nullptr;
    for (int f = tid; f < 32 * HW; f += 256) {
        int e = f / HW, hw = f % HW;
        float v = base[(size_t)e * HW + hw];
        t[e][hw] = v;
        if (obase) obase[(size_t)e * HW + hw] = v;
    }
    __syncthreads();
    for (int f = tid; f < HW * 32; f += 256) {
        int hw = f / 32, e = f % 32;
        gT[((size_t)i * HW + hw) * EMB + e0 + e] = f2bf(t[e][hw]);
    }
    int w = tid >> 6, tl = tid & 63, hl = tl & 31;
    bool negh = tl >= 32;
#pragma unroll 1
    for (int rp = 0; rp < 4; ++rp) {  // row PAIRS: 2 independent DPP chains in flight
        int eA = w * 8 + rp * 2, eB = eA + 1;
        float sA[7], sB[7];
#pragma unroll
        for (int q = 0; q < 7; q++) {
            int hw = hl + 32 * q;
            if (hw < HW) {
                unsigned uA = __builtin_bit_cast(unsigned, t[eA][hw]);
                unsigned uB = __builtin_bit_cast(unsigned, t[eB][hw]);
                if (negh) { uA ^= 0x80000000u; uB ^= 0x80000000u; }
                unsigned id = (unsigned)(q * 32 + hl);
                sA[q] = __builtin_bit_cast(float, (uA & 0xFFFFFF00u) | id);
                sB[q] = __builtin_bit_cast(float, (uB & 0xFFFFFF00u) | id);
            } else {
                sA[q] = -INFINITY;
                sB[q] = -INFINITY;
            }
        }
#define CS2(s, a, b)                               \
    {                                              \
        float hi = fmaxf(s[a], s[b]);              \
        float lo = fminf(s[a], s[b]);              \
        s[a] = hi; s[b] = lo;                      \
    }
#define CSP(a, b) CS2(sA, a, b) CS2(sB, a, b)
        CSP(1, 2) CSP(3, 4) CSP(5, 6)
        CSP(0, 2) CSP(3, 5) CSP(4, 6)
        CSP(0, 1) CSP(4, 5) CSP(2, 6)
        CSP(0, 4) CSP(1, 5)
        CSP(0, 3) CSP(2, 5)
        CSP(1, 3) CSP(2, 4)
        CSP(2, 3)
#undef CSP
#undef CS2
        float accA = 0.f, accB = 0.f;
#pragma unroll
        for (int it = 0; it < NPOOL; ++it) {
            int xA = __builtin_bit_cast(int, sA[0]);
            int xB = __builtin_bit_cast(int, sB[0]);
#define ST2(c)                                                                   \
    {                                                                            \
        int yA = __builtin_amdgcn_update_dpp(xA, xA, c, 0xf, 0xf, false);        \
        int yB = __builtin_amdgcn_update_dpp(xB, xB, c, 0xf, 0xf, false);        \
        float aA = fmaxf(__builtin_bit_cast(float, xA), __builtin_bit_cast(float, yA)); \
        float aB = fmaxf(__builtin_bit_cast(float, xB), __builtin_bit_cast(float, yB)); \
        xA = __builtin_bit_cast(int, aA);                                        \
        xB = __builtin_bit_cast(int, aB);                                        \
    }
            ST2(0x111) ST2(0x112) ST2(0x114) ST2(0x118) ST2(0x142)
#undef ST2
            int mA31 = __builtin_amdgcn_readlane(xA, 31);
            int mA63 = __builtin_amdgcn_readlane(xA, 63);
            int mB31 = __builtin_amdgcn_readlane(xB, 31);
            int mB63 = __builtin_amdgcn_readlane(xB, 63);
            float mselA = __builtin_bit_cast(float, negh ? mA63 : mA31);
            float mselB = __builtin_bit_cast(float, negh ? mB63 : mB31);
            accA += mselA;
            accB += mselB;
            bool wonA = (__builtin_bit_cast(unsigned, sA[0]) ==
                         __builtin_bit_cast(unsigned, mselA));
            bool wonB = (__builtin_bit_cast(unsigned, sB[0]) ==
                         __builtin_bit_cast(unsigned, mselB));
            sA[0] = wonA ? sA[1] : sA[0];  sB[0] = wonB ? sB[1] : sB[0];
            sA[1] = wonA ? sA[2] : sA[1];  sB[1] = wonB ? sB[2] : sB[1];
            sA[2] = wonA ? sA[3] : sA[2];  sB[2] = wonB ? sB[3] : sB[2];
            sA[3] = wonA ? sA[4] : sA[3];  sB[3] = wonB ? sB[4] : sB[3];
            sA[4] = wonA ? sA[5] : sA[4];  sB[4] = wonB ? sB[5] : sB[4];
            sA[5] = wonA ? sA[6] : sA[5];  sB[5] = wonB ? sB[6] : sB[5];
            sA[6] = wonA ? -INFINITY : sA[6];
            sB[6] = wonB ? -INFINITY : sB[6];
        }
        int aiA = __builtin_bit_cast(int, accA);
        int aiB = __builtin_bit_cast(int, accB);
        float a0A = __builtin_bit_cast(float, __builtin_amdgcn_readlane(aiA, 0));
        float a32A = __builtin_bit_cast(float, __builtin_amdgcn_readlane(aiA, 32));
        float a0B = __builtin_bit_cast(float, __builtin_amdgcn_readlane(aiB, 0));
        float a32B = __builtin_bit_cast(float, __builtin_amdgcn_readlane(aiB, 32));
        if (tl == 0) {
            hpool[(size_t)i * EMB + e0 + eA] = (a0A - a32A) / 15.0f;
            hpool[(size_t)i * EMB + e0 + eB] = (a0B - a32B) / 15.0f;
        }
    }
}

// ---- topk body: radix select, wave-level scans (shared layout in smem) ----
__device__ __forceinline__ void topk_body(char* smem, int c,
                                          const float* __restrict__ caps,
                                          int* __restrict__ idxs,
                                          float* __restrict__ vals) {
    float* rowf = (float*)smem;                                // 9600 B
    unsigned(*hist)[256] = (unsigned(*)[256])(smem + 9600);    // 4096 B
    unsigned* scanbuf = (unsigned*)(smem + 13696);             // 1024 B
    unsigned* wtot = (unsigned*)(smem + 14720);                // 16 B
    ull* sprefix = (ull*)(smem + 14744);                       // 8 B
    int* srank = (int*)(smem + 14752);                         // 4 B
    int tid = threadIdx.x;
    int w = tid >> 6, lane = tid & 63;
    const float4* src = (const float4*)(caps + (size_t)c * EMB);
    for (int j = tid; j < EMB / 4; j += 256) {
        float4 v = src[j];
        *(float4*)&rowf[j * 4] = v;
    }
    if (tid == 0) { *sprefix = 0ull; *srank = ATTK; }
#pragma unroll 1
    for (int pass = 0; pass < 6; ++pass) {
        __syncthreads();
        ull pref = *sprefix;
        int rk = *srank;
        int shift = 40 - pass * 8;
        ull pmaskhi = (pass == 0) ? 0ull : ~((1ull << (shift + 8)) - 1ull);
        hist[0][tid] = 0; hist[1][tid] = 0; hist[2][tid] = 0; hist[3][tid] = 0;
        __syncthreads();
        unsigned* myhist = hist[w];
#pragma unroll 1
        for (int s = 0; s < 10; s++) {
            int e = tid + s * 256;
            if (e < EMB) {
                ull key = ((ull)f2sort(rowf[e]) << 16) | ((unsigned)(2399 - e) << 4);
                if ((key & pmaskhi) == pref)
                    atomicAdd(&myhist[(unsigned)(key >> shift) & 255u], 1u);
            }
        }
        __syncthreads();
        unsigned h = hist[0][tid] + hist[1][tid] + hist[2][tid] + hist[3][tid];
        scanbuf[255 - tid] = h;
        __syncthreads();
        unsigned x = scanbuf[tid];
#pragma unroll
        for (int d = 1; d < 64; d <<= 1) {
            unsigned u = __shfl_up(x, d, 64);
            if (lane >= d) x += u;
        }
        if (lane == 63) wtot[w] = x;
        __syncthreads();
        unsigned off = 0;
        for (int ww = 0; ww < w; ww++) off += wtot[ww];
        scanbuf[tid] = x + off;
        __syncthreads();
        unsigned incl = scanbuf[255 - tid];
        unsigned excl = incl - h;
        if (h > 0u && excl < (unsigned)rk && incl >= (unsigned)rk) {
            *srank = rk - (int)excl;
            *sprefix = pref | ((ull)tid << shift);
        }
    }
    __syncthreads();
    ull T = *sprefix;
    unsigned selmask = 0, cnt = 0;
#pragma unroll 1
    for (int s = 0; s < 10; s++) {
        int e = tid + s * 256;
        if (e < EMB) {
            ull key = ((ull)f2sort(rowf[e]) << 16) | ((unsigned)(2399 - e) << 4);
            if (key >= T) { selmask |= 1u << s; cnt++; }
        }
    }
    unsigned x = cnt;
#pragma unroll
    for (int d = 1; d < 64; d <<= 1) {
        unsigned u = __shfl_up(x, d, 64);
        if (lane >= d) x += u;
    }
    if (lane == 63) wtot[w] = x;
    __syncthreads();
    unsigned off = 0;
    for (int ww = 0; ww < w; ww++) off += wtot[ww];
    unsigned slot = x + off - cnt;
#pragma unroll 1
    for (int s = 0; s < 10; s++) {
        if (selmask & (1u << s)) {
            int e = tid + s * 256;
            idxs[c * ATTK + slot] = e;
            vals[c * ATTK + slot] = fabsf(rowf[e]);
            slot++;
        }
    }
}

// ---- convw body: wbf = bf16(fc_w), 4 rows/block (wave per row) ----
__device__ __forceinline__ void convw_body(int b, const float* __restrict__ fc_w,
                                           unsigned short* __restrict__ wbf) {
    int o = b * 4 + (threadIdx.x >> 6);
    int lane = threadIdx.x & 63;
    const float* wrow = fc_w + (size_t)o * EMB;
    unsigned short* wdst = wbf + (size_t)o * EMB;
    for (int e = lane * 4; e < EMB; e += 256) {
        float4 wv = *(const float4*)&wrow[e];
        ushort4 r;
        r.x = f2bf(wv.x); r.y = f2bf(wv.y); r.z = f2bf(wv.z); r.w = f2bf(wv.w);
        *(ushort4*)&wdst[e] = r;
    }
}

// ---- combo dispatcher: [transpool 1200][convw 600][topk 64] ----
__global__ __launch_bounds__(256) void combo_kernel(const float* __restrict__ g,
                                                    float* __restrict__ hpool,
                                                    unsigned short* __restrict__ gT,
                                                    float* __restrict__ gout,
                                                    const float* __restrict__ caps,
                                                    int* __restrict__ idxs,
                                                    float* __restrict__ vals,
                                                    const float* __restrict__ fc_w,
                                                    unsigned short* __restrict__ wbf,
                                                    int nconv) {
    __shared__ __align__(16) char smem[25664];
    int b = blockIdx.x;
    constexpr int NTP = (EMB / 32) * IMGS;  // 1200
    if (b < NTP) {
        transpool_body(smem, b % (EMB / 32), b / (EMB / 32), g, hpool, gT, gout);
    } else if (b < NTP + nconv) {
        convw_body(b - NTP, fc_w, wbf);
    } else {
        topk_body(smem, b - NTP - nconv, caps, idxs, vals);
    }
}

// ---------------- x from bf16 weights: x = hpool @ wbf^T + fc_b ----------------
__global__ __launch_bounds__(256) void x_bf_kernel(const float* __restrict__ hpool,
                                                   const unsigned short* __restrict__ wbf,
                                                   const float* __restrict__ fc_b,
                                                   float* __restrict__ x_out) {
    int o = blockIdx.x * 4 + (threadIdx.x >> 6);
    int lane = threadIdx.x & 63;
    float acc[IMGS];
#pragma unroll
    for (int i = 0; i < IMGS; i++) acc[i] = 0.f;
    const unsigned short* wrow = wbf + (size_t)o * EMB;
    for (int e = lane * 4; e < EMB; e += 256) {
        ushort4 wq = *(const ushort4*)&wrow[e];
        float w0 = bf2f(wq.x), w1 = bf2f(wq.y), w2 = bf2f(wq.z), w3 = bf2f(wq.w);
#pragma unroll
        for (int i = 0; i < IMGS; i++) {
            const float* hp = hpool + i * EMB + e;
            acc[i] += hp[0] * w0 + hp[1] * w1 + hp[2] * w2 + hp[3] * w3;
        }
    }
#pragma unroll
    for (int i = 0; i < IMGS; i++) {
#pragma unroll
        for (int sdx = 32; sdx > 0; sdx >>= 1) acc[i] += __shfl_xor(acc[i], sdx, 64);
    }
    if (lane == 0) {
        float bo = fc_b[o];
#pragma unroll
        for (int i = 0; i < IMGS; i++) x_out[i * EMB + o] = acc[i] + bo;
    }
}

// ---------------- x (fallback, fp32 weights) ----------------
__global__ void x_kernel(const float* __restrict__ hpool, const float* __restrict__ fc_w,
                         const float* __restrict__ fc_b, float* __restrict__ x_out) {
    int o = blockIdx.x;
    int lane = threadIdx.x;
    float acc[IMGS];
#pragma unroll
    for (int i = 0; i < IMGS; i++) acc[i] = 0.f;
    const float* wrow = fc_w + (size_t)o * EMB;
    for (int e = lane; e < EMB; e += 64) {
        float wv = wrow[e];
#pragma unroll
        for (int i = 0; i < IMGS; i++) acc[i] += hpool[i * EMB + e] * wv;
    }
#pragma unroll
    for (int i = 0; i < IMGS; i++) {
#pragma unroll
        for (int sdx = 32; sdx > 0; sdx >>= 1) acc[i] += __shfl_xor(acc[i], sdx, 64);
    }
    if (lane == 0) {
        float bo = fc_b[o];
#pragma unroll
        for (int i = 0; i < IMGS; i++) x_out[i * EMB + o] = acc[i] + bo;
    }
}

// ======== NT bf16 MFMA GEMM, gll staging, 3-buffer counted-vmcnt pipeline ========
// T1 bijective XCD swizzle + y-major; T2 source/read swizzle; T4 counted vmcnt;
// T5 setprio. OUT_MODE 6: signed bf16. OUT_MODE 4: f32 v*invS[z*64+row]+bias[col].
template <int MF, int NF, int OUT_MODE>
__global__ __launch_bounds__(256) void gemm_gll(const unsigned short* __restrict__ A,
                                                const unsigned short* __restrict__ B,
                                                void* __restrict__ outp,
                                                const float* __restrict__ bias,
                                                const float* __restrict__ invS,
                                                int M, int N, int K, int ldb, int kper,
                                                long az, long bz) {
    constexpr int BM = MF * 32, BN = NF * 32;
    constexpr int ROWS = BM + BN;
    constexpr int RPAD = (ROWS + 63) & ~63;
    constexpr int NCALL = RPAD / 16;
    constexpr int LPW = NCALL / 4;
    __shared__ unsigned short lds[3][RPAD][32];
    int gx = gridDim.x, gy = gridDim.y;
    int nwg = gx * gy;
    int flat = blockIdx.y * gx + blockIdx.x;
    int qq = nwg >> 3, rr8 = nwg & 7;
    int xcd = flat & 7, idx = flat >> 3;
    int base = (xcd < rr8) ? xcd * (qq + 1) : rr8 * (qq + 1) + (xcd - rr8) * qq;
    int nf = base + idx;
    int m0 = (nf % gy) * BM;
    int n0 = (nf / gy) * BN;
    int z = blockIdx.z;
    const unsigned short* Ab = A + (size_t)z * az;
    const unsigned short* Bb = B + (size_t)z * bz;
    int kb = (az == 0 && bz == 0) ? z * kper : 0;
    int nt = kper / 32;
    int tid = threadIdx.x, w = tid >> 6, lane = tid & 63;
    int wm = (w >> 1) * (MF * 16), wn = (w & 1) * (NF * 16);
    int ln = lane & 15;
    int ks = (((lane >> 4) ^ ((lane >> 1) & 3))) * 8;
    int srow = lane >> 2;
    int skc = (((lane & 3) ^ ((lane >> 3) & 3))) * 8;

    auto STAGE = [&](int buf, int t) {
        int k0 = kb + t * 32;
#pragma unroll
        for (int j = 0; j < LPW; j++) {
            int jj = w + j * 4;
            int r = jj * 16 + srow;
            const unsigned short* src;
            if (r < BM) src = Ab + (size_t)(m0 + r) * K + k0 + skc;
            else if (r < ROWS) src = Bb + (size_t)(n0 + r - BM) * ldb + k0 + skc;
            else src = Ab + (size_t)m0 * K + k0 + skc;  // dummy (uniform vmcnt)
            __builtin_amdgcn_global_load_lds((gas1_t)(const void*)src,
                                             (las3_t)(void*)&lds[buf][jj * 16][0], 16, 0, 0);
        }
    };

    STAGE(0, 0);
    if (nt > 1) STAGE(1, 1);
    f32x4 acc[MF][NF] = {};
    for (int t = 0; t < nt; ++t) {
        if (t + 1 < nt) {
            if constexpr (LPW == 4) asm volatile("s_waitcnt vmcnt(4) lgkmcnt(0)" ::: "memory");
            else if constexpr (LPW == 5) asm volatile("s_waitcnt vmcnt(5) lgkmcnt(0)" ::: "memory");
            else if constexpr (LPW == 6) asm volatile("s_waitcnt vmcnt(6) lgkmcnt(0)" ::: "memory");
            else asm volatile("s_waitcnt vmcnt(0) lgkmcnt(0)" ::: "memory");
        } else {
            asm volatile("s_waitcnt vmcnt(0) lgkmcnt(0)" ::: "memory");
        }
        __builtin_amdgcn_s_barrier();
        __builtin_amdgcn_sched_barrier(0);  // rule #18
        if (t + 2 < nt) STAGE((t + 2) % 3, t + 2);
        const unsigned short(*buf)[32] = lds[t % 3];
        short8 af[MF], bfv[NF];
#pragma unroll
        for (int mf = 0; mf < MF; mf++)
            af[mf] = *(const short8*)&buf[wm + mf * 16 + ln][ks];
#pragma unroll
        for (int nfi = 0; nfi < NF; nfi++)
            bfv[nfi] = *(const short8*)&buf[BM + wn + nfi * 16 + ln][ks];
        __builtin_amdgcn_s_setprio(1);  // T5
#pragma unroll
        for (int mf = 0; mf < MF; mf++)
#pragma unroll
            for (int nfi = 0; nfi < NF; nfi++)
                acc[mf][nfi] = __builtin_amdgcn_mfma_f32_16x16x32_bf16(af[mf], bfv[nfi],
                                                                       acc[mf][nfi], 0, 0, 0);
        __builtin_amdgcn_s_setprio(0);
    }
#pragma unroll
    for (int mf = 0; mf < MF; mf++) {
#pragma unroll
        for (int nfi = 0; nfi < NF; nfi++) {
#pragma unroll
            for (int rr = 0; rr < 4; rr++) {
                int row = m0 + wm + mf * 16 + (lane >> 4) * 4 + rr;
                int col = n0 + wn + nfi * 16 + ln;
                float v = acc[mf][nfi][rr];
                if (OUT_MODE == 6) {
                    ((unsigned short*)outp)[(size_t)row * N + col] = f2bf(v);
                } else if (OUT_MODE == 4) {
                    ((float*)outp)[((size_t)z * CAPS + row) * N + col] =
                        v * invS[z * CAPS + row] + bias[col];
                }
            }
        }
    }
}

// ======== fallback reg-staged NT GEMM (gemm1 only; used if ws too small for wbf) ========
__device__ inline uint4 load8(const unsigned short* p) { return *(const uint4*)p; }
__device__ inline uint4 load8(const float* p) {
    float4 a = *(const float4*)p;
    float4 b = *(const float4*)(p + 4);
    uint4 r;
    r.x = (unsigned)f2bf(a.x) | ((unsigned)f2bf(a.y) << 16);
    r.y = (unsigned)f2bf(a.z) | ((unsigned)f2bf(a.w) << 16);
    r.z = (unsigned)f2bf(b.x) | ((unsigned)f2bf(b.y) << 16);
    r.w = (unsigned)f2bf(b.z) | ((unsigned)f2bf(b.w) << 16);
    return r;
}

template <int MF, int NF, typename TA, typename TB>
__global__ __launch_bounds__(256) void mfma_gemm_nt(const TA* __restrict__ A,
                                                    const TB* __restrict__ B,
                                                    void* __restrict__ outp,
                                                    int M, int N, int K) {
    constexpr int BM = MF * 32, BN = NF * 32;
    constexpr int nA = BM * 4, nTot = (BM + BN) * 4;
    constexpr int NCH = (nTot + 255) / 256;
    __shared__ unsigned short As[BM][40];
    __shared__ unsigned short Bs[BN][40];
    int m0 = blockIdx.y * BM, n0 = blockIdx.x * BN;
    int tid = threadIdx.x;
    int w = tid >> 6, lane = tid & 63;
    int wm = (w >> 1) * (MF * 16), wn = (w & 1) * (NF * 16);
    int ln = lane & 15, ks = (lane >> 4) * 8;
    uint4 r[NCH];
#pragma unroll
    for (int j = 0; j < NCH; j++) {
        int c = tid + 256 * j;
        if (c < nTot) {
            if (c < nA) {
                int row = c >> 2, kc = c & 3;
                r[j] = load8(A + (size_t)(m0 + row) * K + kc * 8);
            } else {
                int cc = c - nA, row = cc >> 2, kc = cc & 3;
                r[j] = load8(B + (size_t)(n0 + row) * K + kc * 8);
            }
        }
    }
    f32x4 acc[MF][NF] = {};
    for (int k0 = 0; k0 < K; k0 += 32) {
#pragma unroll
        for (int j = 0; j < NCH; j++) {
            int c = tid + 256 * j;
            if (c < nTot) {
                if (c < nA) {
                    int row = c >> 2, kc = c & 3;
                    *(uint4*)&As[row][kc * 8] = r[j];
                } else {
                    int cc = c - nA, row = cc >> 2, kc = cc & 3;
                    *(uint4*)&Bs[row][kc * 8] = r[j];
                }
            }
        }
        __syncthreads();
        if (k0 + 32 < K) {
#pragma unroll
            for (int j = 0; j < NCH; j++) {
                int c = tid + 256 * j;
                if (c < nTot) {
                    if (c < nA) {
                        int row = c >> 2, kc = c & 3;
                        r[j] = load8(A + (size_t)(m0 + row) * K + (k0 + 32) + kc * 8);
                    } else {
                        int cc = c - nA, row = cc >> 2, kc = cc & 3;
                        r[j] = load8(B + (size_t)(n0 + row) * K + (k0 + 32) + kc * 8);
                    }
                }
            }
        }
        short8 af[MF], bfv[NF];
#pragma unroll
        for (int mf = 0; mf < MF; mf++)
            af[mf] = *(const short8*)&As[wm + mf * 16 + ln][ks];
#pragma unroll
        for (int nfi = 0; nfi < NF; nfi++)
            bfv[nfi] = *(const short8*)&Bs[wn + nfi * 16 + ln][ks];
#pragma unroll
        for (int mf = 0; mf < MF; mf++)
#pragma unroll
            for (int nfi = 0; nfi < NF; nfi++)
                acc[mf][nfi] = __builtin_amdgcn_mfma_f32_16x16x32_bf16(af[mf], bfv[nfi],
                                                                       acc[mf][nfi], 0, 0, 0);
        __syncthreads();
    }
#pragma unroll
    for (int mf = 0; mf < MF; mf++) {
#pragma unroll
        for (int nfi = 0; nfi < NF; nfi++) {
#pragma unroll
            for (int rr = 0; rr < 4; rr++) {
                int row = m0 + wm + mf * 16 + (lane >> 4) * 4 + rr;
                int col = n0 + wn + nfi * 16 + ln;
                ((unsigned short*)outp)[(size_t)row * N + col] = f2bf(acc[mf][nfi][rr]);
            }
        }
    }
}

// ---------------- heat v4: (i,c)-block; fused pad-zero + invS ----------------
__global__ __launch_bounds__(256) void heat_kernel(const int* __restrict__ idxs,
                                                   const float* __restrict__ vals,
                                                   const unsigned short* __restrict__ A,
                                                   unsigned short* __restrict__ Hnbf,
                                                   float* __restrict__ invS) {
    __shared__ int sidx[ATTK];
    __shared__ float sval[ATTK];
    __shared__ float wsum[4];
    int i = blockIdx.x, c = blockIdx.y;
    int tid = threadIdx.x;
    int w = tid >> 6, lane = tid & 63;
    if (tid < ATTK) {
        sidx[tid] = idxs[c * ATTK + tid];
        sval[tid] = vals[c * ATTK + tid];
    }
    __syncthreads();
    int hw = tid;
    float v = 0.f;
    if (hw < HW) {
        int n = i * HW + hw;
        float a0 = 0.f, a1 = 0.f, a2 = 0.f, a3 = 0.f;
#pragma unroll 1
        for (int j = 0; j < ATTK; j += 4) {
            a0 += sval[j + 0] * bf2f(A[(size_t)sidx[j + 0] * NCOLS + n] & 0x7FFFu);
            a1 += sval[j + 1] * bf2f(A[(size_t)sidx[j + 1] * NCOLS + n] & 0x7FFFu);
            a2 += sval[j + 2] * bf2f(A[(size_t)sidx[j + 2] * NCOLS + n] & 0x7FFFu);
            a3 += sval[j + 3] * bf2f(A[(size_t)sidx[j + 3] * NCOLS + n] & 0x7FFFu);
        }
        v = (a0 + a1) + (a2 + a3);
    }
    if (hw < KPAD)
        Hnbf[((size_t)i * CAPS + c) * KPAD + hw] = (hw < HW) ? f2bf(v) : (unsigned short)0;
    float s = v;
#pragma unroll
    for (int d = 32; d > 0; d >>= 1) s += __shfl_xor(s, d, 64);
    if (lane == 0) wsum[w] = s;
    __syncthreads();
    if (tid == 0)
        invS[i * CAPS + c] = 1.0f / (wsum[0] + wsum[1] + wsum[2] + wsum[3]);
}

extern "C" void kernel_launch(void* const* d_in, const int* in_sizes, int n_in,
                              void* d_out, int out_size, void* d_ws, size_t ws_size,
                              hipStream_t stream) {
    const float* g = (const float*)d_in[0];
    const float* caps = (const float*)d_in[1];
    const float* fc_w = (const float*)d_in[2];
    const float* fc_b = (const float*)d_in[3];

    float* out = (float*)d_out;
    float* x_out = out;                    // 38400
    float* xa_out = out + 38400;           // 2457600
    float* g_out = out + 38400 + 2457600;  // 7526400 floats = 30.1 MB

    float* ws = (float*)d_ws;
    float* hpool = ws;                                       // 38400 f
    int* idxs = (int*)(ws + 38400);                          // 11520
    float* vals = ws + 49920;                                // 11520
    float* invS = ws + 61440;                                // 1024 f
    unsigned short* Hnbf = (unsigned short*)(ws + 62464);    // 16*64*224 us
    unsigned short* wbf = (unsigned short*)(ws + 1490944);   // ends byte 17483776
    bool use_wbf = ws_size >= (size_t)17483776;
    bool ws_big = use_wbf && ws_size >= (size_t)(17483776 + 2 * 15052800);
    unsigned short* gT_big = (unsigned short*)((char*)d_ws + 17483776);
    unsigned short* Asig_big = (unsigned short*)((char*)d_ws + 17483776 + 15052800);

    // fallback tier: scratch in g_out ([Asig][gT] exact fit), memcpy at end.
    // xa-gemm K-tail (k=196..223) reads <=27 elems past an image slice into
    // initialized finite data x Hn-pad=0 -> exact 0 (both tiers).
    unsigned short* Asig = ws_big ? Asig_big : (unsigned short*)g_out;
    unsigned short* gT = ws_big ? gT_big : ((unsigned short*)g_out + (size_t)EMB * NCOLS);

    if (use_wbf) {
        // combo: [transpool 1200][convw 600][topk 64] -- VALU-heavy first (r19)
        combo_kernel<<<(EMB / 32) * IMGS + EMB / 4 + CAPS, 256, 0, stream>>>(
            g, hpool, gT, ws_big ? g_out : nullptr, caps, idxs, vals, fc_w, wbf, EMB / 4);
        x_bf_kernel<<<EMB / 4, 256, 0, stream>>>(hpool, wbf, fc_b, x_out);
        // gemm1 (5,7): signed Asig; BM=160 (15), BN=224 (14) -> 210 blocks
        gemm_gll<5, 7, 6><<<dim3(NCOLS / 224, EMB / 160, 1), 256, 0, stream>>>(
            wbf, gT, Asig, nullptr, nullptr, EMB, NCOLS, EMB, EMB, EMB, 0, 0);
    } else {
        combo_kernel<<<(EMB / 32) * IMGS + CAPS, 256, 0, stream>>>(
            g, hpool, gT, nullptr, caps, idxs, vals, fc_w, nullptr, 0);
        x_kernel<<<EMB, 64, 0, stream>>>(hpool, fc_w, fc_b, x_out);
        mfma_gemm_nt<5, 2, float, unsigned short>
            <<<dim3(NCOLS / 64, EMB / 160), 256, 0, stream>>>(fc_w, gT, Asig,
                                                              EMB, NCOLS, EMB);
    }
    heat_kernel<<<dim3(IMGS, CAPS), 256, 0, stream>>>(idxs, vals, Asig, Hnbf, invS);
    // xa = (Hraw_i @ Asig_i^T) * invS + bias : per-image batched GEMM
    gemm_gll<2, 5, 4><<<dim3(EMB / 160, 1, IMGS), 256, 0, stream>>>(
        Hnbf, Asig, xa_out, fc_b, invS, CAPS, EMB, KPAD, NCOLS, KPAD,
        (long)CAPS * KPAD, HW);
    if (!ws_big) {
        hipMemcpyAsync(g_out, g, sizeof(float) * (size_t)IMGS * EMB * HW,
                       hipMemcpyDeviceToDevice, stream);
    }
}

// Round 20
// 147.107 us; speedup vs baseline: 1.8762x; 1.0053x over previous
//
#include <hip/hip_runtime.h>
#include <math.h>

#define IMGS 16
#define EMB 2400
#define HW 196
#define CAPS 64
#define ATTK 180
#define NPOOL 15
#define NCOLS (IMGS * HW)  // 3136
#define KPAD 224           // 196 padded to multiple of 32

typedef __attribute__((ext_vector_type(8))) short short8;
typedef __attribute__((ext_vector_type(4))) float f32x4;
typedef const __attribute__((address_space(1))) unsigned int* gas1_t;
typedef __attribute__((address_space(3))) unsigned int* las3_t;
typedef unsigned long long ull;

__device__ inline unsigned short f2bf(float f) {
    unsigned int u = __builtin_bit_cast(unsigned int, f);
    u += 0x7fffu + ((u >> 16) & 1u);  // round-to-nearest-even
    return (unsigned short)(u >> 16);
}
__device__ inline float bf2f(unsigned int lo16) {
    return __builtin_bit_cast(float, lo16 << 16);
}
__device__ inline unsigned f2sort(float f) {
    unsigned u = __builtin_bit_cast(unsigned, f);
    int msk = ((int)u) >> 31;
    return u ^ (unsigned)(msk | 0x80000000);
}

// ================= combo bodies (independent roles, one dispatch) =================
// r20: weldon extraction now runs 4 ROWS simultaneously (4 independent DPP chains;
// r19's 2-chain moved 64->61us, still latency-bound -> deepen ILP). All s[][]
// indices compile-time (full unroll) per rule #20.

// ---- transpool body: transpose+weldon (+optional g passthrough), LDS [32][197] ----
__device__ __forceinline__ void transpool_body(char* smem, int bx, int i,
                                               const float* __restrict__ g,
                                               float* __restrict__ hpool,
                                               unsigned short* __restrict__ gT,
                                               float* __restrict__ gout) {
    float(*t)[197] = (float(*)[197])smem;
    int e0 = bx * 32;
    int tid = threadIdx.x;
    const float* base = g + ((size_t)i * EMB + e0) * HW;
    float* obase = gout ? gout + ((size_t)i * EMB + e0) * HW : nullptr;
    for (int f = tid; f < 32 * HW; f += 256) {
        int e = f / HW, hw = f % HW;
        float v = base[(size_t)e * HW + hw];
        t[e][hw] = v;
        if (obase) obase[(size_t)e * HW + hw] = v;
    }
    __syncthreads();
    for (int f = tid; f < HW * 32; f += 256) {
        int hw = f / 32, e = f % 32;
        gT[((size_t)i * HW + hw) * EMB + e0 + e] = f2bf(t[e][hw]);
    }
    int w = tid >> 6, tl = tid & 63, hl = tl & 31;
    bool negh = tl >= 32;
#pragma unroll 1
    for (int rq = 0; rq < 2; ++rq) {  // row QUADS: 4 independent DPP chains
        int eb = w * 8 + rq * 4;
        float s[4][7];
#pragma unroll
        for (int r = 0; r < 4; r++) {
#pragma unroll
            for (int q = 0; q < 7; q++) {
                int hw = hl + 32 * q;
                if (hw < HW) {
                    unsigned u = __builtin_bit_cast(unsigned, t[eb + r][hw]);
                    if (negh) u ^= 0x80000000u;  // negate for bottom-15
                    s[r][q] = __builtin_bit_cast(
                        float, (u & 0xFFFFFF00u) | (unsigned)(q * 32 + hl));
                } else {
                    s[r][q] = -INFINITY;
                }
            }
        }
        // Bose-Nelson sort-7 (desc) x4, interleaved
#define CS1(r, a, b)                                       \
    {                                                      \
        float hi = fmaxf(s[r][a], s[r][b]);                \
        float lo = fminf(s[r][a], s[r][b]);                \
        s[r][a] = hi; s[r][b] = lo;                        \
    }
#define CSQ(a, b) CS1(0, a, b) CS1(1, a, b) CS1(2, a, b) CS1(3, a, b)
        CSQ(1, 2) CSQ(3, 4) CSQ(5, 6)
        CSQ(0, 2) CSQ(3, 5) CSQ(4, 6)
        CSQ(0, 1) CSQ(4, 5) CSQ(2, 6)
        CSQ(0, 4) CSQ(1, 5)
        CSQ(0, 3) CSQ(2, 5)
        CSQ(1, 3) CSQ(2, 4)
        CSQ(2, 3)
#undef CSQ
#undef CS1
        float acc[4] = {0.f, 0.f, 0.f, 0.f};
#pragma unroll
        for (int it = 0; it < NPOOL; ++it) {
            int xx[4];
#pragma unroll
            for (int r = 0; r < 4; r++) xx[r] = __builtin_bit_cast(int, s[r][0]);
#define ST4(c)                                                                     \
    {                                                                              \
        _Pragma("unroll") for (int r = 0; r < 4; r++) {                            \
            int y = __builtin_amdgcn_update_dpp(xx[r], xx[r], c, 0xf, 0xf, false); \
            float a = fmaxf(__builtin_bit_cast(float, xx[r]),                      \
                            __builtin_bit_cast(float, y));                         \
            xx[r] = __builtin_bit_cast(int, a);                                    \
        }                                                                          \
    }
            ST4(0x111) ST4(0x112) ST4(0x114) ST4(0x118) ST4(0x142)
#undef ST4
#pragma unroll
            for (int r = 0; r < 4; r++) {
                int m31 = __builtin_amdgcn_readlane(xx[r], 31);
                int m63 = __builtin_amdgcn_readlane(xx[r], 63);
                float msel = __builtin_bit_cast(float, negh ? m63 : m31);
                acc[r] += msel;
                bool won = (__builtin_bit_cast(unsigned, s[r][0]) ==
                            __builtin_bit_cast(unsigned, msel));
                s[r][0] = won ? s[r][1] : s[r][0];
                s[r][1] = won ? s[r][2] : s[r][1];
                s[r][2] = won ? s[r][3] : s[r][2];
                s[r][3] = won ? s[r][4] : s[r][3];
                s[r][4] = won ? s[r][5] : s[r][4];
                s[r][5] = won ? s[r][6] : s[r][5];
                s[r][6] = won ? -INFINITY : s[r][6];
            }
        }
#pragma unroll
        for (int r = 0; r < 4; r++) {
            int ai = __builtin_bit_cast(int, acc[r]);
            float a0 = __builtin_bit_cast(float, __builtin_amdgcn_readlane(ai, 0));
            float a32 = __builtin_bit_cast(float, __builtin_amdgcn_readlane(ai, 32));
            if (tl == 0) hpool[(size_t)i * EMB + e0 + eb + r] = (a0 - a32) / 15.0f;
        }
    }
}

// ---- topk body: radix select, wave-level scans (shared layout in smem) ----
__device__ __forceinline__ void topk_body(char* smem, int c,
                                          const float* __restrict__ caps,
                                          int* __restrict__ idxs,
                                          float* __restrict__ vals) {
    float* rowf = (float*)smem;                                // 9600 B
    unsigned(*hist)[256] = (unsigned(*)[256])(smem + 9600);    // 4096 B
    unsigned* scanbuf = (unsigned*)(smem + 13696);             // 1024 B
    unsigned* wtot = (unsigned*)(smem + 14720);                // 16 B
    ull* sprefix = (ull*)(smem + 14744);                       // 8 B
    int* srank = (int*)(smem + 14752);                         // 4 B
    int tid = threadIdx.x;
    int w = tid >> 6, lane = tid & 63;
    const float4* src = (const float4*)(caps + (size_t)c * EMB);
    for (int j = tid; j < EMB / 4; j += 256) {
        float4 v = src[j];
        *(float4*)&rowf[j * 4] = v;
    }
    if (tid == 0) { *sprefix = 0ull; *srank = ATTK; }
#pragma unroll 1
    for (int pass = 0; pass < 6; ++pass) {
        __syncthreads();
        ull pref = *sprefix;
        int rk = *srank;
        int shift = 40 - pass * 8;
        ull pmaskhi = (pass == 0) ? 0ull : ~((1ull << (shift + 8)) - 1ull);
        hist[0][tid] = 0; hist[1][tid] = 0; hist[2][tid] = 0; hist[3][tid] = 0;
        __syncthreads();
        unsigned* myhist = hist[w];
#pragma unroll 1
        for (int s = 0; s < 10; s++) {
            int e = tid + s * 256;
            if (e < EMB) {
                ull key = ((ull)f2sort(rowf[e]) << 16) | ((unsigned)(2399 - e) << 4);
                if ((key & pmaskhi) == pref)
                    atomicAdd(&myhist[(unsigned)(key >> shift) & 255u], 1u);
            }
        }
        __syncthreads();
        unsigned h = hist[0][tid] + hist[1][tid] + hist[2][tid] + hist[3][tid];
        scanbuf[255 - tid] = h;
        __syncthreads();
        unsigned x = scanbuf[tid];
#pragma unroll
        for (int d = 1; d < 64; d <<= 1) {
            unsigned u = __shfl_up(x, d, 64);
            if (lane >= d) x += u;
        }
        if (lane == 63) wtot[w] = x;
        __syncthreads();
        unsigned off = 0;
        for (int ww = 0; ww < w; ww++) off += wtot[ww];
        scanbuf[tid] = x + off;
        __syncthreads();
        unsigned incl = scanbuf[255 - tid];
        unsigned excl = incl - h;
        if (h > 0u && excl < (unsigned)rk && incl >= (unsigned)rk) {
            *srank = rk - (int)excl;
            *sprefix = pref | ((ull)tid << shift);
        }
    }
    __syncthreads();
    ull T = *sprefix;
    unsigned selmask = 0, cnt = 0;
#pragma unroll 1
    for (int s = 0; s < 10; s++) {
        int e = tid + s * 256;
        if (e < EMB) {
            ull key = ((ull)f2sort(rowf[e]) << 16) | ((unsigned)(2399 - e) << 4);
            if (key >= T) { selmask |= 1u << s; cnt++; }
        }
    }
    unsigned x = cnt;
#pragma unroll
    for (int d = 1; d < 64; d <<= 1) {
        unsigned u = __shfl_up(x, d, 64);
        if (lane >= d) x += u;
    }
    if (lane == 63) wtot[w] = x;
    __syncthreads();
    unsigned off = 0;
    for (int ww = 0; ww < w; ww++) off += wtot[ww];
    unsigned slot = x + off - cnt;
#pragma unroll 1
    for (int s = 0; s < 10; s++) {
        if (selmask & (1u << s)) {
            int e = tid + s * 256;
            idxs[c * ATTK + slot] = e;
            vals[c * ATTK + slot] = fabsf(rowf[e]);
            slot++;
        }
    }
}

// ---- convw body: wbf = bf16(fc_w), 4 rows/block (wave per row) ----
__device__ __forceinline__ void convw_body(int b, const float* __restrict__ fc_w,
                                           unsigned short* __restrict__ wbf) {
    int o = b * 4 + (threadIdx.x >> 6);
    int lane = threadIdx.x & 63;
    const float* wrow = fc_w + (size_t)o * EMB;
    unsigned short* wdst = wbf + (size_t)o * EMB;
    for (int e = lane * 4; e < EMB; e += 256) {
        float4 wv = *(const float4*)&wrow[e];
        ushort4 r;
        r.x = f2bf(wv.x); r.y = f2bf(wv.y); r.z = f2bf(wv.z); r.w = f2bf(wv.w);
        *(ushort4*)&wdst[e] = r;
    }
}

// ---- combo dispatcher: [transpool 1200][convw 600][topk 64] ----
__global__ __launch_bounds__(256) void combo_kernel(const float* __restrict__ g,
                                                    float* __restrict__ hpool,
                                                    unsigned short* __restrict__ gT,
                                                    float* __restrict__ gout,
                                                    const float* __restrict__ caps,
                                                    int* __restrict__ idxs,
                                                    float* __restrict__ vals,
                                                    const float* __restrict__ fc_w,
                                                    unsigned short* __restrict__ wbf,
                                                    int nconv) {
    __shared__ __align__(16) char smem[25664];
    int b = blockIdx.x;
    constexpr int NTP = (EMB / 32) * IMGS;  // 1200
    if (b < NTP) {
        transpool_body(smem, b % (EMB / 32), b / (EMB / 32), g, hpool, gT, gout);
    } else if (b < NTP + nconv) {
        convw_body(b - NTP, fc_w, wbf);
    } else {
        topk_body(smem, b - NTP - nconv, caps, idxs, vals);
    }
}

// ---------------- x (fallback, fp32 weights) ----------------
__global__ void x_kernel(const float* __restrict__ hpool, const float* __restrict__ fc_w,
                         const float* __restrict__ fc_b, float* __restrict__ x_out) {
    int o = blockIdx.x;
    int lane = threadIdx.x;
    float acc[IMGS];
#pragma unroll
    for (int i = 0; i < IMGS; i++) acc[i] = 0.f;
    const float* wrow = fc_w + (size_t)o * EMB;
    for (int e = lane; e < EMB; e += 64) {
        float wv = wrow[e];
#pragma unroll
        for (int i = 0; i < IMGS; i++) acc[i] += hpool[i * EMB + e] * wv;
    }
#pragma unroll
    for (int i = 0; i < IMGS; i++) {
#pragma unroll
        for (int sdx = 32; sdx > 0; sdx >>= 1) acc[i] += __shfl_xor(acc[i], sdx, 64);
    }
    if (lane == 0) {
        float bo = fc_b[o];
#pragma unroll
        for (int i = 0; i < IMGS; i++) x_out[i * EMB + o] = acc[i] + bo;
    }
}

// ======== NT bf16 MFMA GEMM, gll staging, 3-buffer counted-vmcnt pipeline ========
// T1 bijective XCD swizzle + y-major; T2 source/read swizzle; T4 counted vmcnt;
// T5 setprio. OUT_MODE 6: signed bf16. OUT_MODE 4: f32 v*invS[z*64+row]+bias[col].
template <int MF, int NF, int OUT_MODE>
__global__ __launch_bounds__(256) void gemm_gll(const unsigned short* __restrict__ A,
                                                const unsigned short* __restrict__ B,
                                                void* __restrict__ outp,
                                                const float* __restrict__ bias,
                                                const float* __restrict__ invS,
                                                int M, int N, int K, int ldb, int kper,
                                                long az, long bz) {
    constexpr int BM = MF * 32, BN = NF * 32;
    constexpr int ROWS = BM + BN;
    constexpr int RPAD = (ROWS + 63) & ~63;
    constexpr int NCALL = RPAD / 16;
    constexpr int LPW = NCALL / 4;
    __shared__ unsigned short lds[3][RPAD][32];
    int gx = gridDim.x, gy = gridDim.y;
    int nwg = gx * gy;
    int flat = blockIdx.y * gx + blockIdx.x;
    int qq = nwg >> 3, rr8 = nwg & 7;
    int xcd = flat & 7, idx = flat >> 3;
    int base = (xcd < rr8) ? xcd * (qq + 1) : rr8 * (qq + 1) + (xcd - rr8) * qq;
    int nf = base + idx;
    int m0 = (nf % gy) * BM;
    int n0 = (nf / gy) * BN;
    int z = blockIdx.z;
    const unsigned short* Ab = A + (size_t)z * az;
    const unsigned short* Bb = B + (size_t)z * bz;
    int kb = (az == 0 && bz == 0) ? z * kper : 0;
    int nt = kper / 32;
    int tid = threadIdx.x, w = tid >> 6, lane = tid & 63;
    int wm = (w >> 1) * (MF * 16), wn = (w & 1) * (NF * 16);
    int ln = lane & 15;
    int ks = (((lane >> 4) ^ ((lane >> 1) & 3))) * 8;
    int srow = lane >> 2;
    int skc = (((lane & 3) ^ ((lane >> 3) & 3))) * 8;

    auto STAGE = [&](int buf, int t) {
        int k0 = kb + t * 32;
#pragma unroll
        for (int j = 0; j < LPW; j++) {
            int jj = w + j * 4;
            int r = jj * 16 + srow;
            const unsigned short* src;
            if (r < BM) src = Ab + (size_t)(m0 + r) * K + k0 + skc;
            else if (r < ROWS) src = Bb + (size_t)(n0 + r - BM) * ldb + k0 + skc;
            else src = Ab + (size_t)m0 * K + k0 + skc;  // dummy (uniform vmcnt)
            __builtin_amdgcn_global_load_lds((gas1_t)(const void*)src,
                                             (las3_t)(void*)&lds[buf][jj * 16][0], 16, 0, 0);
        }
    };

    STAGE(0, 0);
    if (nt > 1) STAGE(1, 1);
    f32x4 acc[MF][NF] = {};
    for (int t = 0; t < nt; ++t) {
        if (t + 1 < nt) {
            if constexpr (LPW == 4) asm volatile("s_waitcnt vmcnt(4) lgkmcnt(0)" ::: "memory");
            else if constexpr (LPW == 5) asm volatile("s_waitcnt vmcnt(5) lgkmcnt(0)" ::: "memory");
            else if constexpr (LPW == 6) asm volatile("s_waitcnt vmcnt(6) lgkmcnt(0)" ::: "memory");
            else asm volatile("s_waitcnt vmcnt(0) lgkmcnt(0)" ::: "memory");
        } else {
            asm volatile("s_waitcnt vmcnt(0) lgkmcnt(0)" ::: "memory");
        }
        __builtin_amdgcn_s_barrier();
        __builtin_amdgcn_sched_barrier(0);  // rule #18
        if (t + 2 < nt) STAGE((t + 2) % 3, t + 2);
        const unsigned short(*buf)[32] = lds[t % 3];
        short8 af[MF], bfv[NF];
#pragma unroll
        for (int mf = 0; mf < MF; mf++)
            af[mf] = *(const short8*)&buf[wm + mf * 16 + ln][ks];
#pragma unroll
        for (int nfi = 0; nfi < NF; nfi++)
            bfv[nfi] = *(const short8*)&buf[BM + wn + nfi * 16 + ln][ks];
        __builtin_amdgcn_s_setprio(1);  // T5
#pragma unroll
        for (int mf = 0; mf < MF; mf++)
#pragma unroll
            for (int nfi = 0; nfi < NF; nfi++)
                acc[mf][nfi] = __builtin_amdgcn_mfma_f32_16x16x32_bf16(af[mf], bfv[nfi],
                                                                       acc[mf][nfi], 0, 0, 0);
        __builtin_amdgcn_s_setprio(0);
    }
#pragma unroll
    for (int mf = 0; mf < MF; mf++) {
#pragma unroll
        for (int nfi = 0; nfi < NF; nfi++) {
#pragma unroll
            for (int rr = 0; rr < 4; rr++) {
                int row = m0 + wm + mf * 16 + (lane >> 4) * 4 + rr;
                int col = n0 + wn + nfi * 16 + ln;
                float v = acc[mf][nfi][rr];
                if (OUT_MODE == 6) {
                    ((unsigned short*)outp)[(size_t)row * N + col] = f2bf(v);
                } else if (OUT_MODE == 4) {
                    ((float*)outp)[((size_t)z * CAPS + row) * N + col] =
                        v * invS[z * CAPS + row] + bias[col];
                }
            }
        }
    }
}

// ======== fallback reg-staged NT GEMM (gemm1 only; used if ws too small for wbf) ========
__device__ inline uint4 load8(const unsigned short* p) { return *(const uint4*)p; }
__device__ inline uint4 load8(const float* p) {
    float4 a = *(const float4*)p;
    float4 b = *(const float4*)(p + 4);
    uint4 r;
    r.x = (unsigned)f2bf(a.x) | ((unsigned)f2bf(a.y) << 16);
    r.y = (unsigned)f2bf(a.z) | ((unsigned)f2bf(a.w) << 16);
    r.z = (unsigned)f2bf(b.x) | ((unsigned)f2bf(b.y) << 16);
    r.w = (unsigned)f2bf(b.z) | ((unsigned)f2bf(b.w) << 16);
    return r;
}

template <int MF, int NF, typename TA, typename TB>
__global__ __launch_bounds__(256) void mfma_gemm_nt(const TA* __restrict__ A,
                                                    const TB* __restrict__ B,
                                                    void* __restrict__ outp,
                                                    int M, int N, int K) {
    constexpr int BM = MF * 32, BN = NF * 32;
    constexpr int nA = BM * 4, nTot = (BM + BN) * 4;
    constexpr int NCH = (nTot + 255) / 256;
    __shared__ unsigned short As[BM][40];
    __shared__ unsigned short Bs[BN][40];
    int m0 = blockIdx.y * BM, n0 = blockIdx.x * BN;
    int tid = threadIdx.x;
    int w = tid >> 6, lane = tid & 63;
    int wm = (w >> 1) * (MF * 16), wn = (w & 1) * (NF * 16);
    int ln = lane & 15, ks = (lane >> 4) * 8;
    uint4 r[NCH];
#pragma unroll
    for (int j = 0; j < NCH; j++) {
        int c = tid + 256 * j;
        if (c < nTot) {
            if (c < nA) {
                int row = c >> 2, kc = c & 3;
                r[j] = load8(A + (size_t)(m0 + row) * K + kc * 8);
            } else {
                int cc = c - nA, row = cc >> 2, kc = cc & 3;
                r[j] = load8(B + (size_t)(n0 + row) * K + kc * 8);
            }
        }
    }
    f32x4 acc[MF][NF] = {};
    for (int k0 = 0; k0 < K; k0 += 32) {
#pragma unroll
        for (int j = 0; j < NCH; j++) {
            int c = tid + 256 * j;
            if (c < nTot) {
                if (c < nA) {
                    int row = c >> 2, kc = c & 3;
                    *(uint4*)&As[row][kc * 8] = r[j];
                } else {
                    int cc = c - nA, row = cc >> 2, kc = cc & 3;
                    *(uint4*)&Bs[row][kc * 8] = r[j];
                }
            }
        }
        __syncthreads();
        if (k0 + 32 < K) {
#pragma unroll
            for (int j = 0; j < NCH; j++) {
                int c = tid + 256 * j;
                if (c < nTot) {
                    if (c < nA) {
                        int row = c >> 2, kc = c & 3;
                        r[j] = load8(A + (size_t)(m0 + row) * K + (k0 + 32) + kc * 8);
                    } else {
                        int cc = c - nA, row = cc >> 2, kc = cc & 3;
                        r[j] = load8(B + (size_t)(n0 + row) * K + (k0 + 32) + kc * 8);
                    }
                }
            }
        }
        short8 af[MF], bfv[NF];
#pragma unroll
        for (int mf = 0; mf < MF; mf++)
            af[mf] = *(const short8*)&As[wm + mf * 16 + ln][ks];
#pragma unroll
        for (int nfi = 0; nfi < NF; nfi++)
            bfv[nfi] = *(const short8*)&Bs[wn + nfi * 16 + ln][ks];
#pragma unroll
        for (int mf = 0; mf < MF; mf++)
#pragma unroll
            for (int nfi = 0; nfi < NF; nfi++)
                acc[mf][nfi] = __builtin_amdgcn_mfma_f32_16x16x32_bf16(af[mf], bfv[nfi],
                                                                       acc[mf][nfi], 0, 0, 0);
        __syncthreads();
    }
#pragma unroll
    for (int mf = 0; mf < MF; mf++) {
#pragma unroll
        for (int nfi = 0; nfi < NF; nfi++) {
#pragma unroll
            for (int rr = 0; rr < 4; rr++) {
                int row = m0 + wm + mf * 16 + (lane >> 4) * 4 + rr;
                int col = n0 + wn + nfi * 16 + ln;
                ((unsigned short*)outp)[(size_t)row * N + col] = f2bf(acc[mf][nfi][rr]);
            }
        }
    }
}

// ======== heatx: heat (i,c)-blocks + x_bf blocks in one dispatch ========
// b < nheat: heat body (fused pad-zero + invS). b >= nheat: x = hpool@wbf^T + b.
__global__ __launch_bounds__(256) void heatx_kernel(const int* __restrict__ idxs,
                                                    const float* __restrict__ vals,
                                                    const unsigned short* __restrict__ A,
                                                    unsigned short* __restrict__ Hnbf,
                                                    float* __restrict__ invS,
                                                    const float* __restrict__ hpool,
                                                    const unsigned short* __restrict__ wbf,
                                                    const float* __restrict__ fc_b,
                                                    float* __restrict__ x_out,
                                                    int nheat) {
    __shared__ int sidx[ATTK];
    __shared__ float sval[ATTK];
    __shared__ float wsum[4];
    int b = blockIdx.x;
    int tid = threadIdx.x;
    int w = tid >> 6, lane = tid & 63;
    if (b < nheat) {
        int i = b % IMGS, c = b / IMGS;
        if (tid < ATTK) {
            sidx[tid] = idxs[c * ATTK + tid];
            sval[tid] = vals[c * ATTK + tid];
        }
        __syncthreads();
        int hw = tid;
        float v = 0.f;
        if (hw < HW) {
            int n = i * HW + hw;
            float a0 = 0.f, a1 = 0.f, a2 = 0.f, a3 = 0.f;
#pragma unroll 1
            for (int j = 0; j < ATTK; j += 4) {
                a0 += sval[j + 0] * bf2f(A[(size_t)sidx[j + 0] * NCOLS + n] & 0x7FFFu);
                a1 += sval[j + 1] * bf2f(A[(size_t)sidx[j + 1] * NCOLS + n] & 0x7FFFu);
                a2 += sval[j + 2] * bf2f(A[(size_t)sidx[j + 2] * NCOLS + n] & 0x7FFFu);
                a3 += sval[j + 3] * bf2f(A[(size_t)sidx[j + 3] * NCOLS + n] & 0x7FFFu);
            }
            v = (a0 + a1) + (a2 + a3);
        }
        if (hw < KPAD)
            Hnbf[((size_t)i * CAPS + c) * KPAD + hw] =
                (hw < HW) ? f2bf(v) : (unsigned short)0;
        float s = v;
#pragma unroll
        for (int d = 32; d > 0; d >>= 1) s += __shfl_xor(s, d, 64);
        if (lane == 0) wsum[w] = s;
        __syncthreads();
        if (tid == 0)
            invS[i * CAPS + c] = 1.0f / (wsum[0] + wsum[1] + wsum[2] + wsum[3]);
    } else {
        int o = (b - nheat) * 4 + w;
        float acc[IMGS];
#pragma unroll
        for (int i = 0; i < IMGS; i++) acc[i] = 0.f;
        const unsigned short* wrow = wbf + (size_t)o * EMB;
        for (int e = lane * 4; e < EMB; e += 256) {
            ushort4 wq = *(const ushort4*)&wrow[e];
            float w0 = bf2f(wq.x), w1 = bf2f(wq.y), w2 = bf2f(wq.z), w3 = bf2f(wq.w);
#pragma unroll
            for (int i = 0; i < IMGS; i++) {
                const float* hp = hpool + i * EMB + e;
                acc[i] += hp[0] * w0 + hp[1] * w1 + hp[2] * w2 + hp[3] * w3;
            }
        }
#pragma unroll
        for (int i = 0; i < IMGS; i++) {
#pragma unroll
            for (int sdx = 32; sdx > 0; sdx >>= 1) acc[i] += __shfl_xor(acc[i], sdx, 64);
        }
        if (lane == 0) {
            float bo = fc_b[o];
#pragma unroll
            for (int i = 0; i < IMGS; i++) x_out[i * EMB + o] = acc[i] + bo;
        }
    }
}

extern "C" void kernel_launch(void* const* d_in, const int* in_sizes, int n_in,
                              void* d_out, int out_size, void* d_ws, size_t ws_size,
                              hipStream_t stream) {
    const float* g = (const float*)d_in[0];
    const float* caps = (const float*)d_in[1];
    const float* fc_w = (const float*)d_in[2];
    const float* fc_b = (const float*)d_in[3];

    float* out = (float*)d_out;
    float* x_out = out;                    // 38400
    float* xa_out = out + 38400;           // 2457600
    float* g_out = out + 38400 + 2457600;  // 7526400 floats = 30.1 MB

    float* ws = (float*)d_ws;
    float* hpool = ws;                                       // 38400 f
    int* idxs = (int*)(ws + 38400);                          // 11520
    float* vals = ws + 49920;                                // 11520
    float* invS = ws + 61440;                                // 1024 f
    unsigned short* Hnbf = (unsigned short*)(ws + 62464);    // 16*64*224 us
    unsigned short* wbf = (unsigned short*)(ws + 1490944);   // ends byte 17483776
    bool use_wbf = ws_size >= (size_t)17483776;
    bool ws_big = use_wbf && ws_size >= (size_t)(17483776 + 2 * 15052800);
    unsigned short* gT_big = (unsigned short*)((char*)d_ws + 17483776);
    unsigned short* Asig_big = (unsigned short*)((char*)d_ws + 17483776 + 15052800);

    // fallback tier: scratch in g_out ([Asig][gT] exact fit), memcpy at end.
    // xa-gemm K-tail (k=196..223) reads <=27 elems past an image slice into
    // initialized finite data x Hn-pad=0 -> exact 0 (both tiers).
    unsigned short* Asig = ws_big ? Asig_big : (unsigned short*)g_out;
    unsigned short* gT = ws_big ? gT_big : ((unsigned short*)g_out + (size_t)EMB * NCOLS);

    if (use_wbf) {
        // combo: [transpool 1200][convw 600][topk 64] -- VALU-heavy first
        combo_kernel<<<(EMB / 32) * IMGS + EMB / 4 + CAPS, 256, 0, stream>>>(
            g, hpool, gT, ws_big ? g_out : nullptr, caps, idxs, vals, fc_w, wbf, EMB / 4);
        // gemm1 (5,7): signed Asig; BM=160 (15), BN=224 (14) -> 210 blocks
        gemm_gll<5, 7, 6><<<dim3(NCOLS / 224, EMB / 160, 1), 256, 0, stream>>>(
            wbf, gT, Asig, nullptr, nullptr, EMB, NCOLS, EMB, EMB, EMB, 0, 0);
        // heat (1024 blocks) + x_bf (600 blocks) co-dispatched
        heatx_kernel<<<IMGS * CAPS + EMB / 4, 256, 0, stream>>>(
            idxs, vals, Asig, Hnbf, invS, hpool, wbf, fc_b, x_out, IMGS * CAPS);
    } else {
        combo_kernel<<<(EMB / 32) * IMGS + CAPS, 256, 0, stream>>>(
            g, hpool, gT, nullptr, caps, idxs, vals, fc_w, nullptr, 0);
        x_kernel<<<EMB, 64, 0, stream>>>(hpool, fc_w, fc_b, x_out);
        mfma_gemm_nt<5, 2, float, unsigned short>
            <<<dim3(NCOLS / 64, EMB / 160), 256, 0, stream>>>(fc_w, gT, Asig,
                                                              EMB, NCOLS, EMB);
        heatx_kernel<<<IMGS * CAPS, 256, 0, stream>>>(
            idxs, vals, Asig, Hnbf, invS, hpool, nullptr, fc_b, x_out, IMGS * CAPS);
    }
    // xa = (Hraw_i @ Asig_i^T) * invS + bias : per-image batched GEMM
    gemm_gll<2, 5, 4><<<dim3(EMB / 160, 1, IMGS), 256, 0, stream>>>(
        Hnbf, Asig, xa_out, fc_b, invS, CAPS, EMB, KPAD, NCOLS, KPAD,
        (long)CAPS * KPAD, HW);
    if (!ws_big) {
        hipMemcpyAsync(g_out, g, sizeof(float) * (size_t)IMGS * EMB * HW,
                       hipMemcpyDeviceToDevice, stream);
    }
}